// Round 2
// baseline (1431.584 us; speedup 1.0000x reference)
//
#include <hip/hip_runtime.h>
#include <hip/hip_bf16.h>

#define DEVI __device__ __forceinline__

DEVI float bf2f(unsigned short u){ return __uint_as_float(((unsigned int)u)<<16); }
DEVI unsigned short f2bf(float f){
  unsigned int u = __float_as_uint(f);
  unsigned int r = (u + 0x7fffu + ((u>>16)&1u)) >> 16;
  return (unsigned short)r;
}
DEVI float sigf(float x){ return 1.f/(1.f + __expf(-x)); }

// ---------------------------------------------------------------------------
// K1: fused conv front-end. One block per signal (B*S*C = 10240 signals).
// conv1(k7,s2,p3)+BN+ReLU+pool3 -> conv2(k5,s2,p2)+BN+ReLU+pool3 ->
// conv3(k3,s1,p1)+BN+ReLU -> mean(83) => feats[sig][64]
// 512 threads; ~56.5KB LDS -> 2 blocks/CU -> 16 waves/CU (VGPR<=128).
// ---------------------------------------------------------------------------
__global__ __launch_bounds__(512) void k_conv(
    const float* __restrict__ x,
    const float* __restrict__ w1g, const float* __restrict__ c1b,
    const float* __restrict__ bg1, const float* __restrict__ bb1,
    const float* __restrict__ w2g, const float* __restrict__ c2b,
    const float* __restrict__ bg2, const float* __restrict__ bb2,
    const float* __restrict__ w3g, const float* __restrict__ c3b,
    const float* __restrict__ bg3, const float* __restrict__ bb3,
    float* __restrict__ feats)
{
  __shared__ float sm[13796];
  __shared__ float w1s[112];
  __shared__ float kb1[32], kb2[64], kb3[128];
  float* s1t = sm;            // [504][16], p = pos+2 (conv1 pooled out, pos 0..499)
  float* sx  = sm + 8064;     // 3012 floats, idx = t+4 (phase A)
  float* w2s = sm + 8064;     // phase B: [32][81] padded
  float* red = sm + 8064;     // phase C reduce [512]
  float* s2t = sm + 11076;    // [85][32], p = pos+1 (conv2 pooled out, pos 0..82)
  float* w3s = sm;            // phase C: [64][97] padded
  const int tid = threadIdx.x;
  const long sig = blockIdx.x;
  const float* xg = x + sig*3000;

  // stage x (float4) + pads + weights/consts
  {
    const float4* xg4 = reinterpret_cast<const float4*>(xg);
    float4* sx4 = reinterpret_cast<float4*>(sx+4);
    for (int i=tid; i<750; i+=512) sx4[i] = xg4[i];
    if (tid<4)  sx[tid]=0.f;
    if (tid<8)  sx[3004+tid]=0.f;
    if (tid<32) s1t[tid]=0.f;                  // pos=-2,-1 pad rows
    if (tid<112) w1s[tid]=w1g[tid];
    const float rs = rsqrtf(1.f+1e-5f);
    if (tid<16){ float s=bg1[tid]*rs; kb1[2*tid]=s; kb1[2*tid+1]=c1b[tid]*s+bb1[tid]; }
    if (tid<32){ float s=bg2[tid]*rs; kb2[2*tid]=s; kb2[2*tid+1]=c2b[tid]*s+bb2[tid]; }
    if (tid<64){ float s=bg3[tid]*rs; kb3[2*tid]=s; kb3[2*tid+1]=c3b[tid]*s+bb3[tid]; }
  }
  __syncthreads();

  // Phase A: conv1+bn+relu+pool -> s1t[pos+2][c], 16ch x 500
  {
    const int c = tid & 15;
    const float s = kb1[2*c], o = kb1[2*c+1];
    float wr[7];
    #pragma unroll
    for (int k=0;k<7;k++) wr[k] = w1s[c*7+k];
    for (int u = tid>>4; u<500; u+=32){
      const float* xb = sx + 6*u + 1;
      float xv[11];
      #pragma unroll
      for (int r=0;r<11;r++) xv[r] = xb[r];
      float a0=0.f,a1=0.f,a2=0.f;
      #pragma unroll
      for (int k=0;k<7;k++){ float w=wr[k]; a0 += xv[k]*w; a1 += xv[k+2]*w; a2 += xv[k+4]*w; }
      float y = fmaxf(fmaxf(a0*s+o, a1*s+o), a2*s+o);
      s1t[(u+2)*16 + c] = fmaxf(y, 0.f);
    }
  }
  __syncthreads();

  for (int i=tid;i<2560;i+=512) w2s[(i/80)*81 + (i%80)] = w2g[i];
  if (tid<32){ s2t[tid]=0.f; s2t[84*32+tid]=0.f; }
  __syncthreads();

  // Phase B: conv2+bn+relu+pool -> s2t[pos+1][oc], 32ch x 83
  {
    const int oc = tid & 31, ug = tid >> 5;   // ug 0..15
    float wreg[80];
    #pragma unroll
    for (int i=0;i<80;i++) wreg[i] = w2s[oc*81+i];   // stride 81: conflict-free
    const float s=kb2[2*oc], o=kb2[2*oc+1];
    for (int u=ug; u<83; u+=16){
      float acc0=0.f, acc1=0.f, acc2=0.f;
      #pragma unroll
      for (int rp=0; rp<9; ++rp){
        const float4* row = reinterpret_cast<const float4*>(s1t + (6*u+rp)*16);
        const float4 v0=row[0], v1=row[1], v2=row[2], v3=row[3];
        #pragma unroll
        for (int tp=0; tp<3; ++tp){
          const int k = rp - 2*tp;
          if (k>=0 && k<5){
            float ssum =
                v0.x*wreg[ 0+k] + v0.y*wreg[ 5+k] + v0.z*wreg[10+k] + v0.w*wreg[15+k]
              + v1.x*wreg[20+k] + v1.y*wreg[25+k] + v1.z*wreg[30+k] + v1.w*wreg[35+k]
              + v2.x*wreg[40+k] + v2.y*wreg[45+k] + v2.z*wreg[50+k] + v2.w*wreg[55+k]
              + v3.x*wreg[60+k] + v3.y*wreg[65+k] + v3.z*wreg[70+k] + v3.w*wreg[75+k];
            if (tp==0) acc0 += ssum; else if (tp==1) acc1 += ssum; else acc2 += ssum;
          }
        }
      }
      float y = fmaxf(fmaxf(acc0*s+o, acc1*s+o), acc2*s+o);
      s2t[(u+1)*32 + oc] = fmaxf(y, 0.f);
    }
  }
  __syncthreads();
  for (int i=tid;i<6144;i+=512) w3s[(i/96)*97 + (i%96)] = w3g[i];
  __syncthreads();

  // Phase C: conv3+bn+relu+mean -> feats[sig][64]
  {
    const int oc = tid & 63;
    float w3r[96];
    #pragma unroll
    for (int i=0;i<96;i++) w3r[i] = w3s[oc*97+i];    // stride 97: conflict-free
    const float s=kb3[2*oc], o=kb3[2*oc+1];
    float acc = 0.f;
    for (int t=(tid>>6); t<83; t+=8){
      float cs = 0.f;
      #pragma unroll
      for (int k=0;k<3;k++){
        const float4* row = reinterpret_cast<const float4*>(s2t + (t+k)*32);
        #pragma unroll
        for (int q=0;q<8;q++){
          float4 v = row[q];
          cs += v.x*w3r[(4*q+0)*3+k] + v.y*w3r[(4*q+1)*3+k]
              + v.z*w3r[(4*q+2)*3+k] + v.w*w3r[(4*q+3)*3+k];
        }
      }
      acc += fmaxf(cs*s+o, 0.f);
    }
    red[tid] = acc;
  }
  __syncthreads();
  if (tid<64){
    float r = red[tid]     + red[tid+64]  + red[tid+128] + red[tid+192]
            + red[tid+256] + red[tid+320] + red[tid+384] + red[tid+448];
    feats[sig*64 + tid] = r * (1.f/83.f);
  }
}

// ---------------------------------------------------------------------------
// K2: build normalized adjacency An (8x8) from edge_index (2,56)
// ---------------------------------------------------------------------------
__global__ void k_an(const int* __restrict__ ei, float* __restrict__ an){
  __shared__ float A[64];
  __shared__ float dinv[8];
  const int tid = threadIdx.x;
  if (tid<64) A[tid] = ((tid>>3)==(tid&7)) ? 1.f : 0.f;
  __syncthreads();
  if (tid==0){
    for (int e=0;e<56;e++){ int s=ei[e], d=ei[56+e]; A[d*8+s] += 1.f; }
  }
  __syncthreads();
  if (tid<8){ float s=0.f; for (int j=0;j<8;j++) s+=A[tid*8+j]; dinv[tid]=rsqrtf(s); }
  __syncthreads();
  if (tid<64) an[tid] = A[tid]*dinv[tid>>3]*dinv[tid&7];
}

// ---------------------------------------------------------------------------
// Generic f32 GEMM: C[M,N] = X[M,K] @ W[N,K]^T (+b1 +b2). Tile 128x64, BK=8.
// M%128==0, N%64==0, K%8==0.
// ---------------------------------------------------------------------------
__global__ __launch_bounds__(256) void k_gemm_nt(
  const float* __restrict__ X, const float* __restrict__ W,
  const float* __restrict__ b1, const float* __restrict__ b2,
  float* __restrict__ C, int M, int N, int K)
{
  __shared__ float Xs[8][132];
  __shared__ float Ws[8][68];
  const int tid = threadIdx.x;
  const int m0 = blockIdx.y*128, n0 = blockIdx.x*64;
  const int tm = tid >> 4, tn = tid & 15;
  float acc[8][4] = {};
  const int xr = tid >> 1,          xk = (tid & 1)*4;
  const int wr = (tid & 127) >> 1,  wk = (tid & 1)*4;

  for (int k0=0; k0<K; k0+=8){
    float4 xa = *reinterpret_cast<const float4*>(X + (long)(m0+xr)*K + k0 + xk);
    float4 wa = make_float4(0,0,0,0);
    if (tid<128) wa = *reinterpret_cast<const float4*>(W + (long)(n0+wr)*K + k0 + wk);
    __syncthreads();
    Xs[xk+0][xr]=xa.x; Xs[xk+1][xr]=xa.y; Xs[xk+2][xr]=xa.z; Xs[xk+3][xr]=xa.w;
    if (tid<128){ Ws[wk+0][wr]=wa.x; Ws[wk+1][wr]=wa.y; Ws[wk+2][wr]=wa.z; Ws[wk+3][wr]=wa.w; }
    __syncthreads();
    #pragma unroll
    for (int kk=0;kk<8;kk++){
      float4 a0 = *reinterpret_cast<const float4*>(&Xs[kk][tm*8]);
      float4 a1 = *reinterpret_cast<const float4*>(&Xs[kk][tm*8+4]);
      float4 b  = *reinterpret_cast<const float4*>(&Ws[kk][tn*4]);
      float av[8] = {a0.x,a0.y,a0.z,a0.w,a1.x,a1.y,a1.z,a1.w};
      float bv[4] = {b.x,b.y,b.z,b.w};
      #pragma unroll
      for (int i=0;i<8;i++)
        #pragma unroll
        for (int j=0;j<4;j++) acc[i][j] += av[i]*bv[j];
    }
  }
  float bias[4] = {0.f,0.f,0.f,0.f};
  if (b1){ float4 t = *reinterpret_cast<const float4*>(b1 + n0 + tn*4);
           bias[0]+=t.x; bias[1]+=t.y; bias[2]+=t.z; bias[3]+=t.w; }
  if (b2){ float4 t = *reinterpret_cast<const float4*>(b2 + n0 + tn*4);
           bias[0]+=t.x; bias[1]+=t.y; bias[2]+=t.z; bias[3]+=t.w; }
  #pragma unroll
  for (int i=0;i<8;i++){
    const long m = m0 + tm*8 + i;
    float4 o;
    o.x = acc[i][0]+bias[0]; o.y = acc[i][1]+bias[1];
    o.z = acc[i][2]+bias[2]; o.w = acc[i][3]+bias[3];
    *reinterpret_cast<float4*>(C + m*N + n0 + tn*4) = o;
  }
}

// ---------------------------------------------------------------------------
// K4: g1[g][i][j] = relu( sum_c An[i][c]*tmp0[g][c][j] + b0[j] )
// ---------------------------------------------------------------------------
__global__ __launch_bounds__(256) void k_mix1(
  const float* __restrict__ tmp0, const float* __restrict__ An,
  const float* __restrict__ b0, float* __restrict__ g1)
{
  __shared__ float ans[64];
  if (threadIdx.x < 64) ans[threadIdx.x] = An[threadIdx.x];
  __syncthreads();
  const long idx = (long)blockIdx.x*256 + threadIdx.x;   // over 1280*128
  const int g = (int)(idx >> 7), j = (int)(idx & 127);
  const float* base = tmp0 + (long)g*1024;
  float t[8];
  #pragma unroll
  for (int c=0;c<8;c++) t[c] = base[c*128+j];
  const float bj = b0[j];
  #pragma unroll
  for (int i=0;i<8;i++){
    float s = bj;
    #pragma unroll
    for (int c=0;c<8;c++) s += ans[i*8+c]*t[c];
    g1[(long)g*1024 + i*128 + j] = fmaxf(s, 0.f);
  }
}

// ---------------------------------------------------------------------------
// K6: g2 = An@tmp1 + b1 ; LN over j (128) per row ; mean over 8 nodes -> emb
// ---------------------------------------------------------------------------
__global__ __launch_bounds__(128) void k_mix2(
  const float* __restrict__ tmp1, const float* __restrict__ An,
  const float* __restrict__ b1, const float* __restrict__ lng,
  const float* __restrict__ lnb, float* __restrict__ emb)
{
  const int g = blockIdx.x, j = threadIdx.x;
  __shared__ float ans[64];
  __shared__ float g2s[8*128];
  __shared__ float stats[16];
  if (j<64) ans[j] = An[j];
  const float* base = tmp1 + (long)g*1024;
  float t[8];
  #pragma unroll
  for (int c=0;c<8;c++) t[c] = base[c*128 + j];
  const float bj = b1[j];
  __syncthreads();
  #pragma unroll
  for (int i=0;i<8;i++){
    float s = bj;
    #pragma unroll
    for (int c=0;c<8;c++) s += ans[i*8+c]*t[c];
    g2s[i*128+j] = s;
  }
  __syncthreads();
  {
    const int c = j>>4, l = j&15;
    float s=0.f, sq=0.f;
    for (int jj=l; jj<128; jj+=16){ float v=g2s[c*128+jj]; s+=v; sq+=v*v; }
    #pragma unroll
    for (int off=8; off>=1; off>>=1){ s += __shfl_xor(s, off); sq += __shfl_xor(sq, off); }
    if (l==0){
      float m = s*(1.f/128.f);
      stats[2*c] = m;
      stats[2*c+1] = rsqrtf(sq*(1.f/128.f) - m*m + 1e-5f);
    }
  }
  __syncthreads();
  float acc=0.f;
  #pragma unroll
  for (int i=0;i<8;i++) acc += (g2s[i*128+j] - stats[2*i]) * stats[2*i+1];
  emb[(long)g*128 + j] = lng[j]*acc*0.125f + lnb[j];
}

// ---------------------------------------------------------------------------
// K7b: transpose w_hh (1024,256) f32 -> wt (256,1024) bf16
// ---------------------------------------------------------------------------
__global__ __launch_bounds__(256) void k_tr(
  const float* __restrict__ in, unsigned short* __restrict__ out)
{
  const int i = blockIdx.x*256 + threadIdx.x;   // 262144
  const int g = i & 1023, j = i >> 10;
  out[i] = f2bf(in[g*256 + j]);
}

// ---------------------------------------------------------------------------
// K8: one LSTM layer, both directions. Block = (batch, dir). h,c block-local.
// ---------------------------------------------------------------------------
__global__ __launch_bounds__(256) void k_lstm(
    const float* __restrict__ xsf, const float* __restrict__ xsr,
    const unsigned short* __restrict__ wtf, const unsigned short* __restrict__ wtr,
    float* __restrict__ out)
{
  const int S = 20;
  const int b = blockIdx.x >> 1, dir = blockIdx.x & 1;
  const float* xs = dir ? xsr : xsf;
  const unsigned short* wt = dir ? wtr : wtf;
  __shared__ float hs[256];
  __shared__ float gs[1024];
  const int tid = threadIdx.x;
  const int grow = (tid>>6)*256 + (tid&63)*4;
  hs[tid] = 0.f;
  float cc = 0.f;
  __syncthreads();
  for (int st=0; st<S; ++st){
    const int t = dir ? (S-1-st) : st;
    const float* xrow = xs + ((long)b*S + t)*1024;
    float4 a = *reinterpret_cast<const float4*>(xrow + grow);
    float acc0=a.x, acc1=a.y, acc2=a.z, acc3=a.w;
    #pragma unroll 4
    for (int j=0;j<256;++j){
      const float hv = hs[j];
      ushort4 w = *reinterpret_cast<const ushort4*>(wt + (long)j*1024 + grow);
      acc0 += hv*bf2f(w.x);
      acc1 += hv*bf2f(w.y);
      acc2 += hv*bf2f(w.z);
      acc3 += hv*bf2f(w.w);
    }
    gs[grow+0]=acc0; gs[grow+1]=acc1; gs[grow+2]=acc2; gs[grow+3]=acc3;
    __syncthreads();
    const float gi = gs[tid], gf = gs[256+tid], gg = gs[512+tid], go = gs[768+tid];
    cc = sigf(gf)*cc + sigf(gi)*tanhf(gg);
    const float h = sigf(go)*tanhf(cc);
    hs[tid] = h;
    out[((long)b*S + t)*512 + dir*256 + tid] = h;
    __syncthreads();
  }
}

// ---------------------------------------------------------------------------
// K11: final LayerNorm(512) + classifier (5) per row
// ---------------------------------------------------------------------------
__global__ __launch_bounds__(128) void k_lncls(
  const float* __restrict__ in, const float* __restrict__ g,
  const float* __restrict__ b, const float* __restrict__ cw,
  const float* __restrict__ cb, float* __restrict__ out)
{
  const int row = blockIdx.x, tid = threadIdx.x;
  __shared__ float sred[4];
  __shared__ float cred[2][5];
  float4 v = *reinterpret_cast<const float4*>(in + (long)row*512 + tid*4);
  float s  = v.x+v.y+v.z+v.w;
  float sq = v.x*v.x+v.y*v.y+v.z*v.z+v.w*v.w;
  #pragma unroll
  for (int off=32; off>=1; off>>=1){ s += __shfl_xor(s, off); sq += __shfl_xor(sq, off); }
  const int wv = tid>>6;
  if ((tid&63)==0){ sred[wv*2]=s; sred[wv*2+1]=sq; }
  __syncthreads();
  const float S = sred[0]+sred[2], SQ = sred[1]+sred[3];
  const float m = S*(1.f/512.f);
  const float rstd = rsqrtf(SQ*(1.f/512.f) - m*m + 1e-5f);
  float4 gg = *reinterpret_cast<const float4*>(g + tid*4);
  float4 bb = *reinterpret_cast<const float4*>(b + tid*4);
  const float n0 = (v.x-m)*rstd*gg.x + bb.x;
  const float n1 = (v.y-m)*rstd*gg.y + bb.y;
  const float n2 = (v.z-m)*rstd*gg.z + bb.z;
  const float n3 = (v.w-m)*rstd*gg.w + bb.w;
  #pragma unroll
  for (int nc=0; nc<5; ++nc){
    float4 w = *reinterpret_cast<const float4*>(cw + nc*512 + tid*4);
    float p = n0*w.x + n1*w.y + n2*w.z + n3*w.w;
    #pragma unroll
    for (int off=32; off>=1; off>>=1) p += __shfl_xor(p, off);
    if ((tid&63)==0) cred[wv][nc] = p;
  }
  __syncthreads();
  if (tid < 5) out[(long)row*5 + tid] = cred[0][tid] + cred[1][tid] + cb[tid];
}

// ---------------------------------------------------------------------------
extern "C" void kernel_launch(void* const* d_in, const int* in_sizes, int n_in,
                              void* d_out, int out_size, void* d_ws, size_t ws_size,
                              hipStream_t stream)
{
  const float* x     = (const float*)d_in[0];
  const int*   ei    = (const int*)d_in[1];
  const float* w1    = (const float*)d_in[2];
  const float* c1b   = (const float*)d_in[3];
  const float* bg1   = (const float*)d_in[4];
  const float* bb1   = (const float*)d_in[5];
  const float* w2    = (const float*)d_in[6];
  const float* c2b   = (const float*)d_in[7];
  const float* bg2   = (const float*)d_in[8];
  const float* bb2   = (const float*)d_in[9];
  const float* w3    = (const float*)d_in[10];
  const float* c3b   = (const float*)d_in[11];
  const float* bg3   = (const float*)d_in[12];
  const float* bb3   = (const float*)d_in[13];
  const float* gcn0w = (const float*)d_in[14];
  const float* gcn0b = (const float*)d_in[15];
  const float* gcn1w = (const float*)d_in[16];
  const float* gcn1b = (const float*)d_in[17];
  const float* lng   = (const float*)d_in[18];
  const float* lnb   = (const float*)d_in[19];
  const float* wih0  = (const float*)d_in[20];
  const float* whh0  = (const float*)d_in[21];
  const float* bih0  = (const float*)d_in[22];
  const float* bhh0  = (const float*)d_in[23];
  const float* wih0r = (const float*)d_in[24];
  const float* whh0r = (const float*)d_in[25];
  const float* bih0r = (const float*)d_in[26];
  const float* bhh0r = (const float*)d_in[27];
  const float* wih1  = (const float*)d_in[28];
  const float* whh1  = (const float*)d_in[29];
  const float* bih1  = (const float*)d_in[30];
  const float* bhh1  = (const float*)d_in[31];
  const float* wih1r = (const float*)d_in[32];
  const float* whh1r = (const float*)d_in[33];
  const float* bih1r = (const float*)d_in[34];
  const float* bhh1r = (const float*)d_in[35];
  const float* lstmg = (const float*)d_in[36];
  const float* lstmb = (const float*)d_in[37];
  const float* clsw  = (const float*)d_in[38];
  const float* clsb  = (const float*)d_in[39];
  float* ws  = (float*)d_ws;
  float* out = (float*)d_out;

  // workspace layout (floats); total 7,897,344 floats = 31.6 MB
  float* An    = ws + 0;
  float* feats = ws + 256;
  float* tmp   = ws + 655616;    // tmp0 and tmp1 (aliased)
  float* g1b   = ws + 1966336;
  float* emb   = ws + 3277056;
  float* xsf   = ws + 3440896;   // reused for layer1
  float* xsr   = ws + 4751616;
  float* l0    = ws + 6062336;
  float* l1    = ws + 6717696;
  unsigned short* wt0f = (unsigned short*)(ws + 7373056);
  unsigned short* wt0r = (unsigned short*)(ws + 7504128);
  unsigned short* wt1f = (unsigned short*)(ws + 7635200);
  unsigned short* wt1r = (unsigned short*)(ws + 7766272);

  // Stage 1: conv front-end
  k_conv<<<10240, 512, 0, stream>>>(x, w1,c1b,bg1,bb1, w2,c2b,bg2,bb2,
                                    w3,c3b,bg3,bb3, feats);
  // Adjacency + weight transposes (independent of k_conv output)
  k_an<<<1, 64, 0, stream>>>(ei, An);
  k_tr<<<1024,256,0,stream>>>(whh0,  wt0f);
  k_tr<<<1024,256,0,stream>>>(whh0r, wt0r);
  k_tr<<<1024,256,0,stream>>>(whh1,  wt1f);
  k_tr<<<1024,256,0,stream>>>(whh1r, wt1r);

  // Stage 2: GCN
  k_gemm_nt<<<dim3(2, 80), 256, 0, stream>>>(feats, gcn0w, nullptr, nullptr, tmp, 10240, 128, 64);
  k_mix1<<<640,256,0,stream>>>(tmp, An, gcn0b, g1b);
  k_gemm_nt<<<dim3(2, 80), 256, 0, stream>>>(g1b, gcn1w, nullptr, nullptr, tmp, 10240, 128, 128);
  k_mix2<<<1280,128,0,stream>>>(tmp, An, gcn1b, lng, lnb, emb);

  // Stage 3: BiLSTM layer 0
  k_gemm_nt<<<dim3(16, 10), 256, 0, stream>>>(emb, wih0,  bih0,  bhh0,  xsf, 1280, 1024, 128);
  k_gemm_nt<<<dim3(16, 10), 256, 0, stream>>>(emb, wih0r, bih0r, bhh0r, xsr, 1280, 1024, 128);
  k_lstm<<<128, 256, 0, stream>>>(xsf, xsr, wt0f, wt0r, l0);

  // BiLSTM layer 1
  k_gemm_nt<<<dim3(16, 10), 256, 0, stream>>>(l0, wih1,  bih1,  bhh1,  xsf, 1280, 1024, 512);
  k_gemm_nt<<<dim3(16, 10), 256, 0, stream>>>(l0, wih1r, bih1r, bhh1r, xsr, 1280, 1024, 512);
  k_lstm<<<128, 256, 0, stream>>>(xsf, xsr, wt1f, wt1r, l1);

  // Stage 4: LN + classifier
  k_lncls<<<1280, 128, 0, stream>>>(l1, lstmg, lstmb, clsw, clsb, out);
}

// Round 3
// 944.056 us; speedup vs baseline: 1.5164x; 1.5164x over previous
//
#include <hip/hip_runtime.h>
#include <hip/hip_bf16.h>

#define DEVI __device__ __forceinline__

typedef _Float16 h2f16 __attribute__((ext_vector_type(2)));
union F4H { float4 f; h2f16 h[4]; };

DEVI float bf2f(unsigned short u){ return __uint_as_float(((unsigned int)u)<<16); }
DEVI unsigned short f2bf(float f){
  unsigned int u = __float_as_uint(f);
  unsigned int r = (u + 0x7fffu + ((u>>16)&1u)) >> 16;
  return (unsigned short)r;
}
DEVI float sigf(float x){ return 1.f/(1.f + __expf(-x)); }

// ---------------------------------------------------------------------------
// K1: fused conv front-end. One block per signal (B*S*C = 10240 signals).
// conv1(k7,s2,p3)+BN+ReLU+pool3 -> conv2(k5,s2,p2)+BN+ReLU+pool3 ->
// conv3(k3,s1,p1)+BN+ReLU -> mean(83) => feats[sig][64]
// f16 intermediates + v_dot2_f32_f16; ~35.5KB LDS -> 4 blocks/CU (16 waves).
// ---------------------------------------------------------------------------
__global__ __launch_bounds__(256,4) void k_conv(
    const float* __restrict__ x,
    const float* __restrict__ w1g, const float* __restrict__ c1b,
    const float* __restrict__ bg1, const float* __restrict__ bb1,
    const float* __restrict__ w2g, const float* __restrict__ c2b,
    const float* __restrict__ bg2, const float* __restrict__ bb2,
    const float* __restrict__ w3g, const float* __restrict__ c3b,
    const float* __restrict__ bg3, const float* __restrict__ bb3,
    float* __restrict__ feats)
{
  // byte pool:
  //   s1t (half) [504][16]              : [0, 16128)
  //   s2t (half) [85][32]               : [16128, 21568)
  //   region (phase-aliased) at 21568:
  //     A: sx (float) 3012              : [21568, 33616)
  //     B: w2s (h2f16) [32][41+1(pad)]  : [21568, 21568+32*41*4=26816)
  //     C: w3s (h2f16) [64][49]         : [21568, 21568+64*49*4=34112)
  //   red (float)[256] aliases s1t base : [0, 1024)
  __shared__ __align__(16) unsigned char smb[34112];
  __shared__ float w1s[112];
  __shared__ float kb1[32], kb2[64], kb3[128];
  _Float16* s1t = reinterpret_cast<_Float16*>(smb);
  _Float16* s2t = reinterpret_cast<_Float16*>(smb + 16128);
  float*    sx  = reinterpret_cast<float*>(smb + 21568);
  h2f16*    w2s = reinterpret_cast<h2f16*>(smb + 21568);
  h2f16*    w3s = reinterpret_cast<h2f16*>(smb + 21568);
  float*    red = reinterpret_cast<float*>(smb);
  const int tid = threadIdx.x;
  const long sig = blockIdx.x;
  const float* xg = x + sig*3000;

  // stage x (float4) + pads + conv1 weights + folded BN consts
  {
    const float4* xg4 = reinterpret_cast<const float4*>(xg);
    float4* sx4 = reinterpret_cast<float4*>(sx+4);
    for (int i=tid; i<750; i+=256) sx4[i] = xg4[i];
    if (tid<4)  sx[tid]=0.f;
    if (tid<8)  sx[3004+tid]=0.f;
    if (tid<32) s1t[tid]=(_Float16)0.f;        // pos=-2,-1 pad rows
    if (tid<112) w1s[tid]=w1g[tid];
    const float rs = rsqrtf(1.f+1e-5f);
    if (tid<16){ float s=bg1[tid]*rs; kb1[2*tid]=s; kb1[2*tid+1]=c1b[tid]*s+bb1[tid]; }
    if (tid<32){ float s=bg2[tid]*rs; kb2[2*tid]=s; kb2[2*tid+1]=c2b[tid]*s+bb2[tid]; }
    if (tid<64){ float s=bg3[tid]*rs; kb3[2*tid]=s; kb3[2*tid+1]=c3b[tid]*s+bb3[tid]; }
  }
  __syncthreads();

  // Phase A: conv1+bn+relu+pool -> s1t[pos+2][c] (f16), 16ch x 500
  {
    const int c = tid & 15;
    const float s = kb1[2*c], o = kb1[2*c+1];
    float wr[7];
    #pragma unroll
    for (int k=0;k<7;k++) wr[k] = w1s[c*7+k];
    for (int u = tid>>4; u<500; u+=16){
      const float* xb = sx + 6*u + 1;
      float xv[11];
      #pragma unroll
      for (int r=0;r<11;r++) xv[r] = xb[r];
      float a0=0.f,a1=0.f,a2=0.f;
      #pragma unroll
      for (int k=0;k<7;k++){ float w=wr[k]; a0 += xv[k]*w; a1 += xv[k+2]*w; a2 += xv[k+4]*w; }
      float y = fmaxf(fmaxf(a0*s+o, a1*s+o), a2*s+o);
      s1t[(u+2)*16 + c] = (_Float16)fmaxf(y, 0.f);
    }
  }
  __syncthreads();

  // stage w2 packed pairs: w2s[oc*41 + k*8 + j] = (w2[oc][2j][k], w2[oc][2j+1][k])
  for (int i=tid; i<1280; i+=256){
    const int oc = i/40, rem = i - oc*40, k = rem>>3, j = rem&7;
    h2f16 p;
    p[0] = (_Float16)w2g[oc*80 + (2*j)*5 + k];
    p[1] = (_Float16)w2g[oc*80 + (2*j+1)*5 + k];
    w2s[oc*41 + k*8 + j] = p;
  }
  if (tid<32){ s2t[tid]=(_Float16)0.f; s2t[84*32+tid]=(_Float16)0.f; }
  __syncthreads();

  // Phase B: conv2+bn+relu+pool -> s2t[pos+1][oc] (f16), 32ch x 83
  {
    const int oc = tid & 31, ug = tid >> 5;   // ug 0..7
    h2f16 w2r[40];
    #pragma unroll
    for (int i=0;i<40;i++) w2r[i] = w2s[oc*41 + i];
    const float s=kb2[2*oc], o=kb2[2*oc+1];
    for (int u=ug; u<83; u+=8){
      float acc0=0.f, acc1=0.f, acc2=0.f;
      #pragma unroll
      for (int rp=0; rp<9; ++rp){
        const float4* rowp = reinterpret_cast<const float4*>(s1t + (6*u+rp)*16);
        F4H ra, rb; ra.f = rowp[0]; rb.f = rowp[1];
        const h2f16 h0=ra.h[0],h1=ra.h[1],h2=ra.h[2],h3=ra.h[3];
        const h2f16 h4=rb.h[0],h5=rb.h[1],h6=rb.h[2],h7=rb.h[3];
        #pragma unroll
        for (int tp=0; tp<3; ++tp){
          const int k = rp - 2*tp;
          if (k>=0 && k<5){
            const h2f16* wk = w2r + k*8;
            float a = (tp==0)?acc0:(tp==1)?acc1:acc2;
            a = __builtin_amdgcn_fdot2(h0, wk[0], a, false);
            a = __builtin_amdgcn_fdot2(h1, wk[1], a, false);
            a = __builtin_amdgcn_fdot2(h2, wk[2], a, false);
            a = __builtin_amdgcn_fdot2(h3, wk[3], a, false);
            a = __builtin_amdgcn_fdot2(h4, wk[4], a, false);
            a = __builtin_amdgcn_fdot2(h5, wk[5], a, false);
            a = __builtin_amdgcn_fdot2(h6, wk[6], a, false);
            a = __builtin_amdgcn_fdot2(h7, wk[7], a, false);
            if (tp==0) acc0=a; else if (tp==1) acc1=a; else acc2=a;
          }
        }
      }
      float y = fmaxf(fmaxf(acc0*s+o, acc1*s+o), acc2*s+o);
      s2t[(u+1)*32 + oc] = (_Float16)fmaxf(y, 0.f);
    }
  }
  __syncthreads();
  // stage w3 packed pairs: w3s[oc*49 + k*16 + j] = (w3[oc][2j][k], w3[oc][2j+1][k])
  for (int i=tid; i<3072; i+=256){
    const int oc = i/48, rem = i - oc*48, k = rem>>4, j = rem&15;
    h2f16 p;
    p[0] = (_Float16)w3g[oc*96 + 6*j + k];
    p[1] = (_Float16)w3g[oc*96 + 6*j + 3 + k];
    w3s[oc*49 + k*16 + j] = p;
  }
  __syncthreads();

  // Phase C: conv3+bn+relu+mean -> feats[sig][64]
  {
    const int oc = tid & 63;
    h2f16 w3r[48];
    #pragma unroll
    for (int i=0;i<48;i++) w3r[i] = w3s[oc*49 + i];
    const float s=kb3[2*oc], o=kb3[2*oc+1];
    float acc = 0.f;
    for (int t=(tid>>6); t<83; t+=4){
      float cs = 0.f;
      #pragma unroll
      for (int k=0;k<3;k++){
        const float4* rowp = reinterpret_cast<const float4*>(s2t + (t+k)*32);
        #pragma unroll
        for (int q=0;q<4;q++){
          F4H r; r.f = rowp[q];
          cs = __builtin_amdgcn_fdot2(r.h[0], w3r[k*16 + q*4 + 0], cs, false);
          cs = __builtin_amdgcn_fdot2(r.h[1], w3r[k*16 + q*4 + 1], cs, false);
          cs = __builtin_amdgcn_fdot2(r.h[2], w3r[k*16 + q*4 + 2], cs, false);
          cs = __builtin_amdgcn_fdot2(r.h[3], w3r[k*16 + q*4 + 3], cs, false);
        }
      }
      acc += fmaxf(cs*s+o, 0.f);
    }
    red[tid] = acc;
  }
  __syncthreads();
  if (tid<64){
    float r = red[tid]+red[tid+64]+red[tid+128]+red[tid+192];
    feats[sig*64 + tid] = r * (1.f/83.f);
  }
}

// ---------------------------------------------------------------------------
// K2: build normalized adjacency An (8x8) from edge_index (2,56)
// ---------------------------------------------------------------------------
__global__ void k_an(const int* __restrict__ ei, float* __restrict__ an){
  __shared__ float A[64];
  __shared__ float dinv[8];
  const int tid = threadIdx.x;
  if (tid<64) A[tid] = ((tid>>3)==(tid&7)) ? 1.f : 0.f;
  __syncthreads();
  if (tid==0){
    for (int e=0;e<56;e++){ int s=ei[e], d=ei[56+e]; A[d*8+s] += 1.f; }
  }
  __syncthreads();
  if (tid<8){ float s=0.f; for (int j=0;j<8;j++) s+=A[tid*8+j]; dinv[tid]=rsqrtf(s); }
  __syncthreads();
  if (tid<64) an[tid] = A[tid]*dinv[tid>>3]*dinv[tid&7];
}

// ---------------------------------------------------------------------------
// Generic f32 GEMM: C[M,N] = X[M,K] @ W[N,K]^T (+b1 +b2). Tile 128x64, BK=8.
// ---------------------------------------------------------------------------
__global__ __launch_bounds__(256) void k_gemm_nt(
  const float* __restrict__ X, const float* __restrict__ W,
  const float* __restrict__ b1, const float* __restrict__ b2,
  float* __restrict__ C, int M, int N, int K)
{
  __shared__ float Xs[8][132];
  __shared__ float Ws[8][68];
  const int tid = threadIdx.x;
  const int m0 = blockIdx.y*128, n0 = blockIdx.x*64;
  const int tm = tid >> 4, tn = tid & 15;
  float acc[8][4] = {};
  const int xr = tid >> 1,          xk = (tid & 1)*4;
  const int wr = (tid & 127) >> 1,  wk = (tid & 1)*4;

  for (int k0=0; k0<K; k0+=8){
    float4 xa = *reinterpret_cast<const float4*>(X + (long)(m0+xr)*K + k0 + xk);
    float4 wa = make_float4(0,0,0,0);
    if (tid<128) wa = *reinterpret_cast<const float4*>(W + (long)(n0+wr)*K + k0 + wk);
    __syncthreads();
    Xs[xk+0][xr]=xa.x; Xs[xk+1][xr]=xa.y; Xs[xk+2][xr]=xa.z; Xs[xk+3][xr]=xa.w;
    if (tid<128){ Ws[wk+0][wr]=wa.x; Ws[wk+1][wr]=wa.y; Ws[wk+2][wr]=wa.z; Ws[wk+3][wr]=wa.w; }
    __syncthreads();
    #pragma unroll
    for (int kk=0;kk<8;kk++){
      float4 a0 = *reinterpret_cast<const float4*>(&Xs[kk][tm*8]);
      float4 a1 = *reinterpret_cast<const float4*>(&Xs[kk][tm*8+4]);
      float4 b  = *reinterpret_cast<const float4*>(&Ws[kk][tn*4]);
      float av[8] = {a0.x,a0.y,a0.z,a0.w,a1.x,a1.y,a1.z,a1.w};
      float bv[4] = {b.x,b.y,b.z,b.w};
      #pragma unroll
      for (int i=0;i<8;i++)
        #pragma unroll
        for (int j=0;j<4;j++) acc[i][j] += av[i]*bv[j];
    }
  }
  float bias[4] = {0.f,0.f,0.f,0.f};
  if (b1){ float4 t = *reinterpret_cast<const float4*>(b1 + n0 + tn*4);
           bias[0]+=t.x; bias[1]+=t.y; bias[2]+=t.z; bias[3]+=t.w; }
  if (b2){ float4 t = *reinterpret_cast<const float4*>(b2 + n0 + tn*4);
           bias[0]+=t.x; bias[1]+=t.y; bias[2]+=t.z; bias[3]+=t.w; }
  #pragma unroll
  for (int i=0;i<8;i++){
    const long m = m0 + tm*8 + i;
    float4 o;
    o.x = acc[i][0]+bias[0]; o.y = acc[i][1]+bias[1];
    o.z = acc[i][2]+bias[2]; o.w = acc[i][3]+bias[3];
    *reinterpret_cast<float4*>(C + m*N + n0 + tn*4) = o;
  }
}

// ---------------------------------------------------------------------------
// K4: g1[g][i][j] = relu( sum_c An[i][c]*tmp0[g][c][j] + b0[j] )
// ---------------------------------------------------------------------------
__global__ __launch_bounds__(256) void k_mix1(
  const float* __restrict__ tmp0, const float* __restrict__ An,
  const float* __restrict__ b0, float* __restrict__ g1)
{
  __shared__ float ans[64];
  if (threadIdx.x < 64) ans[threadIdx.x] = An[threadIdx.x];
  __syncthreads();
  const long idx = (long)blockIdx.x*256 + threadIdx.x;   // over 1280*128
  const int g = (int)(idx >> 7), j = (int)(idx & 127);
  const float* base = tmp0 + (long)g*1024;
  float t[8];
  #pragma unroll
  for (int c=0;c<8;c++) t[c] = base[c*128+j];
  const float bj = b0[j];
  #pragma unroll
  for (int i=0;i<8;i++){
    float s = bj;
    #pragma unroll
    for (int c=0;c<8;c++) s += ans[i*8+c]*t[c];
    g1[(long)g*1024 + i*128 + j] = fmaxf(s, 0.f);
  }
}

// ---------------------------------------------------------------------------
// K6: g2 = An@tmp1 + b1 ; LN over j (128) per row ; mean over 8 nodes -> emb
// ---------------------------------------------------------------------------
__global__ __launch_bounds__(128) void k_mix2(
  const float* __restrict__ tmp1, const float* __restrict__ An,
  const float* __restrict__ b1, const float* __restrict__ lng,
  const float* __restrict__ lnb, float* __restrict__ emb)
{
  const int g = blockIdx.x, j = threadIdx.x;
  __shared__ float ans[64];
  __shared__ float g2s[8*128];
  __shared__ float stats[16];
  if (j<64) ans[j] = An[j];
  const float* base = tmp1 + (long)g*1024;
  float t[8];
  #pragma unroll
  for (int c=0;c<8;c++) t[c] = base[c*128 + j];
  const float bj = b1[j];
  __syncthreads();
  #pragma unroll
  for (int i=0;i<8;i++){
    float s = bj;
    #pragma unroll
    for (int c=0;c<8;c++) s += ans[i*8+c]*t[c];
    g2s[i*128+j] = s;
  }
  __syncthreads();
  {
    const int c = j>>4, l = j&15;
    float s=0.f, sq=0.f;
    for (int jj=l; jj<128; jj+=16){ float v=g2s[c*128+jj]; s+=v; sq+=v*v; }
    #pragma unroll
    for (int off=8; off>=1; off>>=1){ s += __shfl_xor(s, off); sq += __shfl_xor(sq, off); }
    if (l==0){
      float m = s*(1.f/128.f);
      stats[2*c] = m;
      stats[2*c+1] = rsqrtf(sq*(1.f/128.f) - m*m + 1e-5f);
    }
  }
  __syncthreads();
  float acc=0.f;
  #pragma unroll
  for (int i=0;i<8;i++) acc += (g2s[i*128+j] - stats[2*i]) * stats[2*i+1];
  emb[(long)g*128 + j] = lng[j]*acc*0.125f + lnb[j];
}

// ---------------------------------------------------------------------------
// K7b: transpose w_hh (1024,256) f32 -> wt (256,1024) bf16
// ---------------------------------------------------------------------------
__global__ __launch_bounds__(256) void k_tr(
  const float* __restrict__ in, unsigned short* __restrict__ out)
{
  const int i = blockIdx.x*256 + threadIdx.x;   // 262144
  const int g = i & 1023, j = i >> 10;
  out[i] = f2bf(in[g*256 + j]);
}

// ---------------------------------------------------------------------------
// K8: one LSTM layer, both directions. Block = (batch, dir). h,c block-local.
// ---------------------------------------------------------------------------
__global__ __launch_bounds__(256) void k_lstm(
    const float* __restrict__ xsf, const float* __restrict__ xsr,
    const unsigned short* __restrict__ wtf, const unsigned short* __restrict__ wtr,
    float* __restrict__ out)
{
  const int S = 20;
  const int b = blockIdx.x >> 1, dir = blockIdx.x & 1;
  const float* xs = dir ? xsr : xsf;
  const unsigned short* wt = dir ? wtr : wtf;
  __shared__ float hs[256];
  __shared__ float gs[1024];
  const int tid = threadIdx.x;
  const int grow = (tid>>6)*256 + (tid&63)*4;
  hs[tid] = 0.f;
  float cc = 0.f;
  __syncthreads();
  for (int st=0; st<S; ++st){
    const int t = dir ? (S-1-st) : st;
    const float* xrow = xs + ((long)b*S + t)*1024;
    float4 a = *reinterpret_cast<const float4*>(xrow + grow);
    float acc0=a.x, acc1=a.y, acc2=a.z, acc3=a.w;
    #pragma unroll 4
    for (int j=0;j<256;++j){
      const float hv = hs[j];
      ushort4 w = *reinterpret_cast<const ushort4*>(wt + (long)j*1024 + grow);
      acc0 += hv*bf2f(w.x);
      acc1 += hv*bf2f(w.y);
      acc2 += hv*bf2f(w.z);
      acc3 += hv*bf2f(w.w);
    }
    gs[grow+0]=acc0; gs[grow+1]=acc1; gs[grow+2]=acc2; gs[grow+3]=acc3;
    __syncthreads();
    const float gi = gs[tid], gf = gs[256+tid], gg = gs[512+tid], go = gs[768+tid];
    cc = sigf(gf)*cc + sigf(gi)*tanhf(gg);
    const float h = sigf(go)*tanhf(cc);
    hs[tid] = h;
    out[((long)b*S + t)*512 + dir*256 + tid] = h;
    __syncthreads();
  }
}

// ---------------------------------------------------------------------------
// K11: final LayerNorm(512) + classifier (5) per row
// ---------------------------------------------------------------------------
__global__ __launch_bounds__(128) void k_lncls(
  const float* __restrict__ in, const float* __restrict__ g,
  const float* __restrict__ b, const float* __restrict__ cw,
  const float* __restrict__ cb, float* __restrict__ out)
{
  const int row = blockIdx.x, tid = threadIdx.x;
  __shared__ float sred[4];
  __shared__ float cred[2][5];
  float4 v = *reinterpret_cast<const float4*>(in + (long)row*512 + tid*4);
  float s  = v.x+v.y+v.z+v.w;
  float sq = v.x*v.x+v.y*v.y+v.z*v.z+v.w*v.w;
  #pragma unroll
  for (int off=32; off>=1; off>>=1){ s += __shfl_xor(s, off); sq += __shfl_xor(sq, off); }
  const int wv = tid>>6;
  if ((tid&63)==0){ sred[wv*2]=s; sred[wv*2+1]=sq; }
  __syncthreads();
  const float S = sred[0]+sred[2], SQ = sred[1]+sred[3];
  const float m = S*(1.f/512.f);
  const float rstd = rsqrtf(SQ*(1.f/512.f) - m*m + 1e-5f);
  float4 gg = *reinterpret_cast<const float4*>(g + tid*4);
  float4 bb = *reinterpret_cast<const float4*>(b + tid*4);
  const float n0 = (v.x-m)*rstd*gg.x + bb.x;
  const float n1 = (v.y-m)*rstd*gg.y + bb.y;
  const float n2 = (v.z-m)*rstd*gg.z + bb.z;
  const float n3 = (v.w-m)*rstd*gg.w + bb.w;
  #pragma unroll
  for (int nc=0; nc<5; ++nc){
    float4 w = *reinterpret_cast<const float4*>(cw + nc*512 + tid*4);
    float p = n0*w.x + n1*w.y + n2*w.z + n3*w.w;
    #pragma unroll
    for (int off=32; off>=1; off>>=1) p += __shfl_xor(p, off);
    if ((tid&63)==0) cred[wv][nc] = p;
  }
  __syncthreads();
  if (tid < 5) out[(long)row*5 + tid] = cred[0][tid] + cred[1][tid] + cb[tid];
}

// ---------------------------------------------------------------------------
extern "C" void kernel_launch(void* const* d_in, const int* in_sizes, int n_in,
                              void* d_out, int out_size, void* d_ws, size_t ws_size,
                              hipStream_t stream)
{
  const float* x     = (const float*)d_in[0];
  const int*   ei    = (const int*)d_in[1];
  const float* w1    = (const float*)d_in[2];
  const float* c1b   = (const float*)d_in[3];
  const float* bg1   = (const float*)d_in[4];
  const float* bb1   = (const float*)d_in[5];
  const float* w2    = (const float*)d_in[6];
  const float* c2b   = (const float*)d_in[7];
  const float* bg2   = (const float*)d_in[8];
  const float* bb2   = (const float*)d_in[9];
  const float* w3    = (const float*)d_in[10];
  const float* c3b   = (const float*)d_in[11];
  const float* bg3   = (const float*)d_in[12];
  const float* bb3   = (const float*)d_in[13];
  const float* gcn0w = (const float*)d_in[14];
  const float* gcn0b = (const float*)d_in[15];
  const float* gcn1w = (const float*)d_in[16];
  const float* gcn1b = (const float*)d_in[17];
  const float* lng   = (const float*)d_in[18];
  const float* lnb   = (const float*)d_in[19];
  const float* wih0  = (const float*)d_in[20];
  const float* whh0  = (const float*)d_in[21];
  const float* bih0  = (const float*)d_in[22];
  const float* bhh0  = (const float*)d_in[23];
  const float* wih0r = (const float*)d_in[24];
  const float* whh0r = (const float*)d_in[25];
  const float* bih0r = (const float*)d_in[26];
  const float* bhh0r = (const float*)d_in[27];
  const float* wih1  = (const float*)d_in[28];
  const float* whh1  = (const float*)d_in[29];
  const float* bih1  = (const float*)d_in[30];
  const float* bhh1  = (const float*)d_in[31];
  const float* wih1r = (const float*)d_in[32];
  const float* whh1r = (const float*)d_in[33];
  const float* bih1r = (const float*)d_in[34];
  const float* bhh1r = (const float*)d_in[35];
  const float* lstmg = (const float*)d_in[36];
  const float* lstmb = (const float*)d_in[37];
  const float* clsw  = (const float*)d_in[38];
  const float* clsb  = (const float*)d_in[39];
  float* ws  = (float*)d_ws;
  float* out = (float*)d_out;

  // workspace layout (floats); total 7,897,344 floats = 31.6 MB
  float* An    = ws + 0;
  float* feats = ws + 256;
  float* tmp   = ws + 655616;    // tmp0 and tmp1 (aliased)
  float* g1b   = ws + 1966336;
  float* emb   = ws + 3277056;
  float* xsf   = ws + 3440896;   // reused for layer1
  float* xsr   = ws + 4751616;
  float* l0    = ws + 6062336;
  float* l1    = ws + 6717696;
  unsigned short* wt0f = (unsigned short*)(ws + 7373056);
  unsigned short* wt0r = (unsigned short*)(ws + 7504128);
  unsigned short* wt1f = (unsigned short*)(ws + 7635200);
  unsigned short* wt1r = (unsigned short*)(ws + 7766272);

  // Stage 1: conv front-end
  k_conv<<<10240, 256, 0, stream>>>(x, w1,c1b,bg1,bb1, w2,c2b,bg2,bb2,
                                    w3,c3b,bg3,bb3, feats);
  // Adjacency + weight transposes (independent of k_conv output)
  k_an<<<1, 64, 0, stream>>>(ei, An);
  k_tr<<<1024,256,0,stream>>>(whh0,  wt0f);
  k_tr<<<1024,256,0,stream>>>(whh0r, wt0r);
  k_tr<<<1024,256,0,stream>>>(whh1,  wt1f);
  k_tr<<<1024,256,0,stream>>>(whh1r, wt1r);

  // Stage 2: GCN
  k_gemm_nt<<<dim3(2, 80), 256, 0, stream>>>(feats, gcn0w, nullptr, nullptr, tmp, 10240, 128, 64);
  k_mix1<<<640,256,0,stream>>>(tmp, An, gcn0b, g1b);
  k_gemm_nt<<<dim3(2, 80), 256, 0, stream>>>(g1b, gcn1w, nullptr, nullptr, tmp, 10240, 128, 128);
  k_mix2<<<1280,128,0,stream>>>(tmp, An, gcn1b, lng, lnb, emb);

  // Stage 3: BiLSTM layer 0
  k_gemm_nt<<<dim3(16, 10), 256, 0, stream>>>(emb, wih0,  bih0,  bhh0,  xsf, 1280, 1024, 128);
  k_gemm_nt<<<dim3(16, 10), 256, 0, stream>>>(emb, wih0r, bih0r, bhh0r, xsr, 1280, 1024, 128);
  k_lstm<<<128, 256, 0, stream>>>(xsf, xsr, wt0f, wt0r, l0);

  // BiLSTM layer 1
  k_gemm_nt<<<dim3(16, 10), 256, 0, stream>>>(l0, wih1,  bih1,  bhh1,  xsf, 1280, 1024, 512);
  k_gemm_nt<<<dim3(16, 10), 256, 0, stream>>>(l0, wih1r, bih1r, bhh1r, xsr, 1280, 1024, 512);
  k_lstm<<<128, 256, 0, stream>>>(xsf, xsr, wt1f, wt1r, l1);

  // Stage 4: LN + classifier
  k_lncls<<<1280, 128, 0, stream>>>(l1, lstmg, lstmb, clsw, clsb, out);
}

// Round 4
// 604.957 us; speedup vs baseline: 2.3664x; 1.5605x over previous
//
#include <hip/hip_runtime.h>
#include <hip/hip_bf16.h>

#define DEVI __device__ __forceinline__

typedef _Float16 h2f16 __attribute__((ext_vector_type(2)));
union F4H { float4 f; h2f16 h[4]; };
union U4H { uint4 u; h2f16 h[4]; };

DEVI float sigf(float x){ return 1.f/(1.f + __expf(-x)); }
DEVI float tanh_f(float x){
  float ax = fabsf(x);
  float e = __expf(-2.f*ax);
  float t = (1.f - e)/(1.f + e);
  return copysignf(t, x);
}

// ---------------------------------------------------------------------------
// K1: fused conv front-end. One block per signal (B*S*C = 10240 signals).
// conv1(k7,s2,p3)+BN+ReLU+pool3 -> conv2(k5,s2,p2)+BN+ReLU+pool3 ->
// conv3(k3,s1,p1)+BN+ReLU -> mean(83) => feats[sig][64]
// f16 intermediates + v_dot2_f32_f16; ~35.5KB LDS -> 4 blocks/CU (16 waves).
// ---------------------------------------------------------------------------
__global__ __launch_bounds__(256,4) void k_conv(
    const float* __restrict__ x,
    const float* __restrict__ w1g, const float* __restrict__ c1b,
    const float* __restrict__ bg1, const float* __restrict__ bb1,
    const float* __restrict__ w2g, const float* __restrict__ c2b,
    const float* __restrict__ bg2, const float* __restrict__ bb2,
    const float* __restrict__ w3g, const float* __restrict__ c3b,
    const float* __restrict__ bg3, const float* __restrict__ bb3,
    float* __restrict__ feats)
{
  __shared__ __align__(16) unsigned char smb[34112];
  __shared__ float w1s[112];
  __shared__ float kb1[32], kb2[64], kb3[128];
  _Float16* s1t = reinterpret_cast<_Float16*>(smb);
  _Float16* s2t = reinterpret_cast<_Float16*>(smb + 16128);
  float*    sx  = reinterpret_cast<float*>(smb + 21568);
  h2f16*    w2s = reinterpret_cast<h2f16*>(smb + 21568);
  h2f16*    w3s = reinterpret_cast<h2f16*>(smb + 21568);
  float*    red = reinterpret_cast<float*>(smb);
  const int tid = threadIdx.x;
  const long sig = blockIdx.x;
  const float* xg = x + sig*3000;

  {
    const float4* xg4 = reinterpret_cast<const float4*>(xg);
    float4* sx4 = reinterpret_cast<float4*>(sx+4);
    for (int i=tid; i<750; i+=256) sx4[i] = xg4[i];
    if (tid<4)  sx[tid]=0.f;
    if (tid<8)  sx[3004+tid]=0.f;
    if (tid<32) s1t[tid]=(_Float16)0.f;
    if (tid<112) w1s[tid]=w1g[tid];
    const float rs = rsqrtf(1.f+1e-5f);
    if (tid<16){ float s=bg1[tid]*rs; kb1[2*tid]=s; kb1[2*tid+1]=c1b[tid]*s+bb1[tid]; }
    if (tid<32){ float s=bg2[tid]*rs; kb2[2*tid]=s; kb2[2*tid+1]=c2b[tid]*s+bb2[tid]; }
    if (tid<64){ float s=bg3[tid]*rs; kb3[2*tid]=s; kb3[2*tid+1]=c3b[tid]*s+bb3[tid]; }
  }
  __syncthreads();

  // Phase A: conv1+bn+relu+pool -> s1t[pos+2][c] (f16), 16ch x 500
  {
    const int c = tid & 15;
    const float s = kb1[2*c], o = kb1[2*c+1];
    float wr[7];
    #pragma unroll
    for (int k=0;k<7;k++) wr[k] = w1s[c*7+k];
    for (int u = tid>>4; u<500; u+=16){
      const float* xb = sx + 6*u + 1;
      float xv[11];
      #pragma unroll
      for (int r=0;r<11;r++) xv[r] = xb[r];
      float a0=0.f,a1=0.f,a2=0.f;
      #pragma unroll
      for (int k=0;k<7;k++){ float w=wr[k]; a0 += xv[k]*w; a1 += xv[k+2]*w; a2 += xv[k+4]*w; }
      float y = fmaxf(fmaxf(a0*s+o, a1*s+o), a2*s+o);
      s1t[(u+2)*16 + c] = (_Float16)fmaxf(y, 0.f);
    }
  }
  __syncthreads();

  for (int i=tid; i<1280; i+=256){
    const int oc = i/40, rem = i - oc*40, k = rem>>3, j = rem&7;
    h2f16 p;
    p[0] = (_Float16)w2g[oc*80 + (2*j)*5 + k];
    p[1] = (_Float16)w2g[oc*80 + (2*j+1)*5 + k];
    w2s[oc*41 + k*8 + j] = p;
  }
  if (tid<32){ s2t[tid]=(_Float16)0.f; s2t[84*32+tid]=(_Float16)0.f; }
  __syncthreads();

  // Phase B: conv2+bn+relu+pool -> s2t[pos+1][oc] (f16), 32ch x 83
  {
    const int oc = tid & 31, ug = tid >> 5;
    h2f16 w2r[40];
    #pragma unroll
    for (int i=0;i<40;i++) w2r[i] = w2s[oc*41 + i];
    const float s=kb2[2*oc], o=kb2[2*oc+1];
    for (int u=ug; u<83; u+=8){
      float acc0=0.f, acc1=0.f, acc2=0.f;
      #pragma unroll
      for (int rp=0; rp<9; ++rp){
        const float4* rowp = reinterpret_cast<const float4*>(s1t + (6*u+rp)*16);
        F4H ra, rb; ra.f = rowp[0]; rb.f = rowp[1];
        const h2f16 h0=ra.h[0],h1=ra.h[1],h2=ra.h[2],h3=ra.h[3];
        const h2f16 h4=rb.h[0],h5=rb.h[1],h6=rb.h[2],h7=rb.h[3];
        #pragma unroll
        for (int tp=0; tp<3; ++tp){
          const int k = rp - 2*tp;
          if (k>=0 && k<5){
            const h2f16* wk = w2r + k*8;
            float a = (tp==0)?acc0:(tp==1)?acc1:acc2;
            a = __builtin_amdgcn_fdot2(h0, wk[0], a, false);
            a = __builtin_amdgcn_fdot2(h1, wk[1], a, false);
            a = __builtin_amdgcn_fdot2(h2, wk[2], a, false);
            a = __builtin_amdgcn_fdot2(h3, wk[3], a, false);
            a = __builtin_amdgcn_fdot2(h4, wk[4], a, false);
            a = __builtin_amdgcn_fdot2(h5, wk[5], a, false);
            a = __builtin_amdgcn_fdot2(h6, wk[6], a, false);
            a = __builtin_amdgcn_fdot2(h7, wk[7], a, false);
            if (tp==0) acc0=a; else if (tp==1) acc1=a; else acc2=a;
          }
        }
      }
      float y = fmaxf(fmaxf(acc0*s+o, acc1*s+o), acc2*s+o);
      s2t[(u+1)*32 + oc] = (_Float16)fmaxf(y, 0.f);
    }
  }
  __syncthreads();
  for (int i=tid; i<3072; i+=256){
    const int oc = i/48, rem = i - oc*48, k = rem>>4, j = rem&15;
    h2f16 p;
    p[0] = (_Float16)w3g[oc*96 + 6*j + k];
    p[1] = (_Float16)w3g[oc*96 + 6*j + 3 + k];
    w3s[oc*49 + k*16 + j] = p;
  }
  __syncthreads();

  // Phase C: conv3+bn+relu+mean -> feats[sig][64]
  {
    const int oc = tid & 63;
    h2f16 w3r[48];
    #pragma unroll
    for (int i=0;i<48;i++) w3r[i] = w3s[oc*49 + i];
    const float s=kb3[2*oc], o=kb3[2*oc+1];
    float acc = 0.f;
    for (int t=(tid>>6); t<83; t+=4){
      float cs = 0.f;
      #pragma unroll
      for (int k=0;k<3;k++){
        const float4* rowp = reinterpret_cast<const float4*>(s2t + (t+k)*32);
        #pragma unroll
        for (int q=0;q<4;q++){
          F4H r; r.f = rowp[q];
          cs = __builtin_amdgcn_fdot2(r.h[0], w3r[k*16 + q*4 + 0], cs, false);
          cs = __builtin_amdgcn_fdot2(r.h[1], w3r[k*16 + q*4 + 1], cs, false);
          cs = __builtin_amdgcn_fdot2(r.h[2], w3r[k*16 + q*4 + 2], cs, false);
          cs = __builtin_amdgcn_fdot2(r.h[3], w3r[k*16 + q*4 + 3], cs, false);
        }
      }
      acc += fmaxf(cs*s+o, 0.f);
    }
    red[tid] = acc;
  }
  __syncthreads();
  if (tid<64){
    float r = red[tid]+red[tid+64]+red[tid+128]+red[tid+192];
    feats[sig*64 + tid] = r * (1.f/83.f);
  }
}

// ---------------------------------------------------------------------------
// K2: build normalized adjacency An (8x8) from edge_index (2,56)
// ---------------------------------------------------------------------------
__global__ void k_an(const int* __restrict__ ei, float* __restrict__ an){
  __shared__ float A[64];
  __shared__ float dinv[8];
  const int tid = threadIdx.x;
  if (tid<64) A[tid] = ((tid>>3)==(tid&7)) ? 1.f : 0.f;
  __syncthreads();
  if (tid==0){
    for (int e=0;e<56;e++){ int s=ei[e], d=ei[56+e]; A[d*8+s] += 1.f; }
  }
  __syncthreads();
  if (tid<8){ float s=0.f; for (int j=0;j<8;j++) s+=A[tid*8+j]; dinv[tid]=rsqrtf(s); }
  __syncthreads();
  if (tid<64) an[tid] = A[tid]*dinv[tid>>3]*dinv[tid&7];
}

// ---------------------------------------------------------------------------
// f32 GEMM: C[M,N] = X[M,K] @ W[N,K]^T (+b1 +b2), tile 64x64, BK=16, ldc param.
// M%64==0, N%64==0, K%16==0 (K=64 ok).
// ---------------------------------------------------------------------------
__global__ __launch_bounds__(256) void k_gemm64(
  const float* __restrict__ X, const float* __restrict__ W,
  const float* __restrict__ b1, const float* __restrict__ b2,
  float* __restrict__ C, int M, int N, int K, int ldc)
{
  __shared__ float Xs[16][68];
  __shared__ float Ws[16][68];
  const int tid = threadIdx.x;
  const int m0 = blockIdx.y*64, n0 = blockIdx.x*64;
  const int tm = tid >> 4, tn = tid & 15;
  const int lr = tid >> 2, lk = (tid & 3)*4;
  float acc[4][4] = {};
  for (int k0=0; k0<K; k0+=16){
    float4 xa = *reinterpret_cast<const float4*>(X + (long)(m0+lr)*K + k0 + lk);
    float4 wa = *reinterpret_cast<const float4*>(W + (long)(n0+lr)*K + k0 + lk);
    __syncthreads();
    Xs[lk+0][lr]=xa.x; Xs[lk+1][lr]=xa.y; Xs[lk+2][lr]=xa.z; Xs[lk+3][lr]=xa.w;
    Ws[lk+0][lr]=wa.x; Ws[lk+1][lr]=wa.y; Ws[lk+2][lr]=wa.z; Ws[lk+3][lr]=wa.w;
    __syncthreads();
    #pragma unroll
    for (int kk=0;kk<16;kk++){
      float4 a  = *reinterpret_cast<const float4*>(&Xs[kk][tm*4]);
      float4 bv = *reinterpret_cast<const float4*>(&Ws[kk][tn*4]);
      float av[4]={a.x,a.y,a.z,a.w}, bb[4]={bv.x,bv.y,bv.z,bv.w};
      #pragma unroll
      for (int i=0;i<4;i++)
        #pragma unroll
        for (int j=0;j<4;j++) acc[i][j] += av[i]*bb[j];
    }
  }
  float bias[4] = {0.f,0.f,0.f,0.f};
  if (b1){ float4 t = *reinterpret_cast<const float4*>(b1 + n0 + tn*4);
           bias[0]+=t.x; bias[1]+=t.y; bias[2]+=t.z; bias[3]+=t.w; }
  if (b2){ float4 t = *reinterpret_cast<const float4*>(b2 + n0 + tn*4);
           bias[0]+=t.x; bias[1]+=t.y; bias[2]+=t.z; bias[3]+=t.w; }
  #pragma unroll
  for (int i=0;i<4;i++){
    float4 o;
    o.x = acc[i][0]+bias[0]; o.y = acc[i][1]+bias[1];
    o.z = acc[i][2]+bias[2]; o.w = acc[i][3]+bias[3];
    *reinterpret_cast<float4*>(C + (long)(m0+tm*4+i)*ldc + n0 + tn*4) = o;
  }
}

// ---------------------------------------------------------------------------
// K4: g1[g][i][j] = relu( sum_c An[i][c]*tmp0[g][c][j] + b0[j] )
// ---------------------------------------------------------------------------
__global__ __launch_bounds__(256) void k_mix1(
  const float* __restrict__ tmp0, const float* __restrict__ An,
  const float* __restrict__ b0, float* __restrict__ g1)
{
  __shared__ float ans[64];
  if (threadIdx.x < 64) ans[threadIdx.x] = An[threadIdx.x];
  __syncthreads();
  const long idx = (long)blockIdx.x*256 + threadIdx.x;   // over 1280*128
  const int g = (int)(idx >> 7), j = (int)(idx & 127);
  const float* base = tmp0 + (long)g*1024;
  float t[8];
  #pragma unroll
  for (int c=0;c<8;c++) t[c] = base[c*128+j];
  const float bj = b0[j];
  #pragma unroll
  for (int i=0;i<8;i++){
    float s = bj;
    #pragma unroll
    for (int c=0;c<8;c++) s += ans[i*8+c]*t[c];
    g1[(long)g*1024 + i*128 + j] = fmaxf(s, 0.f);
  }
}

// ---------------------------------------------------------------------------
// K6: g2 = An@tmp1 + b1 ; LN over j (128) per row ; mean over 8 nodes -> emb
// ---------------------------------------------------------------------------
__global__ __launch_bounds__(128) void k_mix2(
  const float* __restrict__ tmp1, const float* __restrict__ An,
  const float* __restrict__ b1, const float* __restrict__ lng,
  const float* __restrict__ lnb, float* __restrict__ emb)
{
  const int g = blockIdx.x, j = threadIdx.x;
  __shared__ float ans[64];
  __shared__ float g2s[8*128];
  __shared__ float stats[16];
  if (j<64) ans[j] = An[j];
  const float* base = tmp1 + (long)g*1024;
  float t[8];
  #pragma unroll
  for (int c=0;c<8;c++) t[c] = base[c*128 + j];
  const float bj = b1[j];
  __syncthreads();
  #pragma unroll
  for (int i=0;i<8;i++){
    float s = bj;
    #pragma unroll
    for (int c=0;c<8;c++) s += ans[i*8+c]*t[c];
    g2s[i*128+j] = s;
  }
  __syncthreads();
  {
    const int c = j>>4, l = j&15;
    float s=0.f, sq=0.f;
    for (int jj=l; jj<128; jj+=16){ float v=g2s[c*128+jj]; s+=v; sq+=v*v; }
    #pragma unroll
    for (int off=8; off>=1; off>>=1){ s += __shfl_xor(s, off); sq += __shfl_xor(sq, off); }
    if (l==0){
      float m = s*(1.f/128.f);
      stats[2*c] = m;
      stats[2*c+1] = rsqrtf(sq*(1.f/128.f) - m*m + 1e-5f);
    }
  }
  __syncthreads();
  float acc=0.f;
  #pragma unroll
  for (int i=0;i<8;i++) acc += (g2s[i*128+j] - stats[2*i]) * stats[2*i+1];
  emb[(long)g*128 + j] = lng[j]*acc*0.125f + lnb[j];
}

// ---------------------------------------------------------------------------
// K7: transpose+pack w_hh (1024,256) f32 -> wtp[jp][g] = (w[g][2jp], w[g][2jp+1]) f16x2
// ---------------------------------------------------------------------------
__global__ __launch_bounds__(256) void k_trp(
  const float* __restrict__ in, h2f16* __restrict__ outp)
{
  const int i = blockIdx.x*256 + threadIdx.x;   // 131072
  const int g = i & 1023, jp = i >> 10;
  h2f16 p;
  p[0] = (_Float16)in[g*256 + 2*jp];
  p[1] = (_Float16)in[g*256 + 2*jp + 1];
  outp[(long)jp*1024 + g] = p;
}

// ---------------------------------------------------------------------------
// K8: one LSTM layer, both directions. Block = (batch, dir), 1024 threads.
// 4-way K-split: thread (jg=tid>>8, r=tid&255) accumulates gate rows 4r..4r+3
// over j in [jg*64, jg*64+64) via packed-f16 fdot2; LDS reduce; 256 threads
// do activations. Recurrent h stored f16 in LDS; out written f32.
// ---------------------------------------------------------------------------
__global__ __launch_bounds__(1024) void k_lstm(
    const float* __restrict__ xs,          // [1280][2048] fwd|rev gates
    const h2f16* __restrict__ wtf,         // [128][1024] packed j-pairs
    const h2f16* __restrict__ wtr,
    float* __restrict__ out)               // [1280][512]
{
  const int S = 20;
  const int b = blockIdx.x >> 1, dir = blockIdx.x & 1;
  const h2f16* wt = dir ? wtr : wtf;
  __shared__ float part[4][1024];
  __shared__ _Float16 hsh[256];
  const int tid = threadIdx.x;
  const int jg = tid >> 8, r = tid & 255, grow = r*4;
  if (tid < 256) hsh[tid] = (_Float16)0.f;
  float cc = 0.f;
  __syncthreads();
  const h2f16* hp2 = reinterpret_cast<const h2f16*>(hsh);
  for (int st=0; st<S; ++st){
    const int t = dir ? (S-1-st) : st;
    float a0=0.f,a1=0.f,a2=0.f,a3=0.f;
    #pragma unroll 8
    for (int jp=0; jp<32; ++jp){
      const h2f16 hv = hp2[jg*32 + jp];
      U4H w; w.u = *reinterpret_cast<const uint4*>(
          reinterpret_cast<const unsigned int*>(wt + (long)(jg*32+jp)*1024 + grow));
      a0 = __builtin_amdgcn_fdot2(hv, w.h[0], a0, false);
      a1 = __builtin_amdgcn_fdot2(hv, w.h[1], a1, false);
      a2 = __builtin_amdgcn_fdot2(hv, w.h[2], a2, false);
      a3 = __builtin_amdgcn_fdot2(hv, w.h[3], a3, false);
    }
    *reinterpret_cast<float4*>(&part[jg][grow]) = make_float4(a0,a1,a2,a3);
    __syncthreads();
    if (tid < 256){
      const float* xrow = xs + ((long)b*S + t)*2048 + dir*1024;
      float g0 = xrow[tid]
               + (part[0][tid]      + part[1][tid])      + (part[2][tid]      + part[3][tid]);
      float g1 = xrow[256+tid]
               + (part[0][256+tid]  + part[1][256+tid])  + (part[2][256+tid]  + part[3][256+tid]);
      float g2 = xrow[512+tid]
               + (part[0][512+tid]  + part[1][512+tid])  + (part[2][512+tid]  + part[3][512+tid]);
      float g3 = xrow[768+tid]
               + (part[0][768+tid]  + part[1][768+tid])  + (part[2][768+tid]  + part[3][768+tid]);
      cc = sigf(g1)*cc + sigf(g0)*tanh_f(g2);
      const float h = sigf(g3)*tanh_f(cc);
      hsh[tid] = (_Float16)h;
      out[((long)b*S + t)*512 + dir*256 + tid] = h;
    }
    __syncthreads();
  }
}

// ---------------------------------------------------------------------------
// K11: final LayerNorm(512) + classifier (5) per row
// ---------------------------------------------------------------------------
__global__ __launch_bounds__(128) void k_lncls(
  const float* __restrict__ in, const float* __restrict__ g,
  const float* __restrict__ b, const float* __restrict__ cw,
  const float* __restrict__ cb, float* __restrict__ out)
{
  const int row = blockIdx.x, tid = threadIdx.x;
  __shared__ float sred[4];
  __shared__ float cred[2][5];
  float4 v = *reinterpret_cast<const float4*>(in + (long)row*512 + tid*4);
  float s  = v.x+v.y+v.z+v.w;
  float sq = v.x*v.x+v.y*v.y+v.z*v.z+v.w*v.w;
  #pragma unroll
  for (int off=32; off>=1; off>>=1){ s += __shfl_xor(s, off); sq += __shfl_xor(sq, off); }
  const int wv = tid>>6;
  if ((tid&63)==0){ sred[wv*2]=s; sred[wv*2+1]=sq; }
  __syncthreads();
  const float S = sred[0]+sred[2], SQ = sred[1]+sred[3];
  const float m = S*(1.f/512.f);
  const float rstd = rsqrtf(SQ*(1.f/512.f) - m*m + 1e-5f);
  float4 gg = *reinterpret_cast<const float4*>(g + tid*4);
  float4 bb = *reinterpret_cast<const float4*>(b + tid*4);
  const float n0 = (v.x-m)*rstd*gg.x + bb.x;
  const float n1 = (v.y-m)*rstd*gg.y + bb.y;
  const float n2 = (v.z-m)*rstd*gg.z + bb.z;
  const float n3 = (v.w-m)*rstd*gg.w + bb.w;
  #pragma unroll
  for (int nc=0; nc<5; ++nc){
    float4 w = *reinterpret_cast<const float4*>(cw + nc*512 + tid*4);
    float p = n0*w.x + n1*w.y + n2*w.z + n3*w.w;
    #pragma unroll
    for (int off=32; off>=1; off>>=1) p += __shfl_xor(p, off);
    if ((tid&63)==0) cred[wv][nc] = p;
  }
  __syncthreads();
  if (tid < 5) out[(long)row*5 + tid] = cred[0][tid] + cred[1][tid] + cb[tid];
}

// ---------------------------------------------------------------------------
extern "C" void kernel_launch(void* const* d_in, const int* in_sizes, int n_in,
                              void* d_out, int out_size, void* d_ws, size_t ws_size,
                              hipStream_t stream)
{
  const float* x     = (const float*)d_in[0];
  const int*   ei    = (const int*)d_in[1];
  const float* w1    = (const float*)d_in[2];
  const float* c1b   = (const float*)d_in[3];
  const float* bg1   = (const float*)d_in[4];
  const float* bb1   = (const float*)d_in[5];
  const float* w2    = (const float*)d_in[6];
  const float* c2b   = (const float*)d_in[7];
  const float* bg2   = (const float*)d_in[8];
  const float* bb2   = (const float*)d_in[9];
  const float* w3    = (const float*)d_in[10];
  const float* c3b   = (const float*)d_in[11];
  const float* bg3   = (const float*)d_in[12];
  const float* bb3   = (const float*)d_in[13];
  const float* gcn0w = (const float*)d_in[14];
  const float* gcn0b = (const float*)d_in[15];
  const float* gcn1w = (const float*)d_in[16];
  const float* gcn1b = (const float*)d_in[17];
  const float* lng   = (const float*)d_in[18];
  const float* lnb   = (const float*)d_in[19];
  const float* wih0  = (const float*)d_in[20];
  const float* whh0  = (const float*)d_in[21];
  const float* bih0  = (const float*)d_in[22];
  const float* bhh0  = (const float*)d_in[23];
  const float* wih0r = (const float*)d_in[24];
  const float* whh0r = (const float*)d_in[25];
  const float* bih0r = (const float*)d_in[26];
  const float* bhh0r = (const float*)d_in[27];
  const float* wih1  = (const float*)d_in[28];
  const float* whh1  = (const float*)d_in[29];
  const float* bih1  = (const float*)d_in[30];
  const float* bhh1  = (const float*)d_in[31];
  const float* wih1r = (const float*)d_in[32];
  const float* whh1r = (const float*)d_in[33];
  const float* bih1r = (const float*)d_in[34];
  const float* bhh1r = (const float*)d_in[35];
  const float* lstmg = (const float*)d_in[36];
  const float* lstmb = (const float*)d_in[37];
  const float* clsw  = (const float*)d_in[38];
  const float* clsb  = (const float*)d_in[39];
  float* ws  = (float*)d_ws;
  float* out = (float*)d_out;

  // workspace layout (floats); total 7,897,344 floats = 31.6 MB
  float* An    = ws + 0;
  float* feats = ws + 256;
  float* tmp   = ws + 655616;    // [10240][128] (tmp0/tmp1 aliased)
  float* g1b   = ws + 1966336;   // [10240][128]
  float* emb   = ws + 3277056;   // [1280][128]
  float* xs    = ws + 3440896;   // [1280][2048] fused fwd|rev gate inputs
  float* l0    = ws + 6062336;   // [1280][512]
  float* l1    = ws + 6717696;   // [1280][512]
  h2f16* wt0f  = (h2f16*)(ws + 7373056);
  h2f16* wt0r  = (h2f16*)(ws + 7504128);
  h2f16* wt1f  = (h2f16*)(ws + 7635200);
  h2f16* wt1r  = (h2f16*)(ws + 7766272);

  // Stage 1: conv front-end
  k_conv<<<10240, 256, 0, stream>>>(x, w1,c1b,bg1,bb1, w2,c2b,bg2,bb2,
                                    w3,c3b,bg3,bb3, feats);
  // Adjacency + packed weight transposes (independent of k_conv output)
  k_an<<<1, 64, 0, stream>>>(ei, An);
  k_trp<<<512,256,0,stream>>>(whh0,  wt0f);
  k_trp<<<512,256,0,stream>>>(whh0r, wt0r);
  k_trp<<<512,256,0,stream>>>(whh1,  wt1f);
  k_trp<<<512,256,0,stream>>>(whh1r, wt1r);

  // Stage 2: GCN
  k_gemm64<<<dim3(2, 160), 256, 0, stream>>>(feats, gcn0w, nullptr, nullptr, tmp, 10240, 128, 64, 128);
  k_mix1<<<640,256,0,stream>>>(tmp, An, gcn0b, g1b);
  k_gemm64<<<dim3(2, 160), 256, 0, stream>>>(g1b, gcn1w, nullptr, nullptr, tmp, 10240, 128, 128, 128);
  k_mix2<<<1280,128,0,stream>>>(tmp, An, gcn1b, lng, lnb, emb);

  // Stage 3: BiLSTM layer 0 (fwd|rev gates into one xs buffer, ldc=2048)
  k_gemm64<<<dim3(16, 20), 256, 0, stream>>>(emb, wih0,  bih0,  bhh0,  xs,        1280, 1024, 128, 2048);
  k_gemm64<<<dim3(16, 20), 256, 0, stream>>>(emb, wih0r, bih0r, bhh0r, xs + 1024, 1280, 1024, 128, 2048);
  k_lstm<<<128, 1024, 0, stream>>>(xs, wt0f, wt0r, l0);

  // BiLSTM layer 1
  k_gemm64<<<dim3(16, 20), 256, 0, stream>>>(l0, wih1,  bih1,  bhh1,  xs,        1280, 1024, 512, 2048);
  k_gemm64<<<dim3(16, 20), 256, 0, stream>>>(l0, wih1r, bih1r, bhh1r, xs + 1024, 1280, 1024, 512, 2048);
  k_lstm<<<128, 1024, 0, stream>>>(xs, wt1f, wt1r, l1);

  // Stage 4: LN + classifier
  k_lncls<<<1280, 128, 0, stream>>>(l1, lstmg, lstmb, clsw, clsb, out);
}

// Round 5
// 454.824 us; speedup vs baseline: 3.1476x; 1.3301x over previous
//
#include <hip/hip_runtime.h>
#include <hip/hip_bf16.h>

#define DEVI __device__ __forceinline__

typedef _Float16 h2f16 __attribute__((ext_vector_type(2)));
typedef _Float16 f16x8 __attribute__((ext_vector_type(8)));
typedef float    f32x4 __attribute__((ext_vector_type(4)));
union U4H { uint4 u; h2f16 h[4]; };

DEVI float sigf(float x){ return 1.f/(1.f + __expf(-x)); }
DEVI float tanh_f(float x){
  float ax = fabsf(x);
  float e = __expf(-2.f*ax);
  float t = (1.f - e)/(1.f + e);
  return copysignf(t, x);
}
DEVI h2f16 hmax2(h2f16 a, h2f16 b){
  h2f16 r; r[0] = a[0] > b[0] ? a[0] : b[0]; r[1] = a[1] > b[1] ? a[1] : b[1]; return r;
}

// ---------------------------------------------------------------------------
// K0: pack conv2/conv3 weights to f16, k-major kk ordering, once per launch.
// bw2[kk][oc] : kk = k*16+ic, K=96 (k=5 slot zeroed), oc=32
// bw3[kk][oc] : kk = k*32+ic, K=96, oc=64
// ---------------------------------------------------------------------------
__global__ __launch_bounds__(256) void k_packw(
  const float* __restrict__ w2, const float* __restrict__ w3,
  _Float16* __restrict__ bw2, _Float16* __restrict__ bw3)
{
  const int i = blockIdx.x*256 + threadIdx.x;
  if (i < 3072){
    const int kk = i >> 5, oc = i & 31;
    const int k = kk >> 4, ic = kk & 15;
    bw2[i] = (_Float16)(k < 5 ? w2[oc*80 + ic*5 + k] : 0.f);
  }
  if (i < 6144){
    const int kk = i >> 6, oc = i & 63;
    const int k = kk >> 5, ic = kk & 31;
    bw3[i] = (_Float16)w3[oc*96 + ic*3 + k];
  }
}

// ---------------------------------------------------------------------------
// K1: fused conv front-end. One block per signal (B*S*C = 10240 signals).
// Phase A (conv1+bn+relu+pool): scalar f32 VALU (13% of FLOPs).
// Phase B (conv2) and C (conv3): MFMA 16x16x32 f16 over im2col-in-place LDS.
// ~45.5KB LDS -> 3 blocks/CU.
// ---------------------------------------------------------------------------
__global__ __launch_bounds__(256) void k_conv(
    const float* __restrict__ x,
    const float* __restrict__ w1g, const float* __restrict__ c1b,
    const float* __restrict__ bg1, const float* __restrict__ bb1,
    const _Float16* __restrict__ bw2g,
    const float* __restrict__ c2b, const float* __restrict__ bg2, const float* __restrict__ bb2,
    const _Float16* __restrict__ bw3g,
    const float* __restrict__ c3b, const float* __restrict__ bg3, const float* __restrict__ bb3,
    float* __restrict__ feats)
{
  // byte pool:
  //   s1t   (f16) [504][16] : [0, 16128)        A-write, B-read
  //   s2pre (f16) [250][32] : [16128, 32128)    B-write, pool-read
  //   P2: sx (f32)[3012]    : [32128, 44176)    A only
  //       s2t (f16)[98][32] : [32128, 38400)    pool-write, C-read
  __shared__ __align__(16) unsigned char smb[44176];
  __shared__ float w1s[112];
  __shared__ float kb1[32], kb2[64], kb3[128];
  _Float16* s1t   = reinterpret_cast<_Float16*>(smb);
  _Float16* s2pre = reinterpret_cast<_Float16*>(smb + 16128);
  float*    sx    = reinterpret_cast<float*>(smb + 32128);
  _Float16* s2t   = reinterpret_cast<_Float16*>(smb + 32128);
  const int tid = threadIdx.x;
  const long sig = blockIdx.x;
  const float* xg = x + sig*3000;

  // stage x (float4) + pads + conv1 weights + folded BN consts
  {
    const float4* xg4 = reinterpret_cast<const float4*>(xg);
    float4* sx4 = reinterpret_cast<float4*>(sx+4);
    for (int i=tid; i<750; i+=256) sx4[i] = xg4[i];
    if (tid<4)  sx[tid]=0.f;
    if (tid<8)  sx[3004+tid]=0.f;
    if (tid<32) s1t[tid]=(_Float16)0.f;            // rows 0,1 (pos -2,-1)
    if (tid<32) s1t[8032+tid]=(_Float16)0.f;       // rows 502,503 (pos 500,501)
    if (tid<112) w1s[tid]=w1g[tid];
    const float rs = rsqrtf(1.f+1e-5f);
    if (tid<16){ float s=bg1[tid]*rs; kb1[2*tid]=s; kb1[2*tid+1]=c1b[tid]*s+bb1[tid]; }
    if (tid<32){ float s=bg2[tid]*rs; kb2[2*tid]=s; kb2[2*tid+1]=c2b[tid]*s+bb2[tid]; }
    if (tid<64){ float s=bg3[tid]*rs; kb3[2*tid]=s; kb3[2*tid+1]=c3b[tid]*s+bb3[tid]; }
  }
  __syncthreads();

  // Phase A: conv1+bn+relu+pool -> s1t[pos+2][c] (f16), 16ch x 500
  {
    const int c = tid & 15;
    const float s = kb1[2*c], o = kb1[2*c+1];
    float wr[7];
    #pragma unroll
    for (int k=0;k<7;k++) wr[k] = w1s[c*7+k];
    for (int u = tid>>4; u<500; u+=16){
      const float* xb = sx + 6*u + 1;
      float xv[11];
      #pragma unroll
      for (int r=0;r<11;r++) xv[r] = xb[r];
      float a0=0.f,a1=0.f,a2=0.f;
      #pragma unroll
      for (int k=0;k<7;k++){ float w=wr[k]; a0 += xv[k]*w; a1 += xv[k+2]*w; a2 += xv[k+4]*w; }
      float y = fmaxf(fmaxf(a0*s+o, a1*s+o), a2*s+o);
      s1t[(u+2)*16 + c] = (_Float16)fmaxf(y, 0.f);
    }
  }
  __syncthreads();

  const int wv = tid >> 6, lane = tid & 63;
  const int m = lane & 15, g = lane >> 4;

  // Phase B: conv2 as MFMA. M=256 rows (t), K=96 (kk=k*16+ic), N=32 (oc).
  // A[t][kk] = s1t[2t+k][ic]; wave wv: nt=wv&1, mt=(wv>>1)+2i.
  {
    const int nt = wv & 1;
    f16x8 bf[3];
    #pragma unroll
    for (int s=0;s<3;s++){
      f16x8 t;
      #pragma unroll
      for (int j=0;j<8;j++) t[j] = bw2g[(32*s + 8*g + j)*32 + nt*16 + m];
      bf[s] = t;
    }
    const int oc = nt*16 + m;
    const float sc = kb2[2*oc], of = kb2[2*oc+1];
    #pragma unroll
    for (int i=0;i<8;i++){
      const int mt = (wv>>1) + 2*i;
      const int trow = mt*16 + m;
      f32x4 acc = {0.f,0.f,0.f,0.f};
      #pragma unroll
      for (int s=0;s<3;s++){
        const int kk = 32*s + 8*g;
        const int k = kk >> 4, ic0 = kk & 15;
        f16x8 af = *reinterpret_cast<const f16x8*>(&s1t[(2*trow + k)*16 + ic0]);
        acc = __builtin_amdgcn_mfma_f32_16x16x32_f16(af, bf[s], acc, 0,0,0);
      }
      #pragma unroll
      for (int r=0;r<4;r++){
        const int t = mt*16 + 4*g + r;
        if (t < 250){
          float z = fmaxf(acc[r]*sc + of, 0.f);
          s2pre[t*32 + oc] = (_Float16)z;
        }
      }
    }
  }
  __syncthreads();

  // Pool pass: s2t[u+1][oc] = max over 3 rows of s2pre; zero pad rows 0,84..97.
  {
    h2f16* s2th = reinterpret_cast<h2f16*>(s2t);
    const h2f16* s2ph = reinterpret_cast<const h2f16*>(s2pre);
    if (tid < 240){
      const int rr = tid >> 4, cc = tid & 15;
      const int row = (rr == 0) ? 0 : (83 + rr);
      h2f16 z; z[0]=(_Float16)0.f; z[1]=(_Float16)0.f;
      s2th[row*16 + cc] = z;
    }
    for (int i=tid; i<1328; i+=256){
      const int u = i >> 4, cc = i & 15;
      h2f16 a = s2ph[(3*u)*16 + cc];
      h2f16 b = s2ph[(3*u+1)*16 + cc];
      h2f16 c = s2ph[(3*u+2)*16 + cc];
      s2th[(u+1)*16 + cc] = hmax2(hmax2(a,b), c);
    }
  }
  __syncthreads();

  // Phase C: conv3 as MFMA + bn+relu+mean. M=96 (t), K=96 (kk=k*32+ic), N=64.
  // A[t][kk] = s2t[t+k][ic]; wave wv owns nt=wv; all 6 M-tiles.
  {
    f16x8 bf[3];
    #pragma unroll
    for (int s=0;s<3;s++){
      f16x8 t;
      #pragma unroll
      for (int j=0;j<8;j++) t[j] = bw3g[(32*s + 8*g + j)*64 + wv*16 + m];
      bf[s] = t;
    }
    const int oc = wv*16 + m;
    const float sc = kb3[2*oc], of = kb3[2*oc+1];
    float macc = 0.f;
    #pragma unroll
    for (int mt=0; mt<6; mt++){
      const int trow = mt*16 + m;
      f32x4 acc = {0.f,0.f,0.f,0.f};
      #pragma unroll
      for (int s=0;s<3;s++){
        f16x8 af = *reinterpret_cast<const f16x8*>(&s2t[(trow + s)*32 + 8*g]);
        acc = __builtin_amdgcn_mfma_f32_16x16x32_f16(af, bf[s], acc, 0,0,0);
      }
      #pragma unroll
      for (int r=0;r<4;r++){
        const int t = mt*16 + 4*g + r;
        if (t < 83) macc += fmaxf(acc[r]*sc + of, 0.f);
      }
    }
    macc += __shfl_xor(macc, 16);
    macc += __shfl_xor(macc, 32);
    if (lane < 16) feats[sig*64 + oc] = macc * (1.f/83.f);
  }
}

// ---------------------------------------------------------------------------
// K2: build normalized adjacency An (8x8) from edge_index (2,56)
// ---------------------------------------------------------------------------
__global__ void k_an(const int* __restrict__ ei, float* __restrict__ an){
  __shared__ float A[64];
  __shared__ float dinv[8];
  const int tid = threadIdx.x;
  if (tid<64) A[tid] = ((tid>>3)==(tid&7)) ? 1.f : 0.f;
  __syncthreads();
  if (tid==0){
    for (int e=0;e<56;e++){ int s=ei[e], d=ei[56+e]; A[d*8+s] += 1.f; }
  }
  __syncthreads();
  if (tid<8){ float s=0.f; for (int j=0;j<8;j++) s+=A[tid*8+j]; dinv[tid]=rsqrtf(s); }
  __syncthreads();
  if (tid<64) an[tid] = A[tid]*dinv[tid>>3]*dinv[tid&7];
}

// ---------------------------------------------------------------------------
// f32 GEMM: C[M,N] = X[M,K] @ W[N,K]^T (+b1 +b2), tile 64x64, BK=16, ldc param.
// ---------------------------------------------------------------------------
__global__ __launch_bounds__(256) void k_gemm64(
  const float* __restrict__ X, const float* __restrict__ W,
  const float* __restrict__ b1, const float* __restrict__ b2,
  float* __restrict__ C, int M, int N, int K, int ldc)
{
  __shared__ float Xs[16][68];
  __shared__ float Ws[16][68];
  const int tid = threadIdx.x;
  const int m0 = blockIdx.y*64, n0 = blockIdx.x*64;
  const int tm = tid >> 4, tn = tid & 15;
  const int lr = tid >> 2, lk = (tid & 3)*4;
  float acc[4][4] = {};
  for (int k0=0; k0<K; k0+=16){
    float4 xa = *reinterpret_cast<const float4*>(X + (long)(m0+lr)*K + k0 + lk);
    float4 wa = *reinterpret_cast<const float4*>(W + (long)(n0+lr)*K + k0 + lk);
    __syncthreads();
    Xs[lk+0][lr]=xa.x; Xs[lk+1][lr]=xa.y; Xs[lk+2][lr]=xa.z; Xs[lk+3][lr]=xa.w;
    Ws[lk+0][lr]=wa.x; Ws[lk+1][lr]=wa.y; Ws[lk+2][lr]=wa.z; Ws[lk+3][lr]=wa.w;
    __syncthreads();
    #pragma unroll
    for (int kk=0;kk<16;kk++){
      float4 a  = *reinterpret_cast<const float4*>(&Xs[kk][tm*4]);
      float4 bv = *reinterpret_cast<const float4*>(&Ws[kk][tn*4]);
      float av[4]={a.x,a.y,a.z,a.w}, bb[4]={bv.x,bv.y,bv.z,bv.w};
      #pragma unroll
      for (int i=0;i<4;i++)
        #pragma unroll
        for (int j=0;j<4;j++) acc[i][j] += av[i]*bb[j];
    }
  }
  float bias[4] = {0.f,0.f,0.f,0.f};
  if (b1){ float4 t = *reinterpret_cast<const float4*>(b1 + n0 + tn*4);
           bias[0]+=t.x; bias[1]+=t.y; bias[2]+=t.z; bias[3]+=t.w; }
  if (b2){ float4 t = *reinterpret_cast<const float4*>(b2 + n0 + tn*4);
           bias[0]+=t.x; bias[1]+=t.y; bias[2]+=t.z; bias[3]+=t.w; }
  #pragma unroll
  for (int i=0;i<4;i++){
    float4 o;
    o.x = acc[i][0]+bias[0]; o.y = acc[i][1]+bias[1];
    o.z = acc[i][2]+bias[2]; o.w = acc[i][3]+bias[3];
    *reinterpret_cast<float4*>(C + (long)(m0+tm*4+i)*ldc + n0 + tn*4) = o;
  }
}

// ---------------------------------------------------------------------------
// K4: g1[g][i][j] = relu( sum_c An[i][c]*tmp0[g][c][j] + b0[j] )
// ---------------------------------------------------------------------------
__global__ __launch_bounds__(256) void k_mix1(
  const float* __restrict__ tmp0, const float* __restrict__ An,
  const float* __restrict__ b0, float* __restrict__ g1)
{
  __shared__ float ans[64];
  if (threadIdx.x < 64) ans[threadIdx.x] = An[threadIdx.x];
  __syncthreads();
  const long idx = (long)blockIdx.x*256 + threadIdx.x;   // over 1280*128
  const int g = (int)(idx >> 7), j = (int)(idx & 127);
  const float* base = tmp0 + (long)g*1024;
  float t[8];
  #pragma unroll
  for (int c=0;c<8;c++) t[c] = base[c*128+j];
  const float bj = b0[j];
  #pragma unroll
  for (int i=0;i<8;i++){
    float s = bj;
    #pragma unroll
    for (int c=0;c<8;c++) s += ans[i*8+c]*t[c];
    g1[(long)g*1024 + i*128 + j] = fmaxf(s, 0.f);
  }
}

// ---------------------------------------------------------------------------
// K6: g2 = An@tmp1 + b1 ; LN over j (128) per row ; mean over 8 nodes -> emb
// ---------------------------------------------------------------------------
__global__ __launch_bounds__(128) void k_mix2(
  const float* __restrict__ tmp1, const float* __restrict__ An,
  const float* __restrict__ b1, const float* __restrict__ lng,
  const float* __restrict__ lnb, float* __restrict__ emb)
{
  const int g = blockIdx.x, j = threadIdx.x;
  __shared__ float ans[64];
  __shared__ float g2s[8*128];
  __shared__ float stats[16];
  if (j<64) ans[j] = An[j];
  const float* base = tmp1 + (long)g*1024;
  float t[8];
  #pragma unroll
  for (int c=0;c<8;c++) t[c] = base[c*128 + j];
  const float bj = b1[j];
  __syncthreads();
  #pragma unroll
  for (int i=0;i<8;i++){
    float s = bj;
    #pragma unroll
    for (int c=0;c<8;c++) s += ans[i*8+c]*t[c];
    g2s[i*128+j] = s;
  }
  __syncthreads();
  {
    const int c = j>>4, l = j&15;
    float s=0.f, sq=0.f;
    for (int jj=l; jj<128; jj+=16){ float v=g2s[c*128+jj]; s+=v; sq+=v*v; }
    #pragma unroll
    for (int off=8; off>=1; off>>=1){ s += __shfl_xor(s, off); sq += __shfl_xor(sq, off); }
    if (l==0){
      float m = s*(1.f/128.f);
      stats[2*c] = m;
      stats[2*c+1] = rsqrtf(sq*(1.f/128.f) - m*m + 1e-5f);
    }
  }
  __syncthreads();
  float acc=0.f;
  #pragma unroll
  for (int i=0;i<8;i++) acc += (g2s[i*128+j] - stats[2*i]) * stats[2*i+1];
  emb[(long)g*128 + j] = lng[j]*acc*0.125f + lnb[j];
}

// ---------------------------------------------------------------------------
// K7: transpose+pack w_hh (1024,256) f32 -> wtp[jp][g] = (w[g][2jp], w[g][2jp+1]) f16x2
// ---------------------------------------------------------------------------
__global__ __launch_bounds__(256) void k_trp(
  const float* __restrict__ in, h2f16* __restrict__ outp)
{
  const int i = blockIdx.x*256 + threadIdx.x;   // 131072
  const int g = i & 1023, jp = i >> 10;
  h2f16 p;
  p[0] = (_Float16)in[g*256 + 2*jp];
  p[1] = (_Float16)in[g*256 + 2*jp + 1];
  outp[(long)jp*1024 + g] = p;
}

// ---------------------------------------------------------------------------
// K8: one LSTM layer, both directions. Block = (batch, dir), 1024 threads.
// ---------------------------------------------------------------------------
__global__ __launch_bounds__(1024) void k_lstm(
    const float* __restrict__ xs,          // [1280][2048] fwd|rev gates
    const h2f16* __restrict__ wtf,         // [128][1024] packed j-pairs
    const h2f16* __restrict__ wtr,
    float* __restrict__ out)               // [1280][512]
{
  const int S = 20;
  const int b = blockIdx.x >> 1, dir = blockIdx.x & 1;
  const h2f16* wt = dir ? wtr : wtf;
  __shared__ float part[4][1024];
  __shared__ _Float16 hsh[256];
  const int tid = threadIdx.x;
  const int jg = tid >> 8, r = tid & 255, grow = r*4;
  if (tid < 256) hsh[tid] = (_Float16)0.f;
  float cc = 0.f;
  __syncthreads();
  const h2f16* hp2 = reinterpret_cast<const h2f16*>(hsh);
  for (int st=0; st<S; ++st){
    const int t = dir ? (S-1-st) : st;
    float a0=0.f,a1=0.f,a2=0.f,a3=0.f;
    #pragma unroll 8
    for (int jp=0; jp<32; ++jp){
      const h2f16 hv = hp2[jg*32 + jp];
      U4H w; w.u = *reinterpret_cast<const uint4*>(
          reinterpret_cast<const unsigned int*>(wt + (long)(jg*32+jp)*1024 + grow));
      a0 = __builtin_amdgcn_fdot2(hv, w.h[0], a0, false);
      a1 = __builtin_amdgcn_fdot2(hv, w.h[1], a1, false);
      a2 = __builtin_amdgcn_fdot2(hv, w.h[2], a2, false);
      a3 = __builtin_amdgcn_fdot2(hv, w.h[3], a3, false);
    }
    *reinterpret_cast<float4*>(&part[jg][grow]) = make_float4(a0,a1,a2,a3);
    __syncthreads();
    if (tid < 256){
      const float* xrow = xs + ((long)b*S + t)*2048 + dir*1024;
      float g0 = xrow[tid]
               + (part[0][tid]      + part[1][tid])      + (part[2][tid]      + part[3][tid]);
      float g1 = xrow[256+tid]
               + (part[0][256+tid]  + part[1][256+tid])  + (part[2][256+tid]  + part[3][256+tid]);
      float g2 = xrow[512+tid]
               + (part[0][512+tid]  + part[1][512+tid])  + (part[2][512+tid]  + part[3][512+tid]);
      float g3 = xrow[768+tid]
               + (part[0][768+tid]  + part[1][768+tid])  + (part[2][768+tid]  + part[3][768+tid]);
      cc = sigf(g1)*cc + sigf(g0)*tanh_f(g2);
      const float h = sigf(g3)*tanh_f(cc);
      hsh[tid] = (_Float16)h;
      out[((long)b*S + t)*512 + dir*256 + tid] = h;
    }
    __syncthreads();
  }
}

// ---------------------------------------------------------------------------
// K11: final LayerNorm(512) + classifier (5) per row
// ---------------------------------------------------------------------------
__global__ __launch_bounds__(128) void k_lncls(
  const float* __restrict__ in, const float* __restrict__ g,
  const float* __restrict__ b, const float* __restrict__ cw,
  const float* __restrict__ cb, float* __restrict__ out)
{
  const int row = blockIdx.x, tid = threadIdx.x;
  __shared__ float sred[4];
  __shared__ float cred[2][5];
  float4 v = *reinterpret_cast<const float4*>(in + (long)row*512 + tid*4);
  float s  = v.x+v.y+v.z+v.w;
  float sq = v.x*v.x+v.y*v.y+v.z*v.z+v.w*v.w;
  #pragma unroll
  for (int off=32; off>=1; off>>=1){ s += __shfl_xor(s, off); sq += __shfl_xor(sq, off); }
  const int wv = tid>>6;
  if ((tid&63)==0){ sred[wv*2]=s; sred[wv*2+1]=sq; }
  __syncthreads();
  const float S = sred[0]+sred[2], SQ = sred[1]+sred[3];
  const float m = S*(1.f/512.f);
  const float rstd = rsqrtf(SQ*(1.f/512.f) - m*m + 1e-5f);
  float4 gg = *reinterpret_cast<const float4*>(g + tid*4);
  float4 bb = *reinterpret_cast<const float4*>(b + tid*4);
  const float n0 = (v.x-m)*rstd*gg.x + bb.x;
  const float n1 = (v.y-m)*rstd*gg.y + bb.y;
  const float n2 = (v.z-m)*rstd*gg.z + bb.z;
  const float n3 = (v.w-m)*rstd*gg.w + bb.w;
  #pragma unroll
  for (int nc=0; nc<5; ++nc){
    float4 w = *reinterpret_cast<const float4*>(cw + nc*512 + tid*4);
    float p = n0*w.x + n1*w.y + n2*w.z + n3*w.w;
    #pragma unroll
    for (int off=32; off>=1; off>>=1) p += __shfl_xor(p, off);
    if ((tid&63)==0) cred[wv][nc] = p;
  }
  __syncthreads();
  if (tid < 5) out[(long)row*5 + tid] = cred[0][tid] + cred[1][tid] + cb[tid];
}

// ---------------------------------------------------------------------------
extern "C" void kernel_launch(void* const* d_in, const int* in_sizes, int n_in,
                              void* d_out, int out_size, void* d_ws, size_t ws_size,
                              hipStream_t stream)
{
  const float* x     = (const float*)d_in[0];
  const int*   ei    = (const int*)d_in[1];
  const float* w1    = (const float*)d_in[2];
  const float* c1b   = (const float*)d_in[3];
  const float* bg1   = (const float*)d_in[4];
  const float* bb1   = (const float*)d_in[5];
  const float* w2    = (const float*)d_in[6];
  const float* c2b   = (const float*)d_in[7];
  const float* bg2   = (const float*)d_in[8];
  const float* bb2   = (const float*)d_in[9];
  const float* w3    = (const float*)d_in[10];
  const float* c3b   = (const float*)d_in[11];
  const float* bg3   = (const float*)d_in[12];
  const float* bb3   = (const float*)d_in[13];
  const float* gcn0w = (const float*)d_in[14];
  const float* gcn0b = (const float*)d_in[15];
  const float* gcn1w = (const float*)d_in[16];
  const float* gcn1b = (const float*)d_in[17];
  const float* lng   = (const float*)d_in[18];
  const float* lnb   = (const float*)d_in[19];
  const float* wih0  = (const float*)d_in[20];
  const float* whh0  = (const float*)d_in[21];
  const float* bih0  = (const float*)d_in[22];
  const float* bhh0  = (const float*)d_in[23];
  const float* wih0r = (const float*)d_in[24];
  const float* whh0r = (const float*)d_in[25];
  const float* bih0r = (const float*)d_in[26];
  const float* bhh0r = (const float*)d_in[27];
  const float* wih1  = (const float*)d_in[28];
  const float* whh1  = (const float*)d_in[29];
  const float* bih1  = (const float*)d_in[30];
  const float* bhh1  = (const float*)d_in[31];
  const float* wih1r = (const float*)d_in[32];
  const float* whh1r = (const float*)d_in[33];
  const float* bih1r = (const float*)d_in[34];
  const float* bhh1r = (const float*)d_in[35];
  const float* lstmg = (const float*)d_in[36];
  const float* lstmb = (const float*)d_in[37];
  const float* clsw  = (const float*)d_in[38];
  const float* clsb  = (const float*)d_in[39];
  float* ws  = (float*)d_ws;
  float* out = (float*)d_out;

  // workspace layout (floats); total ~7,901,952 floats = 31.6 MB
  float* An    = ws + 0;
  float* feats = ws + 256;
  float* tmp   = ws + 655616;    // [10240][128] (tmp0/tmp1 aliased)
  float* g1b   = ws + 1966336;   // [10240][128]
  float* emb   = ws + 3277056;   // [1280][128]
  float* xs    = ws + 3440896;   // [1280][2048] fused fwd|rev gate inputs
  float* l0    = ws + 6062336;   // [1280][512]
  float* l1    = ws + 6717696;   // [1280][512]
  h2f16* wt0f  = (h2f16*)(ws + 7373056);
  h2f16* wt0r  = (h2f16*)(ws + 7504128);
  h2f16* wt1f  = (h2f16*)(ws + 7635200);
  h2f16* wt1r  = (h2f16*)(ws + 7766272);
  _Float16* bw2g = (_Float16*)(ws + 7897344);   // 3072 f16
  _Float16* bw3g = (_Float16*)(ws + 7898880);   // 6144 f16

  // Stage 0: weight packs (k_conv depends on k_packw via stream order)
  k_packw<<<24, 256, 0, stream>>>(w2, w3, bw2g, bw3g);
  // Stage 1: conv front-end
  k_conv<<<10240, 256, 0, stream>>>(x, w1,c1b,bg1,bb1, bw2g,c2b,bg2,bb2,
                                    bw3g,c3b,bg3,bb3, feats);
  // Adjacency + packed weight transposes (independent of k_conv output)
  k_an<<<1, 64, 0, stream>>>(ei, An);
  k_trp<<<512,256,0,stream>>>(whh0,  wt0f);
  k_trp<<<512,256,0,stream>>>(whh0r, wt0r);
  k_trp<<<512,256,0,stream>>>(whh1,  wt1f);
  k_trp<<<512,256,0,stream>>>(whh1r, wt1r);

  // Stage 2: GCN
  k_gemm64<<<dim3(2, 160), 256, 0, stream>>>(feats, gcn0w, nullptr, nullptr, tmp, 10240, 128, 64, 128);
  k_mix1<<<640,256,0,stream>>>(tmp, An, gcn0b, g1b);
  k_gemm64<<<dim3(2, 160), 256, 0, stream>>>(g1b, gcn1w, nullptr, nullptr, tmp, 10240, 128, 128, 128);
  k_mix2<<<1280,128,0,stream>>>(tmp, An, gcn1b, lng, lnb, emb);

  // Stage 3: BiLSTM layer 0 (fwd|rev gates into one xs buffer, ldc=2048)
  k_gemm64<<<dim3(16, 20), 256, 0, stream>>>(emb, wih0,  bih0,  bhh0,  xs,        1280, 1024, 128, 2048);
  k_gemm64<<<dim3(16, 20), 256, 0, stream>>>(emb, wih0r, bih0r, bhh0r, xs + 1024, 1280, 1024, 128, 2048);
  k_lstm<<<128, 1024, 0, stream>>>(xs, wt0f, wt0r, l0);

  // BiLSTM layer 1
  k_gemm64<<<dim3(16, 20), 256, 0, stream>>>(l0, wih1,  bih1,  bhh1,  xs,        1280, 1024, 512, 2048);
  k_gemm64<<<dim3(16, 20), 256, 0, stream>>>(l0, wih1r, bih1r, bhh1r, xs + 1024, 1280, 1024, 512, 2048);
  k_lstm<<<128, 1024, 0, stream>>>(xs, wt1f, wt1r, l1);

  // Stage 4: LN + classifier
  k_lncls<<<1280, 128, 0, stream>>>(l1, lstmg, lstmb, clsw, clsb, out);
}

// Round 6
// 439.581 us; speedup vs baseline: 3.2567x; 1.0347x over previous
//
#include <hip/hip_runtime.h>
#include <hip/hip_bf16.h>

#define DEVI __device__ __forceinline__

typedef _Float16 h2f16 __attribute__((ext_vector_type(2)));
typedef _Float16 f16x8 __attribute__((ext_vector_type(8)));
typedef float    f32x4 __attribute__((ext_vector_type(4)));
union U4H { uint4 u; h2f16 h[4]; };

DEVI float sigf(float x){ return 1.f/(1.f + __expf(-x)); }
DEVI float tanh_f(float x){
  float ax = fabsf(x);
  float e = __expf(-2.f*ax);
  float t = (1.f - e)/(1.f + e);
  return copysignf(t, x);
}
DEVI h2f16 hmax2(h2f16 a, h2f16 b){
  h2f16 r; r[0] = a[0] > b[0] ? a[0] : b[0]; r[1] = a[1] > b[1] ? a[1] : b[1]; return r;
}
// LDS XOR swizzle: XOR 16B-block bits 0,1 with bits 2,3 of block index.
// For 32B-row tiles sigma=(r>>1)&3; for 64B-row tiles sigma=r&3. 2-way max.
DEVI int swz(int L){ return L ^ (((L>>6)&3)<<4); }

// ---------------------------------------------------------------------------
// K0: pack conv2/conv3 weights to f16 in MFMA fragment order.
// bw2f[((s*2+nt)*4+g)*128 + m*8 + j]: kk=32s+8g+j (k=kk>>4, ic=kk&15), oc=nt*16+m
// bw3f[((s*4+wv)*4+g)*128 + m*8 + j]: kk=32s+8g+j (k=kk>>5, ic=kk&31), oc=wv*16+m
// ---------------------------------------------------------------------------
__global__ __launch_bounds__(256) void k_packw(
  const float* __restrict__ w2, const float* __restrict__ w3,
  _Float16* __restrict__ bw2f, _Float16* __restrict__ bw3f)
{
  const int i = blockIdx.x*256 + threadIdx.x;
  if (i < 3072){
    const int j = i&7, m = (i>>3)&15, g = (i>>7)&3, nt = (i>>9)&1, s = i>>10;
    const int kk = 32*s + 8*g + j;
    const int k = kk >> 4, ic = kk & 15, oc = nt*16 + m;
    bw2f[i] = (_Float16)(k < 5 ? w2[oc*80 + ic*5 + k] : 0.f);
  }
  if (i < 6144){
    const int j = i&7, m = (i>>3)&15, g = (i>>7)&3, wv = (i>>9)&3, s = i>>11;
    const int kk = 32*s + 8*g + j;
    const int k = kk >> 5, ic = kk & 31, oc = wv*16 + m;
    bw3f[i] = (_Float16)w3[oc*96 + ic*3 + k];
  }
}

// ---------------------------------------------------------------------------
// K1: fused conv front-end. One block per signal (B*S*C = 10240 signals).
// Phase A (conv1+bn+relu+pool): scalar f32 VALU.
// Phase B (conv2), C (conv3): MFMA 16x16x32 f16, swizzled LDS tiles.
// ~32.7KB LDS -> 4 blocks/CU.
// ---------------------------------------------------------------------------
__global__ __launch_bounds__(256,4) void k_conv(
    const float* __restrict__ x,
    const float* __restrict__ w1g, const float* __restrict__ c1b,
    const float* __restrict__ bg1, const float* __restrict__ bb1,
    const _Float16* __restrict__ bw2f,
    const float* __restrict__ c2b, const float* __restrict__ bg2, const float* __restrict__ bb2,
    const _Float16* __restrict__ bw3f,
    const float* __restrict__ c3b, const float* __restrict__ bg3, const float* __restrict__ bb3,
    float* __restrict__ feats)
{
  // byte pool (phase-aliased):
  //   region0 [0,16128):      s1t  f16 [504][16] swz   (A-write, B-read)
  //                     then  s2t  f16 [98][32]  swz   (pool-write, C-read)
  //   region1 [16128,32128):  sx   f32 [3012]          (A only)
  //                     then  s2pre f16 [250][32] lin  (B-write, pool-read)
  __shared__ __align__(16) unsigned char smb[32128];
  __shared__ float w1s[112];
  __shared__ float kb1[32], kb2[64], kb3[128];
  float*    sx    = reinterpret_cast<float*>(smb + 16128);
  _Float16* s2pre = reinterpret_cast<_Float16*>(smb + 16128);
  const int tid = threadIdx.x;
  const long sig = blockIdx.x;
  const float* xg = x + sig*3000;

  // stage x (float4) + pads + conv1 weights + folded BN consts
  {
    const float4* xg4 = reinterpret_cast<const float4*>(xg);
    float4* sx4 = reinterpret_cast<float4*>(sx+4);
    for (int i=tid; i<750; i+=256) sx4[i] = xg4[i];
    if (tid<4)  sx[tid]=0.f;
    if (tid<8)  sx[3004+tid]=0.f;
    if (tid<32){  // s1t pad rows 0,1 (pos -2,-1) and 502,503 (pos 500,501)
      const int r = tid>>4, c = tid&15;
      *reinterpret_cast<_Float16*>(smb + swz(r*32 + c*2)) = (_Float16)0.f;
      *reinterpret_cast<_Float16*>(smb + swz((502+r)*32 + c*2)) = (_Float16)0.f;
    }
    if (tid<112) w1s[tid]=w1g[tid];
    const float rs = rsqrtf(1.f+1e-5f);
    if (tid<16){ float s=bg1[tid]*rs; kb1[2*tid]=s; kb1[2*tid+1]=c1b[tid]*s+bb1[tid]; }
    if (tid<32){ float s=bg2[tid]*rs; kb2[2*tid]=s; kb2[2*tid+1]=c2b[tid]*s+bb2[tid]; }
    if (tid<64){ float s=bg3[tid]*rs; kb3[2*tid]=s; kb3[2*tid+1]=c3b[tid]*s+bb3[tid]; }
  }
  __syncthreads();

  // Phase A: conv1+bn+relu+pool -> s1t[pos+2][c] (f16, swz), 16ch x 500
  {
    const int c = tid & 15;
    const float s = kb1[2*c], o = kb1[2*c+1];
    float wr[7];
    #pragma unroll
    for (int k=0;k<7;k++) wr[k] = w1s[c*7+k];
    for (int u = tid>>4; u<500; u+=16){
      const float* xb = sx + 6*u + 1;
      float xv[11];
      #pragma unroll
      for (int r=0;r<11;r++) xv[r] = xb[r];
      float a0=0.f,a1=0.f,a2=0.f;
      #pragma unroll
      for (int k=0;k<7;k++){ float w=wr[k]; a0 += xv[k]*w; a1 += xv[k+2]*w; a2 += xv[k+4]*w; }
      float y = fmaxf(fmaxf(a0*s+o, a1*s+o), a2*s+o);
      *reinterpret_cast<_Float16*>(smb + swz((u+2)*32 + c*2)) = (_Float16)fmaxf(y, 0.f);
    }
  }
  __syncthreads();

  const int wv = tid >> 6, lane = tid & 63;
  const int m = lane & 15, g = lane >> 4;

  // Phase B: conv2 as MFMA. M=256 (t), K=96 (kk=k*16+ic), N=32 (oc).
  // A[t][kk] = s1t[2t+k][ic] (swz reads); B from bw2f fragment-order.
  {
    const int nt = wv & 1;
    f16x8 bf[3];
    #pragma unroll
    for (int s=0;s<3;s++)
      bf[s] = *reinterpret_cast<const f16x8*>(&bw2f[(((s*2+nt)*4+g)*16+m)*8]);
    const int oc = nt*16 + m;
    const float sc = kb2[2*oc], of = kb2[2*oc+1];
    #pragma unroll
    for (int i=0;i<8;i++){
      const int mt = (wv>>1) + 2*i;
      const int trow = mt*16 + m;
      f32x4 acc = {0.f,0.f,0.f,0.f};
      #pragma unroll
      for (int s=0;s<3;s++){
        const int kk = 32*s + 8*g;
        const int k = kk >> 4, ic0 = kk & 15;
        f16x8 af = *reinterpret_cast<const f16x8*>(smb + swz((2*trow + k)*32 + ic0*2));
        acc = __builtin_amdgcn_mfma_f32_16x16x32_f16(af, bf[s], acc, 0,0,0);
      }
      #pragma unroll
      for (int r=0;r<4;r++){
        const int t = mt*16 + 4*g + r;
        if (t < 250){
          float z = fmaxf(acc[r]*sc + of, 0.f);
          s2pre[t*32 + oc] = (_Float16)z;
        }
      }
    }
  }
  __syncthreads();

  // Pool: s2t[u+1][oc] = max3 rows of s2pre (read lin, write swz); pad rows.
  {
    const h2f16* s2ph = reinterpret_cast<const h2f16*>(s2pre);
    if (tid < 240){
      const int rr = tid >> 4, cc = tid & 15;
      const int row = (rr == 0) ? 0 : (83 + rr);
      h2f16 z; z[0]=(_Float16)0.f; z[1]=(_Float16)0.f;
      *reinterpret_cast<h2f16*>(smb + swz(row*64 + cc*4)) = z;
    }
    for (int i=tid; i<1328; i+=256){
      const int u = i >> 4, cc = i & 15;
      h2f16 a = s2ph[(3*u)*16 + cc];
      h2f16 b = s2ph[(3*u+1)*16 + cc];
      h2f16 c = s2ph[(3*u+2)*16 + cc];
      *reinterpret_cast<h2f16*>(smb + swz((u+1)*64 + cc*4)) = hmax2(hmax2(a,b), c);
    }
  }
  __syncthreads();

  // Phase C: conv3 as MFMA + bn+relu+mean. M=96 (t), K=96 (kk=k*32+ic), N=64.
  // A[t][kk] = s2t[t+k][ic] (swz reads); B from bw3f fragment-order.
  {
    f16x8 bf[3];
    #pragma unroll
    for (int s=0;s<3;s++)
      bf[s] = *reinterpret_cast<const f16x8*>(&bw3f[(((s*4+wv)*4+g)*16+m)*8]);
    const int oc = wv*16 + m;
    const float sc = kb3[2*oc], of = kb3[2*oc+1];
    float macc = 0.f;
    #pragma unroll
    for (int mt=0; mt<6; mt++){
      const int trow = mt*16 + m;
      f32x4 acc = {0.f,0.f,0.f,0.f};
      #pragma unroll
      for (int s=0;s<3;s++){
        f16x8 af = *reinterpret_cast<const f16x8*>(smb + swz((trow + s)*64 + 16*g));
        acc = __builtin_amdgcn_mfma_f32_16x16x32_f16(af, bf[s], acc, 0,0,0);
      }
      #pragma unroll
      for (int r=0;r<4;r++){
        const int t = mt*16 + 4*g + r;
        if (t < 83) macc += fmaxf(acc[r]*sc + of, 0.f);
      }
    }
    macc += __shfl_xor(macc, 16);
    macc += __shfl_xor(macc, 32);
    if (lane < 16) feats[sig*64 + oc] = macc * (1.f/83.f);
  }
}

// ---------------------------------------------------------------------------
// K2: build normalized adjacency An (8x8) from edge_index (2,56)
// ---------------------------------------------------------------------------
__global__ void k_an(const int* __restrict__ ei, float* __restrict__ an){
  __shared__ float A[64];
  __shared__ float dinv[8];
  const int tid = threadIdx.x;
  if (tid<64) A[tid] = ((tid>>3)==(tid&7)) ? 1.f : 0.f;
  __syncthreads();
  if (tid==0){
    for (int e=0;e<56;e++){ int s=ei[e], d=ei[56+e]; A[d*8+s] += 1.f; }
  }
  __syncthreads();
  if (tid<8){ float s=0.f; for (int j=0;j<8;j++) s+=A[tid*8+j]; dinv[tid]=rsqrtf(s); }
  __syncthreads();
  if (tid<64) an[tid] = A[tid]*dinv[tid>>3]*dinv[tid&7];
}

// ---------------------------------------------------------------------------
// f32 GEMM: C[M,N] = X[M,K] @ W[N,K]^T (+b1 +b2), tile 64x64, BK=16, ldc param.
// ---------------------------------------------------------------------------
__global__ __launch_bounds__(256) void k_gemm64(
  const float* __restrict__ X, const float* __restrict__ W,
  const float* __restrict__ b1, const float* __restrict__ b2,
  float* __restrict__ C, int M, int N, int K, int ldc)
{
  __shared__ float Xs[16][68];
  __shared__ float Ws[16][68];
  const int tid = threadIdx.x;
  const int m0 = blockIdx.y*64, n0 = blockIdx.x*64;
  const int tm = tid >> 4, tn = tid & 15;
  const int lr = tid >> 2, lk = (tid & 3)*4;
  float acc[4][4] = {};
  for (int k0=0; k0<K; k0+=16){
    float4 xa = *reinterpret_cast<const float4*>(X + (long)(m0+lr)*K + k0 + lk);
    float4 wa = *reinterpret_cast<const float4*>(W + (long)(n0+lr)*K + k0 + lk);
    __syncthreads();
    Xs[lk+0][lr]=xa.x; Xs[lk+1][lr]=xa.y; Xs[lk+2][lr]=xa.z; Xs[lk+3][lr]=xa.w;
    Ws[lk+0][lr]=wa.x; Ws[lk+1][lr]=wa.y; Ws[lk+2][lr]=wa.z; Ws[lk+3][lr]=wa.w;
    __syncthreads();
    #pragma unroll
    for (int kk=0;kk<16;kk++){
      float4 a  = *reinterpret_cast<const float4*>(&Xs[kk][tm*4]);
      float4 bv = *reinterpret_cast<const float4*>(&Ws[kk][tn*4]);
      float av[4]={a.x,a.y,a.z,a.w}, bb[4]={bv.x,bv.y,bv.z,bv.w};
      #pragma unroll
      for (int i=0;i<4;i++)
        #pragma unroll
        for (int j=0;j<4;j++) acc[i][j] += av[i]*bb[j];
    }
  }
  float bias[4] = {0.f,0.f,0.f,0.f};
  if (b1){ float4 t = *reinterpret_cast<const float4*>(b1 + n0 + tn*4);
           bias[0]+=t.x; bias[1]+=t.y; bias[2]+=t.z; bias[3]+=t.w; }
  if (b2){ float4 t = *reinterpret_cast<const float4*>(b2 + n0 + tn*4);
           bias[0]+=t.x; bias[1]+=t.y; bias[2]+=t.z; bias[3]+=t.w; }
  #pragma unroll
  for (int i=0;i<4;i++){
    float4 o;
    o.x = acc[i][0]+bias[0]; o.y = acc[i][1]+bias[1];
    o.z = acc[i][2]+bias[2]; o.w = acc[i][3]+bias[3];
    *reinterpret_cast<float4*>(C + (long)(m0+tm*4+i)*ldc + n0 + tn*4) = o;
  }
}

// ---------------------------------------------------------------------------
// K4: g1[g][i][j] = relu( sum_c An[i][c]*tmp0[g][c][j] + b0[j] )
// ---------------------------------------------------------------------------
__global__ __launch_bounds__(256) void k_mix1(
  const float* __restrict__ tmp0, const float* __restrict__ An,
  const float* __restrict__ b0, float* __restrict__ g1)
{
  __shared__ float ans[64];
  if (threadIdx.x < 64) ans[threadIdx.x] = An[threadIdx.x];
  __syncthreads();
  const long idx = (long)blockIdx.x*256 + threadIdx.x;   // over 1280*128
  const int g = (int)(idx >> 7), j = (int)(idx & 127);
  const float* base = tmp0 + (long)g*1024;
  float t[8];
  #pragma unroll
  for (int c=0;c<8;c++) t[c] = base[c*128+j];
  const float bj = b0[j];
  #pragma unroll
  for (int i=0;i<8;i++){
    float s = bj;
    #pragma unroll
    for (int c=0;c<8;c++) s += ans[i*8+c]*t[c];
    g1[(long)g*1024 + i*128 + j] = fmaxf(s, 0.f);
  }
}

// ---------------------------------------------------------------------------
// K6: g2 = An@tmp1 + b1 ; LN over j (128) per row ; mean over 8 nodes -> emb
// ---------------------------------------------------------------------------
__global__ __launch_bounds__(128) void k_mix2(
  const float* __restrict__ tmp1, const float* __restrict__ An,
  const float* __restrict__ b1, const float* __restrict__ lng,
  const float* __restrict__ lnb, float* __restrict__ emb)
{
  const int g = blockIdx.x, j = threadIdx.x;
  __shared__ float ans[64];
  __shared__ float g2s[8*128];
  __shared__ float stats[16];
  if (j<64) ans[j] = An[j];
  const float* base = tmp1 + (long)g*1024;
  float t[8];
  #pragma unroll
  for (int c=0;c<8;c++) t[c] = base[c*128 + j];
  const float bj = b1[j];
  __syncthreads();
  #pragma unroll
  for (int i=0;i<8;i++){
    float s = bj;
    #pragma unroll
    for (int c=0;c<8;c++) s += ans[i*8+c]*t[c];
    g2s[i*128+j] = s;
  }
  __syncthreads();
  {
    const int c = j>>4, l = j&15;
    float s=0.f, sq=0.f;
    for (int jj=l; jj<128; jj+=16){ float v=g2s[c*128+jj]; s+=v; sq+=v*v; }
    #pragma unroll
    for (int off=8; off>=1; off>>=1){ s += __shfl_xor(s, off); sq += __shfl_xor(sq, off); }
    if (l==0){
      float m = s*(1.f/128.f);
      stats[2*c] = m;
      stats[2*c+1] = rsqrtf(sq*(1.f/128.f) - m*m + 1e-5f);
    }
  }
  __syncthreads();
  float acc=0.f;
  #pragma unroll
  for (int i=0;i<8;i++) acc += (g2s[i*128+j] - stats[2*i]) * stats[2*i+1];
  emb[(long)g*128 + j] = lng[j]*acc*0.125f + lnb[j];
}

// ---------------------------------------------------------------------------
// K7: transpose+pack w_hh (1024,256) f32 -> wtp[jp][g] = (w[g][2jp], w[g][2jp+1]) f16x2
// ---------------------------------------------------------------------------
__global__ __launch_bounds__(256) void k_trp(
  const float* __restrict__ in, h2f16* __restrict__ outp)
{
  const int i = blockIdx.x*256 + threadIdx.x;   // 131072
  const int g = i & 1023, jp = i >> 10;
  h2f16 p;
  p[0] = (_Float16)in[g*256 + 2*jp];
  p[1] = (_Float16)in[g*256 + 2*jp + 1];
  outp[(long)jp*1024 + g] = p;
}

// ---------------------------------------------------------------------------
// K8: one LSTM layer, both directions. Block = (batch, dir), 1024 threads.
// ---------------------------------------------------------------------------
__global__ __launch_bounds__(1024) void k_lstm(
    const float* __restrict__ xs,          // [1280][2048] fwd|rev gates
    const h2f16* __restrict__ wtf,         // [128][1024] packed j-pairs
    const h2f16* __restrict__ wtr,
    float* __restrict__ out)               // [1280][512]
{
  const int S = 20;
  const int b = blockIdx.x >> 1, dir = blockIdx.x & 1;
  const h2f16* wt = dir ? wtr : wtf;
  __shared__ float part[4][1024];
  __shared__ _Float16 hsh[256];
  const int tid = threadIdx.x;
  const int jg = tid >> 8, r = tid & 255, grow = r*4;
  if (tid < 256) hsh[tid] = (_Float16)0.f;
  float cc = 0.f;
  __syncthreads();
  const h2f16* hp2 = reinterpret_cast<const h2f16*>(hsh);
  for (int st=0; st<S; ++st){
    const int t = dir ? (S-1-st) : st;
    float a0=0.f,a1=0.f,a2=0.f,a3=0.f;
    #pragma unroll 8
    for (int jp=0; jp<32; ++jp){
      const h2f16 hv = hp2[jg*32 + jp];
      U4H w; w.u = *reinterpret_cast<const uint4*>(
          reinterpret_cast<const unsigned int*>(wt + (long)(jg*32+jp)*1024 + grow));
      a0 = __builtin_amdgcn_fdot2(hv, w.h[0], a0, false);
      a1 = __builtin_amdgcn_fdot2(hv, w.h[1], a1, false);
      a2 = __builtin_amdgcn_fdot2(hv, w.h[2], a2, false);
      a3 = __builtin_amdgcn_fdot2(hv, w.h[3], a3, false);
    }
    *reinterpret_cast<float4*>(&part[jg][grow]) = make_float4(a0,a1,a2,a3);
    __syncthreads();
    if (tid < 256){
      const float* xrow = xs + ((long)b*S + t)*2048 + dir*1024;
      float g0 = xrow[tid]
               + (part[0][tid]      + part[1][tid])      + (part[2][tid]      + part[3][tid]);
      float g1 = xrow[256+tid]
               + (part[0][256+tid]  + part[1][256+tid])  + (part[2][256+tid]  + part[3][256+tid]);
      float g2 = xrow[512+tid]
               + (part[0][512+tid]  + part[1][512+tid])  + (part[2][512+tid]  + part[3][512+tid]);
      float g3 = xrow[768+tid]
               + (part[0][768+tid]  + part[1][768+tid])  + (part[2][768+tid]  + part[3][768+tid]);
      cc = sigf(g1)*cc + sigf(g0)*tanh_f(g2);
      const float h = sigf(g3)*tanh_f(cc);
      hsh[tid] = (_Float16)h;
      out[((long)b*S + t)*512 + dir*256 + tid] = h;
    }
    __syncthreads();
  }
}

// ---------------------------------------------------------------------------
// K11: final LayerNorm(512) + classifier (5) per row
// ---------------------------------------------------------------------------
__global__ __launch_bounds__(128) void k_lncls(
  const float* __restrict__ in, const float* __restrict__ g,
  const float* __restrict__ b, const float* __restrict__ cw,
  const float* __restrict__ cb, float* __restrict__ out)
{
  const int row = blockIdx.x, tid = threadIdx.x;
  __shared__ float sred[4];
  __shared__ float cred[2][5];
  float4 v = *reinterpret_cast<const float4*>(in + (long)row*512 + tid*4);
  float s  = v.x+v.y+v.z+v.w;
  float sq = v.x*v.x+v.y*v.y+v.z*v.z+v.w*v.w;
  #pragma unroll
  for (int off=32; off>=1; off>>=1){ s += __shfl_xor(s, off); sq += __shfl_xor(sq, off); }
  const int wv = tid>>6;
  if ((tid&63)==0){ sred[wv*2]=s; sred[wv*2+1]=sq; }
  __syncthreads();
  const float S = sred[0]+sred[2], SQ = sred[1]+sred[3];
  const float m = S*(1.f/512.f);
  const float rstd = rsqrtf(SQ*(1.f/512.f) - m*m + 1e-5f);
  float4 gg = *reinterpret_cast<const float4*>(g + tid*4);
  float4 bb = *reinterpret_cast<const float4*>(b + tid*4);
  const float n0 = (v.x-m)*rstd*gg.x + bb.x;
  const float n1 = (v.y-m)*rstd*gg.y + bb.y;
  const float n2 = (v.z-m)*rstd*gg.z + bb.z;
  const float n3 = (v.w-m)*rstd*gg.w + bb.w;
  #pragma unroll
  for (int nc=0; nc<5; ++nc){
    float4 w = *reinterpret_cast<const float4*>(cw + nc*512 + tid*4);
    float p = n0*w.x + n1*w.y + n2*w.z + n3*w.w;
    #pragma unroll
    for (int off=32; off>=1; off>>=1) p += __shfl_xor(p, off);
    if ((tid&63)==0) cred[wv][nc] = p;
  }
  __syncthreads();
  if (tid < 5) out[(long)row*5 + tid] = cred[0][tid] + cred[1][tid] + cb[tid];
}

// ---------------------------------------------------------------------------
extern "C" void kernel_launch(void* const* d_in, const int* in_sizes, int n_in,
                              void* d_out, int out_size, void* d_ws, size_t ws_size,
                              hipStream_t stream)
{
  const float* x     = (const float*)d_in[0];
  const int*   ei    = (const int*)d_in[1];
  const float* w1    = (const float*)d_in[2];
  const float* c1b   = (const float*)d_in[3];
  const float* bg1   = (const float*)d_in[4];
  const float* bb1   = (const float*)d_in[5];
  const float* w2    = (const float*)d_in[6];
  const float* c2b   = (const float*)d_in[7];
  const float* bg2   = (const float*)d_in[8];
  const float* bb2   = (const float*)d_in[9];
  const float* w3    = (const float*)d_in[10];
  const float* c3b   = (const float*)d_in[11];
  const float* bg3   = (const float*)d_in[12];
  const float* bb3   = (const float*)d_in[13];
  const float* gcn0w = (const float*)d_in[14];
  const float* gcn0b = (const float*)d_in[15];
  const float* gcn1w = (const float*)d_in[16];
  const float* gcn1b = (const float*)d_in[17];
  const float* lng   = (const float*)d_in[18];
  const float* lnb   = (const float*)d_in[19];
  const float* wih0  = (const float*)d_in[20];
  const float* whh0  = (const float*)d_in[21];
  const float* bih0  = (const float*)d_in[22];
  const float* bhh0  = (const float*)d_in[23];
  const float* wih0r = (const float*)d_in[24];
  const float* whh0r = (const float*)d_in[25];
  const float* bih0r = (const float*)d_in[26];
  const float* bhh0r = (const float*)d_in[27];
  const float* wih1  = (const float*)d_in[28];
  const float* whh1  = (const float*)d_in[29];
  const float* bih1  = (const float*)d_in[30];
  const float* bhh1  = (const float*)d_in[31];
  const float* wih1r = (const float*)d_in[32];
  const float* whh1r = (const float*)d_in[33];
  const float* bih1r = (const float*)d_in[34];
  const float* bhh1r = (const float*)d_in[35];
  const float* lstmg = (const float*)d_in[36];
  const float* lstmb = (const float*)d_in[37];
  const float* clsw  = (const float*)d_in[38];
  const float* clsb  = (const float*)d_in[39];
  float* ws  = (float*)d_ws;
  float* out = (float*)d_out;

  // workspace layout (floats)
  float* An    = ws + 0;
  float* feats = ws + 256;
  float* tmp   = ws + 655616;    // [10240][128] (tmp0/tmp1 aliased)
  float* g1b   = ws + 1966336;   // [10240][128]
  float* emb   = ws + 3277056;   // [1280][128]
  float* xs    = ws + 3440896;   // [1280][2048] fused fwd|rev gate inputs
  float* l0    = ws + 6062336;   // [1280][512]
  float* l1    = ws + 6717696;   // [1280][512]
  h2f16* wt0f  = (h2f16*)(ws + 7373056);
  h2f16* wt0r  = (h2f16*)(ws + 7504128);
  h2f16* wt1f  = (h2f16*)(ws + 7635200);
  h2f16* wt1r  = (h2f16*)(ws + 7766272);
  _Float16* bw2f = (_Float16*)(ws + 7897344);   // 3072 f16
  _Float16* bw3f = (_Float16*)(ws + 7898880);   // 6144 f16

  // Stage 0: weight packs (k_conv depends on k_packw via stream order)
  k_packw<<<24, 256, 0, stream>>>(w2, w3, bw2f, bw3f);
  // Stage 1: conv front-end
  k_conv<<<10240, 256, 0, stream>>>(x, w1,c1b,bg1,bb1, bw2f,c2b,bg2,bb2,
                                    bw3f,c3b,bg3,bb3, feats);
  // Adjacency + packed weight transposes (independent of k_conv output)
  k_an<<<1, 64, 0, stream>>>(ei, An);
  k_trp<<<512,256,0,stream>>>(whh0,  wt0f);
  k_trp<<<512,256,0,stream>>>(whh0r, wt0r);
  k_trp<<<512,256,0,stream>>>(whh1,  wt1f);
  k_trp<<<512,256,0,stream>>>(whh1r, wt1r);

  // Stage 2: GCN
  k_gemm64<<<dim3(2, 160), 256, 0, stream>>>(feats, gcn0w, nullptr, nullptr, tmp, 10240, 128, 64, 128);
  k_mix1<<<640,256,0,stream>>>(tmp, An, gcn0b, g1b);
  k_gemm64<<<dim3(2, 160), 256, 0, stream>>>(g1b, gcn1w, nullptr, nullptr, tmp, 10240, 128, 128, 128);
  k_mix2<<<1280,128,0,stream>>>(tmp, An, gcn1b, lng, lnb, emb);

  // Stage 3: BiLSTM layer 0 (fwd|rev gates into one xs buffer, ldc=2048)
  k_gemm64<<<dim3(16, 20), 256, 0, stream>>>(emb, wih0,  bih0,  bhh0,  xs,        1280, 1024, 128, 2048);
  k_gemm64<<<dim3(16, 20), 256, 0, stream>>>(emb, wih0r, bih0r, bhh0r, xs + 1024, 1280, 1024, 128, 2048);
  k_lstm<<<128, 1024, 0, stream>>>(xs, wt0f, wt0r, l0);

  // BiLSTM layer 1
  k_gemm64<<<dim3(16, 20), 256, 0, stream>>>(l0, wih1,  bih1,  bhh1,  xs,        1280, 1024, 512, 2048);
  k_gemm64<<<dim3(16, 20), 256, 0, stream>>>(l0, wih1r, bih1r, bhh1r, xs + 1024, 1280, 1024, 512, 2048);
  k_lstm<<<128, 1024, 0, stream>>>(xs, wt1f, wt1r, l1);

  // Stage 4: LN + classifier
  k_lncls<<<1280, 128, 0, stream>>>(l1, lstmg, lstmb, clsw, clsb, out);
}

// Round 7
// 413.362 us; speedup vs baseline: 3.4633x; 1.0634x over previous
//
#include <hip/hip_runtime.h>
#include <hip/hip_bf16.h>

#define DEVI __device__ __forceinline__

typedef _Float16 h2f16 __attribute__((ext_vector_type(2)));
typedef _Float16 f16x4 __attribute__((ext_vector_type(4)));
typedef _Float16 f16x8 __attribute__((ext_vector_type(8)));
typedef float    f32x4 __attribute__((ext_vector_type(4)));
union U4H { uint4 u; h2f16 h[4]; };
union F8  { f16x8 v8; f16x4 v4[2]; };

DEVI float sigf(float x){ return 1.f/(1.f + __expf(-x)); }
DEVI float tanh_f(float x){
  float ax = fabsf(x);
  float e = __expf(-2.f*ax);
  float t = (1.f - e)/(1.f + e);
  return copysignf(t, x);
}
DEVI h2f16 hmax2(h2f16 a, h2f16 b){
  h2f16 r; r[0] = a[0] > b[0] ? a[0] : b[0]; r[1] = a[1] > b[1] ? a[1] : b[1]; return r;
}

// ---------------------------------------------------------------------------
// K0: pack conv2/conv3 weights to f16, MFMA fragment order, BN scale folded.
// ---------------------------------------------------------------------------
__global__ __launch_bounds__(256) void k_packw(
  const float* __restrict__ w2, const float* __restrict__ w3,
  const float* __restrict__ bg2, const float* __restrict__ bg3,
  _Float16* __restrict__ bw2f, _Float16* __restrict__ bw3f)
{
  const int i = blockIdx.x*256 + threadIdx.x;
  const float rs = rsqrtf(1.f+1e-5f);
  if (i < 3072){
    const int j = i&7, m = (i>>3)&15, g = (i>>7)&3, nt = (i>>9)&1, s = i>>10;
    const int kk = 32*s + 8*g + j;
    const int k = kk >> 4, ic = kk & 15, oc = nt*16 + m;
    bw2f[i] = (_Float16)((k < 5 ? w2[oc*80 + ic*5 + k] : 0.f) * (bg2[oc]*rs));
  }
  if (i < 6144){
    const int j = i&7, m = (i>>3)&15, g = (i>>7)&3, wv = (i>>9)&3, s = i>>11;
    const int kk = 32*s + 8*g + j;
    const int k = kk >> 5, ic = kk & 31, oc = wv*16 + m;
    bw3f[i] = (_Float16)(w3[oc*96 + ic*3 + k] * (bg3[oc]*rs));
  }
}

// ---------------------------------------------------------------------------
// K1: fused conv front-end. One block per signal (B*S*C = 10240 signals).
// Phase A: conv1 via fdot2 (f16 pairs), 2 channels/thread, BN-scale folded.
// Phase B (conv2), C (conv3): MFMA 16x16x32 f16; padded LDS row strides
// (s1t 40B, s2pre 72B, s2t 80B) for conflict-free fragment reads/writes.
// ~39.2KB LDS -> 4 blocks/CU.
// ---------------------------------------------------------------------------
__global__ __launch_bounds__(256,4) void k_conv(
    const float* __restrict__ x,
    const float* __restrict__ w1g, const float* __restrict__ c1b,
    const float* __restrict__ bg1, const float* __restrict__ bb1,
    const _Float16* __restrict__ bw2f,
    const float* __restrict__ c2b, const float* __restrict__ bg2, const float* __restrict__ bb2,
    const _Float16* __restrict__ bw3f,
    const float* __restrict__ c3b, const float* __restrict__ bg3, const float* __restrict__ bb3,
    float* __restrict__ feats)
{
  // byte pool:
  //   region0 [0,20160):      s1t f16 [504] rows, stride 40B (A-write, B-read)
  //                     then  s2t f16 [98] rows, stride 80B (pool-write, C-read)
  //   region1 [20160,38592):  sxh h2f16[1503+pad]            (A only)
  //                     then  s2pre f16 [256] rows stride 72B (B-write, pool-read)
  __shared__ __align__(16) unsigned char smb[38592];
  __shared__ h2f16 w1p[16][4];
  __shared__ float kb1o[16], kb2o[32], kb3o[64];
  h2f16* sxh = reinterpret_cast<h2f16*>(smb + 20160);
  const int tid = threadIdx.x;
  const long sig = blockIdx.x;
  const float* xg = x + sig*3000;

  // stage x as f16 pairs (arr idx q+2), pads, folded conv1 weight pairs, offsets
  {
    const float4* xg4 = reinterpret_cast<const float4*>(xg);
    for (int i=tid; i<750; i+=256){
      float4 v = xg4[i];
      h2f16 p0; p0[0]=(_Float16)v.x; p0[1]=(_Float16)v.y;
      h2f16 p1; p1[0]=(_Float16)v.z; p1[1]=(_Float16)v.w;
      sxh[2*i+2] = p0; sxh[2*i+3] = p1;
    }
    if (tid<3){
      h2f16 z; z[0]=(_Float16)0.f; z[1]=(_Float16)0.f;
      sxh[tid<2 ? tid : 1502] = z;
    }
    if (tid<32){   // s1t pad rows 0,1 (pos -2,-1) and 502,503
      const int rr = tid>>3, cp = tid&7;
      const int row = (rr<2) ? rr : (500+rr);
      h2f16 z; z[0]=(_Float16)0.f; z[1]=(_Float16)0.f;
      *reinterpret_cast<h2f16*>(smb + row*40 + 4*cp) = z;
    }
    const float rs = rsqrtf(1.f+1e-5f);
    if (tid<64){
      const int c = tid>>2, j = tid&3;
      const float s = bg1[c]*rs;
      h2f16 p;
      if (j==0){ p[0]=(_Float16)0.f; p[1]=(_Float16)(w1g[c*7+0]*s); }
      else     { p[0]=(_Float16)(w1g[c*7+2*j-1]*s); p[1]=(_Float16)(w1g[c*7+2*j]*s); }
      w1p[c][j] = p;
    }
    if (tid<16) kb1o[tid] = c1b[tid]*(bg1[tid]*rs) + bb1[tid];
    if (tid<32) kb2o[tid] = c2b[tid]*(bg2[tid]*rs) + bb2[tid];
    if (tid<64) kb3o[tid] = c3b[tid]*(bg3[tid]*rs) + bb3[tid];
  }
  __syncthreads();

  // Phase A: conv1+bn+relu+pool -> s1t rows (u+2), 2 channels per thread
  {
    const int cp = tid & 7;          // channels 2cp, 2cp+1
    h2f16 wpa[4], wpb[4];
    #pragma unroll
    for (int j=0;j<4;j++){ wpa[j] = w1p[2*cp][j]; wpb[j] = w1p[2*cp+1][j]; }
    const float oa = kb1o[2*cp], ob = kb1o[2*cp+1];
    for (int u = tid>>3; u<500; u+=32){
      h2f16 xq[6];
      #pragma unroll
      for (int r=0;r<6;r++) xq[r] = sxh[3*u + r];
      float a0=0.f,a1=0.f,a2=0.f,b0=0.f,b1=0.f,b2=0.f;
      #pragma unroll
      for (int j=0;j<4;j++){
        a0 = __builtin_amdgcn_fdot2(xq[j],   wpa[j], a0, false);
        a1 = __builtin_amdgcn_fdot2(xq[j+1], wpa[j], a1, false);
        a2 = __builtin_amdgcn_fdot2(xq[j+2], wpa[j], a2, false);
        b0 = __builtin_amdgcn_fdot2(xq[j],   wpb[j], b0, false);
        b1 = __builtin_amdgcn_fdot2(xq[j+1], wpb[j], b1, false);
        b2 = __builtin_amdgcn_fdot2(xq[j+2], wpb[j], b2, false);
      }
      const float ya = fmaxf(fmaxf(fmaxf(a0,a1),a2) + oa, 0.f);
      const float yb = fmaxf(fmaxf(fmaxf(b0,b1),b2) + ob, 0.f);
      h2f16 p; p[0]=(_Float16)ya; p[1]=(_Float16)yb;
      *reinterpret_cast<h2f16*>(smb + (u+2)*40 + 4*cp) = p;
    }
  }
  __syncthreads();

  const int wv = tid >> 6, lane = tid & 63;
  const int m = lane & 15, g = lane >> 4;

  // Phase B: conv2 as MFMA. M=256 (t), K=96 (kk=k*16+ic), N=32 (oc).
  // A[t][kk] = s1t[2t+k][ic]; byte = 80*trow + 40*k + 16*(g&1).
  {
    const int nt = wv & 1;
    f16x8 bf[3];
    #pragma unroll
    for (int s=0;s<3;s++)
      bf[s] = *reinterpret_cast<const f16x8*>(&bw2f[(((s*2+nt)*4+g)*16+m)*8]);
    const int oc = nt*16 + m;
    const float of = kb2o[oc];
    #pragma unroll
    for (int i=0;i<8;i++){
      const int mt = (wv>>1) + 2*i;
      const int trow = mt*16 + m;
      f32x4 acc = {0.f,0.f,0.f,0.f};
      #pragma unroll
      for (int s=0;s<3;s++){
        const int kk = 32*s + 8*g;
        const int k = kk >> 4;
        const int ab = 80*trow + 40*k + 16*(g&1);
        F8 a;
        a.v4[0] = *reinterpret_cast<const f16x4*>(smb + ab);
        a.v4[1] = *reinterpret_cast<const f16x4*>(smb + ab + 8);
        acc = __builtin_amdgcn_mfma_f32_16x16x32_f16(a.v8, bf[s], acc, 0,0,0);
      }
      #pragma unroll
      for (int r=0;r<4;r++){
        const int t = mt*16 + 4*g + r;
        const float z = fmaxf(acc[r] + of, 0.f);
        *reinterpret_cast<_Float16*>(smb + 20160 + t*72 + 2*oc) = (_Float16)z;
      }
    }
  }
  __syncthreads();

  // Pool: s2t[u+1][oc] = max3 rows of s2pre; zero pad rows 0, 84..97.
  {
    if (tid < 240){
      const int rr = tid >> 4, cc = tid & 15;
      const int row = (rr == 0) ? 0 : (83 + rr);
      h2f16 z; z[0]=(_Float16)0.f; z[1]=(_Float16)0.f;
      *reinterpret_cast<h2f16*>(smb + row*80 + 4*cc) = z;
    }
    for (int i=tid; i<1328; i+=256){
      const int u = i >> 4, cc = i & 15;
      h2f16 a = *reinterpret_cast<const h2f16*>(smb + 20160 + (3*u)*72 + 4*cc);
      h2f16 b = *reinterpret_cast<const h2f16*>(smb + 20160 + (3*u+1)*72 + 4*cc);
      h2f16 c = *reinterpret_cast<const h2f16*>(smb + 20160 + (3*u+2)*72 + 4*cc);
      *reinterpret_cast<h2f16*>(smb + (u+1)*80 + 4*cc) = hmax2(hmax2(a,b), c);
    }
  }
  __syncthreads();

  // Phase C: conv3 as MFMA + bn+relu+mean. M=96 (t), K=96 (kk=k*32+ic), N=64.
  // A[t][kk] = s2t[t+k][ic]; byte = (trow+s)*80 + 16*g (16B-aligned b128).
  {
    f16x8 bf[3];
    #pragma unroll
    for (int s=0;s<3;s++)
      bf[s] = *reinterpret_cast<const f16x8*>(&bw3f[(((s*4+wv)*4+g)*16+m)*8]);
    const int oc = wv*16 + m;
    const float of = kb3o[oc];
    float macc = 0.f;
    #pragma unroll
    for (int mt=0; mt<6; mt++){
      const int trow = mt*16 + m;
      f32x4 acc = {0.f,0.f,0.f,0.f};
      #pragma unroll
      for (int s=0;s<3;s++){
        f16x8 af = *reinterpret_cast<const f16x8*>(smb + (trow + s)*80 + 16*g);
        acc = __builtin_amdgcn_mfma_f32_16x16x32_f16(af, bf[s], acc, 0,0,0);
      }
      #pragma unroll
      for (int r=0;r<4;r++){
        const int t = mt*16 + 4*g + r;
        if (t < 83) macc += fmaxf(acc[r] + of, 0.f);
      }
    }
    macc += __shfl_xor(macc, 16);
    macc += __shfl_xor(macc, 32);
    if (lane < 16) feats[sig*64 + oc] = macc * (1.f/83.f);
  }
}

// ---------------------------------------------------------------------------
// K2: build normalized adjacency An (8x8) from edge_index (2,56)
// ---------------------------------------------------------------------------
__global__ void k_an(const int* __restrict__ ei, float* __restrict__ an){
  __shared__ float A[64];
  __shared__ float dinv[8];
  const int tid = threadIdx.x;
  if (tid<64) A[tid] = ((tid>>3)==(tid&7)) ? 1.f : 0.f;
  __syncthreads();
  if (tid==0){
    for (int e=0;e<56;e++){ int s=ei[e], d=ei[56+e]; A[d*8+s] += 1.f; }
  }
  __syncthreads();
  if (tid<8){ float s=0.f; for (int j=0;j<8;j++) s+=A[tid*8+j]; dinv[tid]=rsqrtf(s); }
  __syncthreads();
  if (tid<64) an[tid] = A[tid]*dinv[tid>>3]*dinv[tid&7];
}

// ---------------------------------------------------------------------------
// f32 GEMM: C[M,N] = X[M,K] @ W[N,K]^T (+b1 +b2), tile 64x64, BK=16, ldc param.
// ---------------------------------------------------------------------------
__global__ __launch_bounds__(256) void k_gemm64(
  const float* __restrict__ X, const float* __restrict__ W,
  const float* __restrict__ b1, const float* __restrict__ b2,
  float* __restrict__ C, int M, int N, int K, int ldc)
{
  __shared__ float Xs[16][68];
  __shared__ float Ws[16][68];
  const int tid = threadIdx.x;
  const int m0 = blockIdx.y*64, n0 = blockIdx.x*64;
  const int tm = tid >> 4, tn = tid & 15;
  const int lr = tid >> 2, lk = (tid & 3)*4;
  float acc[4][4] = {};
  for (int k0=0; k0<K; k0+=16){
    float4 xa = *reinterpret_cast<const float4*>(X + (long)(m0+lr)*K + k0 + lk);
    float4 wa = *reinterpret_cast<const float4*>(W + (long)(n0+lr)*K + k0 + lk);
    __syncthreads();
    Xs[lk+0][lr]=xa.x; Xs[lk+1][lr]=xa.y; Xs[lk+2][lr]=xa.z; Xs[lk+3][lr]=xa.w;
    Ws[lk+0][lr]=wa.x; Ws[lk+1][lr]=wa.y; Ws[lk+2][lr]=wa.z; Ws[lk+3][lr]=wa.w;
    __syncthreads();
    #pragma unroll
    for (int kk=0;kk<16;kk++){
      float4 a  = *reinterpret_cast<const float4*>(&Xs[kk][tm*4]);
      float4 bv = *reinterpret_cast<const float4*>(&Ws[kk][tn*4]);
      float av[4]={a.x,a.y,a.z,a.w}, bb[4]={bv.x,bv.y,bv.z,bv.w};
      #pragma unroll
      for (int i=0;i<4;i++)
        #pragma unroll
        for (int j=0;j<4;j++) acc[i][j] += av[i]*bb[j];
    }
  }
  float bias[4] = {0.f,0.f,0.f,0.f};
  if (b1){ float4 t = *reinterpret_cast<const float4*>(b1 + n0 + tn*4);
           bias[0]+=t.x; bias[1]+=t.y; bias[2]+=t.z; bias[3]+=t.w; }
  if (b2){ float4 t = *reinterpret_cast<const float4*>(b2 + n0 + tn*4);
           bias[0]+=t.x; bias[1]+=t.y; bias[2]+=t.z; bias[3]+=t.w; }
  #pragma unroll
  for (int i=0;i<4;i++){
    float4 o;
    o.x = acc[i][0]+bias[0]; o.y = acc[i][1]+bias[1];
    o.z = acc[i][2]+bias[2]; o.w = acc[i][3]+bias[3];
    *reinterpret_cast<float4*>(C + (long)(m0+tm*4+i)*ldc + n0 + tn*4) = o;
  }
}

// ---------------------------------------------------------------------------
// K4: g1[g][i][j] = relu( sum_c An[i][c]*tmp0[g][c][j] + b0[j] )
// ---------------------------------------------------------------------------
__global__ __launch_bounds__(256) void k_mix1(
  const float* __restrict__ tmp0, const float* __restrict__ An,
  const float* __restrict__ b0, float* __restrict__ g1)
{
  __shared__ float ans[64];
  if (threadIdx.x < 64) ans[threadIdx.x] = An[threadIdx.x];
  __syncthreads();
  const long idx = (long)blockIdx.x*256 + threadIdx.x;   // over 1280*128
  const int g = (int)(idx >> 7), j = (int)(idx & 127);
  const float* base = tmp0 + (long)g*1024;
  float t[8];
  #pragma unroll
  for (int c=0;c<8;c++) t[c] = base[c*128+j];
  const float bj = b0[j];
  #pragma unroll
  for (int i=0;i<8;i++){
    float s = bj;
    #pragma unroll
    for (int c=0;c<8;c++) s += ans[i*8+c]*t[c];
    g1[(long)g*1024 + i*128 + j] = fmaxf(s, 0.f);
  }
}

// ---------------------------------------------------------------------------
// K6: g2 = An@tmp1 + b1 ; LN over j (128) per row ; mean over 8 nodes -> emb
// ---------------------------------------------------------------------------
__global__ __launch_bounds__(128) void k_mix2(
  const float* __restrict__ tmp1, const float* __restrict__ An,
  const float* __restrict__ b1, const float* __restrict__ lng,
  const float* __restrict__ lnb, float* __restrict__ emb)
{
  const int g = blockIdx.x, j = threadIdx.x;
  __shared__ float ans[64];
  __shared__ float g2s[8*128];
  __shared__ float stats[16];
  if (j<64) ans[j] = An[j];
  const float* base = tmp1 + (long)g*1024;
  float t[8];
  #pragma unroll
  for (int c=0;c<8;c++) t[c] = base[c*128 + j];
  const float bj = b1[j];
  __syncthreads();
  #pragma unroll
  for (int i=0;i<8;i++){
    float s = bj;
    #pragma unroll
    for (int c=0;c<8;c++) s += ans[i*8+c]*t[c];
    g2s[i*128+j] = s;
  }
  __syncthreads();
  {
    const int c = j>>4, l = j&15;
    float s=0.f, sq=0.f;
    for (int jj=l; jj<128; jj+=16){ float v=g2s[c*128+jj]; s+=v; sq+=v*v; }
    #pragma unroll
    for (int off=8; off>=1; off>>=1){ s += __shfl_xor(s, off); sq += __shfl_xor(sq, off); }
    if (l==0){
      float m = s*(1.f/128.f);
      stats[2*c] = m;
      stats[2*c+1] = rsqrtf(sq*(1.f/128.f) - m*m + 1e-5f);
    }
  }
  __syncthreads();
  float acc=0.f;
  #pragma unroll
  for (int i=0;i<8;i++) acc += (g2s[i*128+j] - stats[2*i]) * stats[2*i+1];
  emb[(long)g*128 + j] = lng[j]*acc*0.125f + lnb[j];
}

// ---------------------------------------------------------------------------
// K7: transpose+pack w_hh (1024,256) f32 -> wtp[jp][g] = (w[g][2jp], w[g][2jp+1]) f16x2
// ---------------------------------------------------------------------------
__global__ __launch_bounds__(256) void k_trp(
  const float* __restrict__ in, h2f16* __restrict__ outp)
{
  const int i = blockIdx.x*256 + threadIdx.x;   // 131072
  const int g = i & 1023, jp = i >> 10;
  h2f16 p;
  p[0] = (_Float16)in[g*256 + 2*jp];
  p[1] = (_Float16)in[g*256 + 2*jp + 1];
  outp[(long)jp*1024 + g] = p;
}

// ---------------------------------------------------------------------------
// K8: one LSTM layer, both directions. Block = (batch, dir), 1024 threads.
// ---------------------------------------------------------------------------
__global__ __launch_bounds__(1024) void k_lstm(
    const float* __restrict__ xs,          // [1280][2048] fwd|rev gates
    const h2f16* __restrict__ wtf,         // [128][1024] packed j-pairs
    const h2f16* __restrict__ wtr,
    float* __restrict__ out)               // [1280][512]
{
  const int S = 20;
  const int b = blockIdx.x >> 1, dir = blockIdx.x & 1;
  const h2f16* wt = dir ? wtr : wtf;
  __shared__ float part[4][1024];
  __shared__ _Float16 hsh[256];
  const int tid = threadIdx.x;
  const int jg = tid >> 8, r = tid & 255, grow = r*4;
  if (tid < 256) hsh[tid] = (_Float16)0.f;
  float cc = 0.f;
  __syncthreads();
  const h2f16* hp2 = reinterpret_cast<const h2f16*>(hsh);
  for (int st=0; st<S; ++st){
    const int t = dir ? (S-1-st) : st;
    float a0=0.f,a1=0.f,a2=0.f,a3=0.f;
    #pragma unroll 8
    for (int jp=0; jp<32; ++jp){
      const h2f16 hv = hp2[jg*32 + jp];
      U4H w; w.u = *reinterpret_cast<const uint4*>(
          reinterpret_cast<const unsigned int*>(wt + (long)(jg*32+jp)*1024 + grow));
      a0 = __builtin_amdgcn_fdot2(hv, w.h[0], a0, false);
      a1 = __builtin_amdgcn_fdot2(hv, w.h[1], a1, false);
      a2 = __builtin_amdgcn_fdot2(hv, w.h[2], a2, false);
      a3 = __builtin_amdgcn_fdot2(hv, w.h[3], a3, false);
    }
    *reinterpret_cast<float4*>(&part[jg][grow]) = make_float4(a0,a1,a2,a3);
    __syncthreads();
    if (tid < 256){
      const float* xrow = xs + ((long)b*S + t)*2048 + dir*1024;
      float g0 = xrow[tid]
               + (part[0][tid]      + part[1][tid])      + (part[2][tid]      + part[3][tid]);
      float g1 = xrow[256+tid]
               + (part[0][256+tid]  + part[1][256+tid])  + (part[2][256+tid]  + part[3][256+tid]);
      float g2 = xrow[512+tid]
               + (part[0][512+tid]  + part[1][512+tid])  + (part[2][512+tid]  + part[3][512+tid]);
      float g3 = xrow[768+tid]
               + (part[0][768+tid]  + part[1][768+tid])  + (part[2][768+tid]  + part[3][768+tid]);
      cc = sigf(g1)*cc + sigf(g0)*tanh_f(g2);
      const float h = sigf(g3)*tanh_f(cc);
      hsh[tid] = (_Float16)h;
      out[((long)b*S + t)*512 + dir*256 + tid] = h;
    }
    __syncthreads();
  }
}

// ---------------------------------------------------------------------------
// K11: final LayerNorm(512) + classifier (5) per row
// ---------------------------------------------------------------------------
__global__ __launch_bounds__(128) void k_lncls(
  const float* __restrict__ in, const float* __restrict__ g,
  const float* __restrict__ b, const float* __restrict__ cw,
  const float* __restrict__ cb, float* __restrict__ out)
{
  const int row = blockIdx.x, tid = threadIdx.x;
  __shared__ float sred[4];
  __shared__ float cred[2][5];
  float4 v = *reinterpret_cast<const float4*>(in + (long)row*512 + tid*4);
  float s  = v.x+v.y+v.z+v.w;
  float sq = v.x*v.x+v.y*v.y+v.z*v.z+v.w*v.w;
  #pragma unroll
  for (int off=32; off>=1; off>>=1){ s += __shfl_xor(s, off); sq += __shfl_xor(sq, off); }
  const int wv = tid>>6;
  if ((tid&63)==0){ sred[wv*2]=s; sred[wv*2+1]=sq; }
  __syncthreads();
  const float S = sred[0]+sred[2], SQ = sred[1]+sred[3];
  const float m = S*(1.f/512.f);
  const float rstd = rsqrtf(SQ*(1.f/512.f) - m*m + 1e-5f);
  float4 gg = *reinterpret_cast<const float4*>(g + tid*4);
  float4 bb = *reinterpret_cast<const float4*>(b + tid*4);
  const float n0 = (v.x-m)*rstd*gg.x + bb.x;
  const float n1 = (v.y-m)*rstd*gg.y + bb.y;
  const float n2 = (v.z-m)*rstd*gg.z + bb.z;
  const float n3 = (v.w-m)*rstd*gg.w + bb.w;
  #pragma unroll
  for (int nc=0; nc<5; ++nc){
    float4 w = *reinterpret_cast<const float4*>(cw + nc*512 + tid*4);
    float p = n0*w.x + n1*w.y + n2*w.z + n3*w.w;
    #pragma unroll
    for (int off=32; off>=1; off>>=1) p += __shfl_xor(p, off);
    if ((tid&63)==0) cred[wv][nc] = p;
  }
  __syncthreads();
  if (tid < 5) out[(long)row*5 + tid] = cred[0][tid] + cred[1][tid] + cb[tid];
}

// ---------------------------------------------------------------------------
extern "C" void kernel_launch(void* const* d_in, const int* in_sizes, int n_in,
                              void* d_out, int out_size, void* d_ws, size_t ws_size,
                              hipStream_t stream)
{
  const float* x     = (const float*)d_in[0];
  const int*   ei    = (const int*)d_in[1];
  const float* w1    = (const float*)d_in[2];
  const float* c1b   = (const float*)d_in[3];
  const float* bg1   = (const float*)d_in[4];
  const float* bb1   = (const float*)d_in[5];
  const float* w2    = (const float*)d_in[6];
  const float* c2b   = (const float*)d_in[7];
  const float* bg2   = (const float*)d_in[8];
  const float* bb2   = (const float*)d_in[9];
  const float* w3    = (const float*)d_in[10];
  const float* c3b   = (const float*)d_in[11];
  const float* bg3   = (const float*)d_in[12];
  const float* bb3   = (const float*)d_in[13];
  const float* gcn0w = (const float*)d_in[14];
  const float* gcn0b = (const float*)d_in[15];
  const float* gcn1w = (const float*)d_in[16];
  const float* gcn1b = (const float*)d_in[17];
  const float* lng   = (const float*)d_in[18];
  const float* lnb   = (const float*)d_in[19];
  const float* wih0  = (const float*)d_in[20];
  const float* whh0  = (const float*)d_in[21];
  const float* bih0  = (const float*)d_in[22];
  const float* bhh0  = (const float*)d_in[23];
  const float* wih0r = (const float*)d_in[24];
  const float* whh0r = (const float*)d_in[25];
  const float* bih0r = (const float*)d_in[26];
  const float* bhh0r = (const float*)d_in[27];
  const float* wih1  = (const float*)d_in[28];
  const float* whh1  = (const float*)d_in[29];
  const float* bih1  = (const float*)d_in[30];
  const float* bhh1  = (const float*)d_in[31];
  const float* wih1r = (const float*)d_in[32];
  const float* whh1r = (const float*)d_in[33];
  const float* bih1r = (const float*)d_in[34];
  const float* bhh1r = (const float*)d_in[35];
  const float* lstmg = (const float*)d_in[36];
  const float* lstmb = (const float*)d_in[37];
  const float* clsw  = (const float*)d_in[38];
  const float* clsb  = (const float*)d_in[39];
  float* ws  = (float*)d_ws;
  float* out = (float*)d_out;

  // workspace layout (floats)
  float* An    = ws + 0;
  float* feats = ws + 256;
  float* tmp   = ws + 655616;    // [10240][128] (tmp0/tmp1 aliased)
  float* g1b   = ws + 1966336;   // [10240][128]
  float* emb   = ws + 3277056;   // [1280][128]
  float* xs    = ws + 3440896;   // [1280][2048] fused fwd|rev gate inputs
  float* l0    = ws + 6062336;   // [1280][512]
  float* l1    = ws + 6717696;   // [1280][512]
  h2f16* wt0f  = (h2f16*)(ws + 7373056);
  h2f16* wt0r  = (h2f16*)(ws + 7504128);
  h2f16* wt1f  = (h2f16*)(ws + 7635200);
  h2f16* wt1r  = (h2f16*)(ws + 7766272);
  _Float16* bw2f = (_Float16*)(ws + 7897344);   // 3072 f16
  _Float16* bw3f = (_Float16*)(ws + 7898880);   // 6144 f16

  // Stage 0: weight packs (k_conv depends on k_packw via stream order)
  k_packw<<<24, 256, 0, stream>>>(w2, w3, bg2, bg3, bw2f, bw3f);
  // Stage 1: conv front-end
  k_conv<<<10240, 256, 0, stream>>>(x, w1,c1b,bg1,bb1, bw2f,c2b,bg2,bb2,
                                    bw3f,c3b,bg3,bb3, feats);
  // Adjacency + packed weight transposes (independent of k_conv output)
  k_an<<<1, 64, 0, stream>>>(ei, An);
  k_trp<<<512,256,0,stream>>>(whh0,  wt0f);
  k_trp<<<512,256,0,stream>>>(whh0r, wt0r);
  k_trp<<<512,256,0,stream>>>(whh1,  wt1f);
  k_trp<<<512,256,0,stream>>>(whh1r, wt1r);

  // Stage 2: GCN
  k_gemm64<<<dim3(2, 160), 256, 0, stream>>>(feats, gcn0w, nullptr, nullptr, tmp, 10240, 128, 64, 128);
  k_mix1<<<640,256,0,stream>>>(tmp, An, gcn0b, g1b);
  k_gemm64<<<dim3(2, 160), 256, 0, stream>>>(g1b, gcn1w, nullptr, nullptr, tmp, 10240, 128, 128, 128);
  k_mix2<<<1280,128,0,stream>>>(tmp, An, gcn1b, lng, lnb, emb);

  // Stage 3: BiLSTM layer 0 (fwd|rev gates into one xs buffer, ldc=2048)
  k_gemm64<<<dim3(16, 20), 256, 0, stream>>>(emb, wih0,  bih0,  bhh0,  xs,        1280, 1024, 128, 2048);
  k_gemm64<<<dim3(16, 20), 256, 0, stream>>>(emb, wih0r, bih0r, bhh0r, xs + 1024, 1280, 1024, 128, 2048);
  k_lstm<<<128, 1024, 0, stream>>>(xs, wt0f, wt0r, l0);

  // BiLSTM layer 1
  k_gemm64<<<dim3(16, 20), 256, 0, stream>>>(l0, wih1,  bih1,  bhh1,  xs,        1280, 1024, 512, 2048);
  k_gemm64<<<dim3(16, 20), 256, 0, stream>>>(l0, wih1r, bih1r, bhh1r, xs + 1024, 1280, 1024, 512, 2048);
  k_lstm<<<128, 1024, 0, stream>>>(xs, wt1f, wt1r, l1);

  // Stage 4: LN + classifier
  k_lncls<<<1280, 128, 0, stream>>>(l1, lstmg, lstmb, clsw, clsb, out);
}

// Round 8
// 407.547 us; speedup vs baseline: 3.5127x; 1.0143x over previous
//
#include <hip/hip_runtime.h>
#include <hip/hip_bf16.h>

#define DEVI __device__ __forceinline__

typedef _Float16 h2f16 __attribute__((ext_vector_type(2)));
typedef _Float16 f16x4 __attribute__((ext_vector_type(4)));
typedef _Float16 f16x8 __attribute__((ext_vector_type(8)));
typedef float    f32x4 __attribute__((ext_vector_type(4)));
union U4H { uint4 u; h2f16 h[4]; };
union F8  { f16x8 v8; f16x4 v4[2]; };

DEVI float sigf(float x){ return 1.f/(1.f + __expf(-x)); }
DEVI float tanh_f(float x){
  float ax = fabsf(x);
  float e = __expf(-2.f*ax);
  float t = (1.f - e)/(1.f + e);
  return copysignf(t, x);
}
DEVI h2f16 hmax2(h2f16 a, h2f16 b){
  h2f16 r; r[0] = a[0] > b[0] ? a[0] : b[0]; r[1] = a[1] > b[1] ? a[1] : b[1]; return r;
}

// ---------------------------------------------------------------------------
// K0: pack conv2/conv3 weights to f16, MFMA fragment order, BN scale folded.
// ---------------------------------------------------------------------------
__global__ __launch_bounds__(256) void k_packw(
  const float* __restrict__ w2, const float* __restrict__ w3,
  const float* __restrict__ bg2, const float* __restrict__ bg3,
  _Float16* __restrict__ bw2f, _Float16* __restrict__ bw3f)
{
  const int i = blockIdx.x*256 + threadIdx.x;
  const float rs = rsqrtf(1.f+1e-5f);
  if (i < 3072){
    const int j = i&7, m = (i>>3)&15, g = (i>>7)&3, nt = (i>>9)&1, s = i>>10;
    const int kk = 32*s + 8*g + j;
    const int k = kk >> 4, ic = kk & 15, oc = nt*16 + m;
    bw2f[i] = (_Float16)((k < 5 ? w2[oc*80 + ic*5 + k] : 0.f) * (bg2[oc]*rs));
  }
  if (i < 6144){
    const int j = i&7, m = (i>>3)&15, g = (i>>7)&3, wv = (i>>9)&3, s = i>>11;
    const int kk = 32*s + 8*g + j;
    const int k = kk >> 5, ic = kk & 31, oc = wv*16 + m;
    bw3f[i] = (_Float16)(w3[oc*96 + ic*3 + k] * (bg3[oc]*rs));
  }
}

// ---------------------------------------------------------------------------
// K0b: pack the 6 GEMM weight matrices f32 -> f16 (dense, same layout).
// ---------------------------------------------------------------------------
__global__ __launch_bounds__(256) void k_packall(
  const float* __restrict__ a0, const float* __restrict__ a1,
  const float* __restrict__ a2, const float* __restrict__ a3,
  const float* __restrict__ a4, const float* __restrict__ a5,
  _Float16* __restrict__ o0, _Float16* __restrict__ o1,
  _Float16* __restrict__ o2, _Float16* __restrict__ o3,
  _Float16* __restrict__ o4, _Float16* __restrict__ o5)
{
  const int i = blockIdx.x*256 + threadIdx.x;
  if      (i <  131072) o0[i] = (_Float16)a0[i];
  else if (i <  262144) o1[i-131072] = (_Float16)a1[i-131072];
  else if (i <  786432) o2[i-262144] = (_Float16)a2[i-262144];
  else if (i < 1310720) o3[i-786432] = (_Float16)a3[i-786432];
  else if (i < 1318912) o4[i-1310720] = (_Float16)a4[i-1310720];
  else if (i < 1335296) o5[i-1318912] = (_Float16)a5[i-1318912];
}

// ---------------------------------------------------------------------------
// K1: fused conv front-end (unchanged compute; feats now f16).
// ---------------------------------------------------------------------------
__global__ __launch_bounds__(256,4) void k_conv(
    const float* __restrict__ x,
    const float* __restrict__ w1g, const float* __restrict__ c1b,
    const float* __restrict__ bg1, const float* __restrict__ bb1,
    const _Float16* __restrict__ bw2f,
    const float* __restrict__ c2b, const float* __restrict__ bg2, const float* __restrict__ bb2,
    const _Float16* __restrict__ bw3f,
    const float* __restrict__ c3b, const float* __restrict__ bg3, const float* __restrict__ bb3,
    _Float16* __restrict__ feats)
{
  __shared__ __align__(16) unsigned char smb[38592];
  __shared__ h2f16 w1p[16][4];
  __shared__ float kb1o[16], kb2o[32], kb3o[64];
  h2f16* sxh = reinterpret_cast<h2f16*>(smb + 20160);
  const int tid = threadIdx.x;
  const long sig = blockIdx.x;
  const float* xg = x + sig*3000;

  {
    const float4* xg4 = reinterpret_cast<const float4*>(xg);
    for (int i=tid; i<750; i+=256){
      float4 v = xg4[i];
      h2f16 p0; p0[0]=(_Float16)v.x; p0[1]=(_Float16)v.y;
      h2f16 p1; p1[0]=(_Float16)v.z; p1[1]=(_Float16)v.w;
      sxh[2*i+2] = p0; sxh[2*i+3] = p1;
    }
    if (tid<3){
      h2f16 z; z[0]=(_Float16)0.f; z[1]=(_Float16)0.f;
      sxh[tid<2 ? tid : 1502] = z;
    }
    if (tid<32){
      const int rr = tid>>3, cp = tid&7;
      const int row = (rr<2) ? rr : (500+rr);
      h2f16 z; z[0]=(_Float16)0.f; z[1]=(_Float16)0.f;
      *reinterpret_cast<h2f16*>(smb + row*40 + 4*cp) = z;
    }
    const float rs = rsqrtf(1.f+1e-5f);
    if (tid<64){
      const int c = tid>>2, j = tid&3;
      const float s = bg1[c]*rs;
      h2f16 p;
      if (j==0){ p[0]=(_Float16)0.f; p[1]=(_Float16)(w1g[c*7+0]*s); }
      else     { p[0]=(_Float16)(w1g[c*7+2*j-1]*s); p[1]=(_Float16)(w1g[c*7+2*j]*s); }
      w1p[c][j] = p;
    }
    if (tid<16) kb1o[tid] = c1b[tid]*(bg1[tid]*rs) + bb1[tid];
    if (tid<32) kb2o[tid] = c2b[tid]*(bg2[tid]*rs) + bb2[tid];
    if (tid<64) kb3o[tid] = c3b[tid]*(bg3[tid]*rs) + bb3[tid];
  }
  __syncthreads();

  // Phase A
  {
    const int cp = tid & 7;
    h2f16 wpa[4], wpb[4];
    #pragma unroll
    for (int j=0;j<4;j++){ wpa[j] = w1p[2*cp][j]; wpb[j] = w1p[2*cp+1][j]; }
    const float oa = kb1o[2*cp], ob = kb1o[2*cp+1];
    for (int u = tid>>3; u<500; u+=32){
      h2f16 xq[6];
      #pragma unroll
      for (int r=0;r<6;r++) xq[r] = sxh[3*u + r];
      float a0=0.f,a1=0.f,a2=0.f,b0=0.f,b1=0.f,b2=0.f;
      #pragma unroll
      for (int j=0;j<4;j++){
        a0 = __builtin_amdgcn_fdot2(xq[j],   wpa[j], a0, false);
        a1 = __builtin_amdgcn_fdot2(xq[j+1], wpa[j], a1, false);
        a2 = __builtin_amdgcn_fdot2(xq[j+2], wpa[j], a2, false);
        b0 = __builtin_amdgcn_fdot2(xq[j],   wpb[j], b0, false);
        b1 = __builtin_amdgcn_fdot2(xq[j+1], wpb[j], b1, false);
        b2 = __builtin_amdgcn_fdot2(xq[j+2], wpb[j], b2, false);
      }
      const float ya = fmaxf(fmaxf(fmaxf(a0,a1),a2) + oa, 0.f);
      const float yb = fmaxf(fmaxf(fmaxf(b0,b1),b2) + ob, 0.f);
      h2f16 p; p[0]=(_Float16)ya; p[1]=(_Float16)yb;
      *reinterpret_cast<h2f16*>(smb + (u+2)*40 + 4*cp) = p;
    }
  }
  __syncthreads();

  const int wv = tid >> 6, lane = tid & 63;
  const int m = lane & 15, g = lane >> 4;

  // Phase B
  {
    const int nt = wv & 1;
    f16x8 bf[3];
    #pragma unroll
    for (int s=0;s<3;s++)
      bf[s] = *reinterpret_cast<const f16x8*>(&bw2f[(((s*2+nt)*4+g)*16+m)*8]);
    const int oc = nt*16 + m;
    const float of = kb2o[oc];
    #pragma unroll
    for (int i=0;i<8;i++){
      const int mt = (wv>>1) + 2*i;
      const int trow = mt*16 + m;
      f32x4 acc = {0.f,0.f,0.f,0.f};
      #pragma unroll
      for (int s=0;s<3;s++){
        const int kk = 32*s + 8*g;
        const int k = kk >> 4;
        const int ab = 80*trow + 40*k + 16*(g&1);
        F8 a;
        a.v4[0] = *reinterpret_cast<const f16x4*>(smb + ab);
        a.v4[1] = *reinterpret_cast<const f16x4*>(smb + ab + 8);
        acc = __builtin_amdgcn_mfma_f32_16x16x32_f16(a.v8, bf[s], acc, 0,0,0);
      }
      #pragma unroll
      for (int r=0;r<4;r++){
        const int t = mt*16 + 4*g + r;
        const float z = fmaxf(acc[r] + of, 0.f);
        *reinterpret_cast<_Float16*>(smb + 20160 + t*72 + 2*oc) = (_Float16)z;
      }
    }
  }
  __syncthreads();

  // Pool
  {
    if (tid < 240){
      const int rr = tid >> 4, cc = tid & 15;
      const int row = (rr == 0) ? 0 : (83 + rr);
      h2f16 z; z[0]=(_Float16)0.f; z[1]=(_Float16)0.f;
      *reinterpret_cast<h2f16*>(smb + row*80 + 4*cc) = z;
    }
    for (int i=tid; i<1328; i+=256){
      const int u = i >> 4, cc = i & 15;
      h2f16 a = *reinterpret_cast<const h2f16*>(smb + 20160 + (3*u)*72 + 4*cc);
      h2f16 b = *reinterpret_cast<const h2f16*>(smb + 20160 + (3*u+1)*72 + 4*cc);
      h2f16 c = *reinterpret_cast<const h2f16*>(smb + 20160 + (3*u+2)*72 + 4*cc);
      *reinterpret_cast<h2f16*>(smb + (u+1)*80 + 4*cc) = hmax2(hmax2(a,b), c);
    }
  }
  __syncthreads();

  // Phase C
  {
    f16x8 bf[3];
    #pragma unroll
    for (int s=0;s<3;s++)
      bf[s] = *reinterpret_cast<const f16x8*>(&bw3f[(((s*4+wv)*4+g)*16+m)*8]);
    const int oc = wv*16 + m;
    const float of = kb3o[oc];
    float macc = 0.f;
    #pragma unroll
    for (int mt=0; mt<6; mt++){
      const int trow = mt*16 + m;
      f32x4 acc = {0.f,0.f,0.f,0.f};
      #pragma unroll
      for (int s=0;s<3;s++){
        f16x8 af = *reinterpret_cast<const f16x8*>(smb + (trow + s)*80 + 16*g);
        acc = __builtin_amdgcn_mfma_f32_16x16x32_f16(af, bf[s], acc, 0,0,0);
      }
      #pragma unroll
      for (int r=0;r<4;r++){
        const int t = mt*16 + 4*g + r;
        if (t < 83) macc += fmaxf(acc[r] + of, 0.f);
      }
    }
    macc += __shfl_xor(macc, 16);
    macc += __shfl_xor(macc, 32);
    if (lane < 16) feats[sig*64 + oc] = (_Float16)(macc * (1.f/83.f));
  }
}

// ---------------------------------------------------------------------------
// K2: build normalized adjacency An (8x8) from edge_index (2,56)
// ---------------------------------------------------------------------------
__global__ void k_an(const int* __restrict__ ei, float* __restrict__ an){
  __shared__ float A[64];
  __shared__ float dinv[8];
  const int tid = threadIdx.x;
  if (tid<64) A[tid] = ((tid>>3)==(tid&7)) ? 1.f : 0.f;
  __syncthreads();
  if (tid==0){
    for (int e=0;e<56;e++){ int s=ei[e], d=ei[56+e]; A[d*8+s] += 1.f; }
  }
  __syncthreads();
  if (tid<8){ float s=0.f; for (int j=0;j<8;j++) s+=A[tid*8+j]; dinv[tid]=rsqrtf(s); }
  __syncthreads();
  if (tid<64) an[tid] = A[tid]*dinv[tid>>3]*dinv[tid&7];
}

// ---------------------------------------------------------------------------
// K3: MFMA f16 GEMM: C[M,N] = X16[M,K] @ W16[N,K]^T (+b1+b2), f32 out.
// Tile 64x64, BK=32, 256 threads (4 waves, wave = 16 rows x 64 cols).
// LDS rows padded to 72B. M%64==0, N%64==0, K%32==0.
// ---------------------------------------------------------------------------
__global__ __launch_bounds__(256) void k_gemm_mf(
  const _Float16* __restrict__ X, const _Float16* __restrict__ W,
  const float* __restrict__ b1, const float* __restrict__ b2,
  float* __restrict__ C, int M, int N, int K, int ldc)
{
  __shared__ __align__(16) unsigned char lds[128*72];
  unsigned char* Xs = lds;
  unsigned char* Ws = lds + 64*72;
  const int tid = threadIdx.x;
  const int m0 = blockIdx.y*64, n0 = blockIdx.x*64;
  const int wv = tid>>6, lane = tid&63, m = lane&15, g = lane>>4;
  const int sr = tid>>2, sq = tid&3;
  f32x4 acc[4] = {{0.f,0.f,0.f,0.f},{0.f,0.f,0.f,0.f},{0.f,0.f,0.f,0.f},{0.f,0.f,0.f,0.f}};
  for (int k0=0; k0<K; k0+=32){
    uint4 xa = *reinterpret_cast<const uint4*>(X + (long)(m0+sr)*K + k0 + sq*8);
    uint4 wa = *reinterpret_cast<const uint4*>(W + (long)(n0+sr)*K + k0 + sq*8);
    __syncthreads();
    *reinterpret_cast<uint4*>(Xs + sr*72 + sq*16) = xa;
    *reinterpret_cast<uint4*>(Ws + sr*72 + sq*16) = wa;
    __syncthreads();
    f16x8 af = *reinterpret_cast<const f16x8*>(Xs + (wv*16+m)*72 + g*16);
    #pragma unroll
    for (int nt=0;nt<4;nt++){
      f16x8 bf = *reinterpret_cast<const f16x8*>(Ws + (nt*16+m)*72 + g*16);
      acc[nt] = __builtin_amdgcn_mfma_f32_16x16x32_f16(af, bf, acc[nt], 0,0,0);
    }
  }
  #pragma unroll
  for (int nt=0;nt<4;nt++){
    const int col = n0 + nt*16 + m;
    float bias = 0.f;
    if (b1) bias += b1[col];
    if (b2) bias += b2[col];
    #pragma unroll
    for (int r=0;r<4;r++)
      C[(long)(m0 + wv*16 + g*4 + r)*ldc + col] = acc[nt][r] + bias;
  }
}

// ---------------------------------------------------------------------------
// K4: g1[g][i][j] = relu( sum_c An[i][c]*tmp0[g][c][j] + b0[j] )  (f16 out)
// ---------------------------------------------------------------------------
__global__ __launch_bounds__(256) void k_mix1(
  const float* __restrict__ tmp0, const float* __restrict__ An,
  const float* __restrict__ b0, _Float16* __restrict__ g1)
{
  __shared__ float ans[64];
  if (threadIdx.x < 64) ans[threadIdx.x] = An[threadIdx.x];
  __syncthreads();
  const long idx = (long)blockIdx.x*256 + threadIdx.x;   // over 1280*128
  const int g = (int)(idx >> 7), j = (int)(idx & 127);
  const float* base = tmp0 + (long)g*1024;
  float t[8];
  #pragma unroll
  for (int c=0;c<8;c++) t[c] = base[c*128+j];
  const float bj = b0[j];
  #pragma unroll
  for (int i=0;i<8;i++){
    float s = bj;
    #pragma unroll
    for (int c=0;c<8;c++) s += ans[i*8+c]*t[c];
    g1[(long)g*1024 + i*128 + j] = (_Float16)fmaxf(s, 0.f);
  }
}

// ---------------------------------------------------------------------------
// K6: g2 = An@tmp1 + b1 ; LN over j ; mean over 8 nodes -> emb (f16 out)
// ---------------------------------------------------------------------------
__global__ __launch_bounds__(128) void k_mix2(
  const float* __restrict__ tmp1, const float* __restrict__ An,
  const float* __restrict__ b1, const float* __restrict__ lng,
  const float* __restrict__ lnb, _Float16* __restrict__ emb)
{
  const int g = blockIdx.x, j = threadIdx.x;
  __shared__ float ans[64];
  __shared__ float g2s[8*128];
  __shared__ float stats[16];
  if (j<64) ans[j] = An[j];
  const float* base = tmp1 + (long)g*1024;
  float t[8];
  #pragma unroll
  for (int c=0;c<8;c++) t[c] = base[c*128 + j];
  const float bj = b1[j];
  __syncthreads();
  #pragma unroll
  for (int i=0;i<8;i++){
    float s = bj;
    #pragma unroll
    for (int c=0;c<8;c++) s += ans[i*8+c]*t[c];
    g2s[i*128+j] = s;
  }
  __syncthreads();
  {
    const int c = j>>4, l = j&15;
    float s=0.f, sq=0.f;
    for (int jj=l; jj<128; jj+=16){ float v=g2s[c*128+jj]; s+=v; sq+=v*v; }
    #pragma unroll
    for (int off=8; off>=1; off>>=1){ s += __shfl_xor(s, off); sq += __shfl_xor(sq, off); }
    if (l==0){
      float m = s*(1.f/128.f);
      stats[2*c] = m;
      stats[2*c+1] = rsqrtf(sq*(1.f/128.f) - m*m + 1e-5f);
    }
  }
  __syncthreads();
  float acc=0.f;
  #pragma unroll
  for (int i=0;i<8;i++) acc += (g2s[i*128+j] - stats[2*i]) * stats[2*i+1];
  emb[(long)g*128 + j] = (_Float16)(lng[j]*acc*0.125f + lnb[j]);
}

// ---------------------------------------------------------------------------
// K7: transpose+pack w_hh (1024,256) f32 -> wtp[jp][g] f16x2
// ---------------------------------------------------------------------------
__global__ __launch_bounds__(256) void k_trp(
  const float* __restrict__ in, h2f16* __restrict__ outp)
{
  const int i = blockIdx.x*256 + threadIdx.x;   // 131072
  const int g = i & 1023, jp = i >> 10;
  h2f16 p;
  p[0] = (_Float16)in[g*256 + 2*jp];
  p[1] = (_Float16)in[g*256 + 2*jp + 1];
  outp[(long)jp*1024 + g] = p;
}

// ---------------------------------------------------------------------------
// K8: one LSTM layer, both directions. Block = (batch, dir), 1024 threads.
// Writes both f32 (outf) and f16 (outh) copies of h.
// ---------------------------------------------------------------------------
__global__ __launch_bounds__(1024) void k_lstm(
    const float* __restrict__ xs,          // [1280][2048] fwd|rev gates
    const h2f16* __restrict__ wtf,         // [128][1024] packed j-pairs
    const h2f16* __restrict__ wtr,
    float* __restrict__ outf,              // [1280][512]
    _Float16* __restrict__ outh)           // [1280][512]
{
  const int S = 20;
  const int b = blockIdx.x >> 1, dir = blockIdx.x & 1;
  const h2f16* wt = dir ? wtr : wtf;
  __shared__ float part[4][1024];
  __shared__ _Float16 hsh[256];
  const int tid = threadIdx.x;
  const int jg = tid >> 8, r = tid & 255, grow = r*4;
  if (tid < 256) hsh[tid] = (_Float16)0.f;
  float cc = 0.f;
  __syncthreads();
  const h2f16* hp2 = reinterpret_cast<const h2f16*>(hsh);
  for (int st=0; st<S; ++st){
    const int t = dir ? (S-1-st) : st;
    float a0=0.f,a1=0.f,a2=0.f,a3=0.f;
    #pragma unroll 8
    for (int jp=0; jp<32; ++jp){
      const h2f16 hv = hp2[jg*32 + jp];
      U4H w; w.u = *reinterpret_cast<const uint4*>(
          reinterpret_cast<const unsigned int*>(wt + (long)(jg*32+jp)*1024 + grow));
      a0 = __builtin_amdgcn_fdot2(hv, w.h[0], a0, false);
      a1 = __builtin_amdgcn_fdot2(hv, w.h[1], a1, false);
      a2 = __builtin_amdgcn_fdot2(hv, w.h[2], a2, false);
      a3 = __builtin_amdgcn_fdot2(hv, w.h[3], a3, false);
    }
    *reinterpret_cast<float4*>(&part[jg][grow]) = make_float4(a0,a1,a2,a3);
    __syncthreads();
    if (tid < 256){
      const float* xrow = xs + ((long)b*S + t)*2048 + dir*1024;
      float g0 = xrow[tid]
               + (part[0][tid]      + part[1][tid])      + (part[2][tid]      + part[3][tid]);
      float g1 = xrow[256+tid]
               + (part[0][256+tid]  + part[1][256+tid])  + (part[2][256+tid]  + part[3][256+tid]);
      float g2 = xrow[512+tid]
               + (part[0][512+tid]  + part[1][512+tid])  + (part[2][512+tid]  + part[3][512+tid]);
      float g3 = xrow[768+tid]
               + (part[0][768+tid]  + part[1][768+tid])  + (part[2][768+tid]  + part[3][768+tid]);
      cc = sigf(g1)*cc + sigf(g0)*tanh_f(g2);
      const float h = sigf(g3)*tanh_f(cc);
      hsh[tid] = (_Float16)h;
      const long o = ((long)b*S + t)*512 + dir*256 + tid;
      outf[o] = h;
      outh[o] = (_Float16)h;
    }
    __syncthreads();
  }
}

// ---------------------------------------------------------------------------
// K11: final LayerNorm(512) + classifier (5) per row
// ---------------------------------------------------------------------------
__global__ __launch_bounds__(128) void k_lncls(
  const float* __restrict__ in, const float* __restrict__ g,
  const float* __restrict__ b, const float* __restrict__ cw,
  const float* __restrict__ cb, float* __restrict__ out)
{
  const int row = blockIdx.x, tid = threadIdx.x;
  __shared__ float sred[4];
  __shared__ float cred[2][5];
  float4 v = *reinterpret_cast<const float4*>(in + (long)row*512 + tid*4);
  float s  = v.x+v.y+v.z+v.w;
  float sq = v.x*v.x+v.y*v.y+v.z*v.z+v.w*v.w;
  #pragma unroll
  for (int off=32; off>=1; off>>=1){ s += __shfl_xor(s, off); sq += __shfl_xor(sq, off); }
  const int wv = tid>>6;
  if ((tid&63)==0){ sred[wv*2]=s; sred[wv*2+1]=sq; }
  __syncthreads();
  const float S = sred[0]+sred[2], SQ = sred[1]+sred[3];
  const float m = S*(1.f/512.f);
  const float rstd = rsqrtf(SQ*(1.f/512.f) - m*m + 1e-5f);
  float4 gg = *reinterpret_cast<const float4*>(g + tid*4);
  float4 bb = *reinterpret_cast<const float4*>(b + tid*4);
  const float n0 = (v.x-m)*rstd*gg.x + bb.x;
  const float n1 = (v.y-m)*rstd*gg.y + bb.y;
  const float n2 = (v.z-m)*rstd*gg.z + bb.z;
  const float n3 = (v.w-m)*rstd*gg.w + bb.w;
  #pragma unroll
  for (int nc=0; nc<5; ++nc){
    float4 w = *reinterpret_cast<const float4*>(cw + nc*512 + tid*4);
    float p = n0*w.x + n1*w.y + n2*w.z + n3*w.w;
    #pragma unroll
    for (int off=32; off>=1; off>>=1) p += __shfl_xor(p, off);
    if ((tid&63)==0) cred[wv][nc] = p;
  }
  __syncthreads();
  if (tid < 5) out[(long)row*5 + tid] = cred[0][tid] + cred[1][tid] + cb[tid];
}

// ---------------------------------------------------------------------------
extern "C" void kernel_launch(void* const* d_in, const int* in_sizes, int n_in,
                              void* d_out, int out_size, void* d_ws, size_t ws_size,
                              hipStream_t stream)
{
  const float* x     = (const float*)d_in[0];
  const int*   ei    = (const int*)d_in[1];
  const float* w1    = (const float*)d_in[2];
  const float* c1b   = (const float*)d_in[3];
  const float* bg1   = (const float*)d_in[4];
  const float* bb1   = (const float*)d_in[5];
  const float* w2    = (const float*)d_in[6];
  const float* c2b   = (const float*)d_in[7];
  const float* bg2   = (const float*)d_in[8];
  const float* bb2   = (const float*)d_in[9];
  const float* w3    = (const float*)d_in[10];
  const float* c3b   = (const float*)d_in[11];
  const float* bg3   = (const float*)d_in[12];
  const float* bb3   = (const float*)d_in[13];
  const float* gcn0w = (const float*)d_in[14];
  const float* gcn0b = (const float*)d_in[15];
  const float* gcn1w = (const float*)d_in[16];
  const float* gcn1b = (const float*)d_in[17];
  const float* lng   = (const float*)d_in[18];
  const float* lnb   = (const float*)d_in[19];
  const float* wih0  = (const float*)d_in[20];
  const float* whh0  = (const float*)d_in[21];
  const float* bih0  = (const float*)d_in[22];
  const float* bhh0  = (const float*)d_in[23];
  const float* wih0r = (const float*)d_in[24];
  const float* whh0r = (const float*)d_in[25];
  const float* bih0r = (const float*)d_in[26];
  const float* bhh0r = (const float*)d_in[27];
  const float* wih1  = (const float*)d_in[28];
  const float* whh1  = (const float*)d_in[29];
  const float* bih1  = (const float*)d_in[30];
  const float* bhh1  = (const float*)d_in[31];
  const float* wih1r = (const float*)d_in[32];
  const float* whh1r = (const float*)d_in[33];
  const float* bih1r = (const float*)d_in[34];
  const float* bhh1r = (const float*)d_in[35];
  const float* lstmg = (const float*)d_in[36];
  const float* lstmb = (const float*)d_in[37];
  const float* clsw  = (const float*)d_in[38];
  const float* clsb  = (const float*)d_in[39];
  float* ws  = (float*)d_ws;
  float* out = (float*)d_out;

  // workspace layout (float offsets), ~23.5 MB total
  float*    An      = ws + 0;                         // 64
  _Float16* bw2f    = (_Float16*)(ws + 64);           // 3072 h
  _Float16* bw3f    = (_Float16*)(ws + 1600);         // 6144 h
  _Float16* feats16 = (_Float16*)(ws + 4672);         // 655360 h
  _Float16* g1b16   = (_Float16*)(ws + 332352);       // 1310720 h
  _Float16* emb16   = (_Float16*)(ws + 987712);       // 163840 h
  _Float16* l0h     = (_Float16*)(ws + 1069632);      // 655360 h
  _Float16* w0f     = (_Float16*)(ws + 1397312);      // 131072 h
  _Float16* w0rf    = (_Float16*)(ws + 1462848);      // 131072 h
  _Float16* w1f     = (_Float16*)(ws + 1528384);      // 524288 h
  _Float16* w1rf    = (_Float16*)(ws + 1790528);      // 524288 h
  _Float16* gw0f    = (_Float16*)(ws + 2052672);      // 8192 h
  _Float16* gw1f    = (_Float16*)(ws + 2056768);      // 16384 h
  h2f16*    wt0f    = (h2f16*)(ws + 2064960);         // 131072 f each
  h2f16*    wt0r    = (h2f16*)(ws + 2196032);
  h2f16*    wt1f    = (h2f16*)(ws + 2327104);
  h2f16*    wt1r    = (h2f16*)(ws + 2458176);
  float*    l1f     = ws + 2589248;                   // 655360 f
  float*    xs      = ws + 3244608;                   // 2621440 f
  float*    tmp     = xs;                             // aliases xs ([10240][128] f32)

  // Stage 0: weight packs
  k_packw<<<24, 256, 0, stream>>>(w2, w3, bg2, bg3, bw2f, bw3f);
  k_packall<<<5216, 256, 0, stream>>>(wih0, wih0r, wih1, wih1r, gcn0w, gcn1w,
                                      w0f, w0rf, w1f, w1rf, gw0f, gw1f);
  // Stage 1: conv front-end
  k_conv<<<10240, 256, 0, stream>>>(x, w1,c1b,bg1,bb1, bw2f,c2b,bg2,bb2,
                                    bw3f,c3b,bg3,bb3, feats16);
  // Adjacency + recurrent weight transposes
  k_an<<<1, 64, 0, stream>>>(ei, An);
  k_trp<<<512,256,0,stream>>>(whh0,  wt0f);
  k_trp<<<512,256,0,stream>>>(whh0r, wt0r);
  k_trp<<<512,256,0,stream>>>(whh1,  wt1f);
  k_trp<<<512,256,0,stream>>>(whh1r, wt1r);

  // Stage 2: GCN (MFMA GEMMs)
  k_gemm_mf<<<dim3(2, 160), 256, 0, stream>>>(feats16, gw0f, nullptr, nullptr, tmp, 10240, 128, 64, 128);
  k_mix1<<<640,256,0,stream>>>(tmp, An, gcn0b, g1b16);
  k_gemm_mf<<<dim3(2, 160), 256, 0, stream>>>(g1b16, gw1f, nullptr, nullptr, tmp, 10240, 128, 128, 128);
  k_mix2<<<1280,128,0,stream>>>(tmp, An, gcn1b, lng, lnb, emb16);

  // Stage 3: BiLSTM layer 0
  k_gemm_mf<<<dim3(16, 20), 256, 0, stream>>>(emb16, w0f,  bih0,  bhh0,  xs,        1280, 1024, 128, 2048);
  k_gemm_mf<<<dim3(16, 20), 256, 0, stream>>>(emb16, w0rf, bih0r, bhh0r, xs + 1024, 1280, 1024, 128, 2048);
  k_lstm<<<128, 1024, 0, stream>>>(xs, wt0f, wt0r, l1f, l0h);

  // BiLSTM layer 1
  k_gemm_mf<<<dim3(16, 20), 256, 0, stream>>>(l0h, w1f,  bih1,  bhh1,  xs,        1280, 1024, 512, 2048);
  k_gemm_mf<<<dim3(16, 20), 256, 0, stream>>>(l0h, w1rf, bih1r, bhh1r, xs + 1024, 1280, 1024, 512, 2048);
  k_lstm<<<128, 1024, 0, stream>>>(xs, wt1f, wt1r, l1f, l0h);

  // Stage 4: LN + classifier
  k_lncls<<<1280, 128, 0, stream>>>(l1f, lstmg, lstmb, clsw, clsb, out);
}

// Round 9
// 324.455 us; speedup vs baseline: 4.4123x; 1.2561x over previous
//
#include <hip/hip_runtime.h>
#include <hip/hip_bf16.h>

#define DEVI __device__ __forceinline__

typedef _Float16 h2f16 __attribute__((ext_vector_type(2)));
typedef _Float16 f16x4 __attribute__((ext_vector_type(4)));
typedef _Float16 f16x8 __attribute__((ext_vector_type(8)));
typedef float    f32x4 __attribute__((ext_vector_type(4)));
union U4H { uint4 u; h2f16 h[4]; };
union F8  { f16x8 v8; f16x4 v4[2]; };

DEVI float sigf(float x){ return 1.f/(1.f + __expf(-x)); }
DEVI float tanh_f(float x){
  float ax = fabsf(x);
  float e = __expf(-2.f*ax);
  float t = (1.f - e)/(1.f + e);
  return copysignf(t, x);
}
DEVI h2f16 hmax2(h2f16 a, h2f16 b){
  h2f16 r; r[0] = a[0] > b[0] ? a[0] : b[0]; r[1] = a[1] > b[1] ? a[1] : b[1]; return r;
}

// ---------------------------------------------------------------------------
// K0: fused prep. bid 0: adjacency; 1..24: conv w pack; 25..5240: GEMM w pack;
// 5241..7288: w_hh transpose+pack (4 matrices).
// ---------------------------------------------------------------------------
__global__ __launch_bounds__(256) void k_prep(
  const int* __restrict__ ei, float* __restrict__ An,
  const float* __restrict__ w2, const float* __restrict__ w3,
  const float* __restrict__ bg2, const float* __restrict__ bg3,
  _Float16* __restrict__ bw2f, _Float16* __restrict__ bw3f,
  const float* __restrict__ a0, const float* __restrict__ a1,
  const float* __restrict__ a2, const float* __restrict__ a3,
  const float* __restrict__ a4, const float* __restrict__ a5,
  _Float16* __restrict__ o0, _Float16* __restrict__ o1,
  _Float16* __restrict__ o2, _Float16* __restrict__ o3,
  _Float16* __restrict__ o4, _Float16* __restrict__ o5,
  const float* __restrict__ whh0, const float* __restrict__ whh0r,
  const float* __restrict__ whh1, const float* __restrict__ whh1r,
  h2f16* __restrict__ wt0f, h2f16* __restrict__ wt0r,
  h2f16* __restrict__ wt1f, h2f16* __restrict__ wt1r)
{
  const int bid = blockIdx.x, tid = threadIdx.x;
  if (bid == 0){
    __shared__ float A[64];
    __shared__ float dinv[8];
    if (tid<64) A[tid] = ((tid>>3)==(tid&7)) ? 1.f : 0.f;
    __syncthreads();
    if (tid==0){
      for (int e=0;e<56;e++){ int s=ei[e], d=ei[56+e]; A[d*8+s] += 1.f; }
    }
    __syncthreads();
    if (tid<8){ float s=0.f; for (int j=0;j<8;j++) s+=A[tid*8+j]; dinv[tid]=rsqrtf(s); }
    __syncthreads();
    if (tid<64) An[tid] = A[tid]*dinv[tid>>3]*dinv[tid&7];
    return;
  }
  if (bid <= 24){
    const int i = (bid-1)*256 + tid;
    const float rs = rsqrtf(1.f+1e-5f);
    if (i < 3072){
      const int j = i&7, m = (i>>3)&15, g = (i>>7)&3, nt = (i>>9)&1, s = i>>10;
      const int kk = 32*s + 8*g + j;
      const int k = kk >> 4, ic = kk & 15, oc = nt*16 + m;
      bw2f[i] = (_Float16)((k < 5 ? w2[oc*80 + ic*5 + k] : 0.f) * (bg2[oc]*rs));
    }
    if (i < 6144){
      const int j = i&7, m = (i>>3)&15, g = (i>>7)&3, wv = (i>>9)&3, s = i>>11;
      const int kk = 32*s + 8*g + j;
      const int k = kk >> 5, ic = kk & 31, oc = wv*16 + m;
      bw3f[i] = (_Float16)(w3[oc*96 + ic*3 + k] * (bg3[oc]*rs));
    }
    return;
  }
  if (bid <= 5240){
    const int i = (bid-25)*256 + tid;
    if      (i <  131072) o0[i] = (_Float16)a0[i];
    else if (i <  262144) o1[i-131072] = (_Float16)a1[i-131072];
    else if (i <  786432) o2[i-262144] = (_Float16)a2[i-262144];
    else if (i < 1310720) o3[i-786432] = (_Float16)a3[i-786432];
    else if (i < 1318912) o4[i-1310720] = (_Float16)a4[i-1310720];
    else if (i < 1335296) o5[i-1318912] = (_Float16)a5[i-1318912];
    return;
  }
  {
    const int idx = (bid-5241)*256 + tid;        // [0, 524288)
    const int which = idx >> 17, i = idx & 131071;
    const int g = i & 1023, jp = i >> 10;
    const float* in = (which==0) ? whh0 : (which==1) ? whh0r : (which==2) ? whh1 : whh1r;
    h2f16* outp    = (which==0) ? wt0f : (which==1) ? wt0r  : (which==2) ? wt1f : wt1r;
    h2f16 p;
    p[0] = (_Float16)in[g*256 + 2*jp];
    p[1] = (_Float16)in[g*256 + 2*jp + 1];
    outp[(long)jp*1024 + g] = p;
  }
}

// ---------------------------------------------------------------------------
// K1: fused conv front-end (unchanged from round 8).
// ---------------------------------------------------------------------------
__global__ __launch_bounds__(256,4) void k_conv(
    const float* __restrict__ x,
    const float* __restrict__ w1g, const float* __restrict__ c1b,
    const float* __restrict__ bg1, const float* __restrict__ bb1,
    const _Float16* __restrict__ bw2f,
    const float* __restrict__ c2b, const float* __restrict__ bg2, const float* __restrict__ bb2,
    const _Float16* __restrict__ bw3f,
    const float* __restrict__ c3b, const float* __restrict__ bg3, const float* __restrict__ bb3,
    _Float16* __restrict__ feats)
{
  __shared__ __align__(16) unsigned char smb[38592];
  __shared__ h2f16 w1p[16][4];
  __shared__ float kb1o[16], kb2o[32], kb3o[64];
  h2f16* sxh = reinterpret_cast<h2f16*>(smb + 20160);
  const int tid = threadIdx.x;
  const long sig = blockIdx.x;
  const float* xg = x + sig*3000;

  {
    const float4* xg4 = reinterpret_cast<const float4*>(xg);
    for (int i=tid; i<750; i+=256){
      float4 v = xg4[i];
      h2f16 p0; p0[0]=(_Float16)v.x; p0[1]=(_Float16)v.y;
      h2f16 p1; p1[0]=(_Float16)v.z; p1[1]=(_Float16)v.w;
      sxh[2*i+2] = p0; sxh[2*i+3] = p1;
    }
    if (tid<3){
      h2f16 z; z[0]=(_Float16)0.f; z[1]=(_Float16)0.f;
      sxh[tid<2 ? tid : 1502] = z;
    }
    if (tid<32){
      const int rr = tid>>3, cp = tid&7;
      const int row = (rr<2) ? rr : (500+rr);
      h2f16 z; z[0]=(_Float16)0.f; z[1]=(_Float16)0.f;
      *reinterpret_cast<h2f16*>(smb + row*40 + 4*cp) = z;
    }
    const float rs = rsqrtf(1.f+1e-5f);
    if (tid<64){
      const int c = tid>>2, j = tid&3;
      const float s = bg1[c]*rs;
      h2f16 p;
      if (j==0){ p[0]=(_Float16)0.f; p[1]=(_Float16)(w1g[c*7+0]*s); }
      else     { p[0]=(_Float16)(w1g[c*7+2*j-1]*s); p[1]=(_Float16)(w1g[c*7+2*j]*s); }
      w1p[c][j] = p;
    }
    if (tid<16) kb1o[tid] = c1b[tid]*(bg1[tid]*rs) + bb1[tid];
    if (tid<32) kb2o[tid] = c2b[tid]*(bg2[tid]*rs) + bb2[tid];
    if (tid<64) kb3o[tid] = c3b[tid]*(bg3[tid]*rs) + bb3[tid];
  }
  __syncthreads();

  // Phase A
  {
    const int cp = tid & 7;
    h2f16 wpa[4], wpb[4];
    #pragma unroll
    for (int j=0;j<4;j++){ wpa[j] = w1p[2*cp][j]; wpb[j] = w1p[2*cp+1][j]; }
    const float oa = kb1o[2*cp], ob = kb1o[2*cp+1];
    for (int u = tid>>3; u<500; u+=32){
      h2f16 xq[6];
      #pragma unroll
      for (int r=0;r<6;r++) xq[r] = sxh[3*u + r];
      float a0=0.f,a1=0.f,a2=0.f,b0=0.f,b1=0.f,b2=0.f;
      #pragma unroll
      for (int j=0;j<4;j++){
        a0 = __builtin_amdgcn_fdot2(xq[j],   wpa[j], a0, false);
        a1 = __builtin_amdgcn_fdot2(xq[j+1], wpa[j], a1, false);
        a2 = __builtin_amdgcn_fdot2(xq[j+2], wpa[j], a2, false);
        b0 = __builtin_amdgcn_fdot2(xq[j],   wpb[j], b0, false);
        b1 = __builtin_amdgcn_fdot2(xq[j+1], wpb[j], b1, false);
        b2 = __builtin_amdgcn_fdot2(xq[j+2], wpb[j], b2, false);
      }
      const float ya = fmaxf(fmaxf(fmaxf(a0,a1),a2) + oa, 0.f);
      const float yb = fmaxf(fmaxf(fmaxf(b0,b1),b2) + ob, 0.f);
      h2f16 p; p[0]=(_Float16)ya; p[1]=(_Float16)yb;
      *reinterpret_cast<h2f16*>(smb + (u+2)*40 + 4*cp) = p;
    }
  }
  __syncthreads();

  const int wv = tid >> 6, lane = tid & 63;
  const int m = lane & 15, g = lane >> 4;

  // Phase B
  {
    const int nt = wv & 1;
    f16x8 bf[3];
    #pragma unroll
    for (int s=0;s<3;s++)
      bf[s] = *reinterpret_cast<const f16x8*>(&bw2f[(((s*2+nt)*4+g)*16+m)*8]);
    const int oc = nt*16 + m;
    const float of = kb2o[oc];
    #pragma unroll
    for (int i=0;i<8;i++){
      const int mt = (wv>>1) + 2*i;
      const int trow = mt*16 + m;
      f32x4 acc = {0.f,0.f,0.f,0.f};
      #pragma unroll
      for (int s=0;s<3;s++){
        const int kk = 32*s + 8*g;
        const int k = kk >> 4;
        const int ab = 80*trow + 40*k + 16*(g&1);
        F8 a;
        a.v4[0] = *reinterpret_cast<const f16x4*>(smb + ab);
        a.v4[1] = *reinterpret_cast<const f16x4*>(smb + ab + 8);
        acc = __builtin_amdgcn_mfma_f32_16x16x32_f16(a.v8, bf[s], acc, 0,0,0);
      }
      #pragma unroll
      for (int r=0;r<4;r++){
        const int t = mt*16 + 4*g + r;
        const float z = fmaxf(acc[r] + of, 0.f);
        *reinterpret_cast<_Float16*>(smb + 20160 + t*72 + 2*oc) = (_Float16)z;
      }
    }
  }
  __syncthreads();

  // Pool
  {
    if (tid < 240){
      const int rr = tid >> 4, cc = tid & 15;
      const int row = (rr == 0) ? 0 : (83 + rr);
      h2f16 z; z[0]=(_Float16)0.f; z[1]=(_Float16)0.f;
      *reinterpret_cast<h2f16*>(smb + row*80 + 4*cc) = z;
    }
    for (int i=tid; i<1328; i+=256){
      const int u = i >> 4, cc = i & 15;
      h2f16 a = *reinterpret_cast<const h2f16*>(smb + 20160 + (3*u)*72 + 4*cc);
      h2f16 b = *reinterpret_cast<const h2f16*>(smb + 20160 + (3*u+1)*72 + 4*cc);
      h2f16 c = *reinterpret_cast<const h2f16*>(smb + 20160 + (3*u+2)*72 + 4*cc);
      *reinterpret_cast<h2f16*>(smb + (u+1)*80 + 4*cc) = hmax2(hmax2(a,b), c);
    }
  }
  __syncthreads();

  // Phase C
  {
    f16x8 bf[3];
    #pragma unroll
    for (int s=0;s<3;s++)
      bf[s] = *reinterpret_cast<const f16x8*>(&bw3f[(((s*4+wv)*4+g)*16+m)*8]);
    const int oc = wv*16 + m;
    const float of = kb3o[oc];
    float macc = 0.f;
    #pragma unroll
    for (int mt=0; mt<6; mt++){
      const int trow = mt*16 + m;
      f32x4 acc = {0.f,0.f,0.f,0.f};
      #pragma unroll
      for (int s=0;s<3;s++){
        f16x8 af = *reinterpret_cast<const f16x8*>(smb + (trow + s)*80 + 16*g);
        acc = __builtin_amdgcn_mfma_f32_16x16x32_f16(af, bf[s], acc, 0,0,0);
      }
      #pragma unroll
      for (int r=0;r<4;r++){
        const int t = mt*16 + 4*g + r;
        if (t < 83) macc += fmaxf(acc[r] + of, 0.f);
      }
    }
    macc += __shfl_xor(macc, 16);
    macc += __shfl_xor(macc, 32);
    if (lane < 16) feats[sig*64 + oc] = (_Float16)(macc * (1.f/83.f));
  }
}

// ---------------------------------------------------------------------------
// K3: MFMA f16 GEMM (single-W): C = X16 @ W16^T (+b1+b2), f32 out.
// ---------------------------------------------------------------------------
__global__ __launch_bounds__(256) void k_gemm_mf(
  const _Float16* __restrict__ X, const _Float16* __restrict__ W,
  const float* __restrict__ b1, const float* __restrict__ b2,
  float* __restrict__ C, int M, int N, int K, int ldc)
{
  __shared__ __align__(16) unsigned char lds[128*72];
  unsigned char* Xs = lds;
  unsigned char* Ws = lds + 64*72;
  const int tid = threadIdx.x;
  const int m0 = blockIdx.y*64, n0 = blockIdx.x*64;
  const int wv = tid>>6, lane = tid&63, m = lane&15, g = lane>>4;
  const int sr = tid>>2, sq = tid&3;
  f32x4 acc[4] = {{0.f,0.f,0.f,0.f},{0.f,0.f,0.f,0.f},{0.f,0.f,0.f,0.f},{0.f,0.f,0.f,0.f}};
  for (int k0=0; k0<K; k0+=32){
    uint4 xa = *reinterpret_cast<const uint4*>(X + (long)(m0+sr)*K + k0 + sq*8);
    uint4 wa = *reinterpret_cast<const uint4*>(W + (long)(n0+sr)*K + k0 + sq*8);
    __syncthreads();
    *reinterpret_cast<uint4*>(Xs + sr*72 + sq*16) = xa;
    *reinterpret_cast<uint4*>(Ws + sr*72 + sq*16) = wa;
    __syncthreads();
    f16x8 af = *reinterpret_cast<const f16x8*>(Xs + (wv*16+m)*72 + g*16);
    #pragma unroll
    for (int nt=0;nt<4;nt++){
      f16x8 bf = *reinterpret_cast<const f16x8*>(Ws + (nt*16+m)*72 + g*16);
      acc[nt] = __builtin_amdgcn_mfma_f32_16x16x32_f16(af, bf, acc[nt], 0,0,0);
    }
  }
  #pragma unroll
  for (int nt=0;nt<4;nt++){
    const int col = n0 + nt*16 + m;
    float bias = 0.f;
    if (b1) bias += b1[col];
    if (b2) bias += b2[col];
    #pragma unroll
    for (int r=0;r<4;r++)
      C[(long)(m0 + wv*16 + g*4 + r)*ldc + col] = acc[nt][r] + bias;
  }
}

// ---------------------------------------------------------------------------
// K3b: dual-W MFMA GEMM: blockIdx.z selects (Wa,b1a,b2a,C) vs (Wb,b1b,b2b,C+co)
// ---------------------------------------------------------------------------
__global__ __launch_bounds__(256) void k_gemm_mf2(
  const _Float16* __restrict__ X,
  const _Float16* __restrict__ Wa, const _Float16* __restrict__ Wb,
  const float* __restrict__ b1a, const float* __restrict__ b2a,
  const float* __restrict__ b1b, const float* __restrict__ b2b,
  float* __restrict__ C, int co, int M, int N, int K, int ldc)
{
  __shared__ __align__(16) unsigned char lds[128*72];
  unsigned char* Xs = lds;
  unsigned char* Ws = lds + 64*72;
  const int z = blockIdx.z;
  const _Float16* W = z ? Wb : Wa;
  const float* b1 = z ? b1b : b1a;
  const float* b2 = z ? b2b : b2a;
  float* Cz = C + (z ? co : 0);
  const int tid = threadIdx.x;
  const int m0 = blockIdx.y*64, n0 = blockIdx.x*64;
  const int wv = tid>>6, lane = tid&63, m = lane&15, g = lane>>4;
  const int sr = tid>>2, sq = tid&3;
  f32x4 acc[4] = {{0.f,0.f,0.f,0.f},{0.f,0.f,0.f,0.f},{0.f,0.f,0.f,0.f},{0.f,0.f,0.f,0.f}};
  for (int k0=0; k0<K; k0+=32){
    uint4 xa = *reinterpret_cast<const uint4*>(X + (long)(m0+sr)*K + k0 + sq*8);
    uint4 wa = *reinterpret_cast<const uint4*>(W + (long)(n0+sr)*K + k0 + sq*8);
    __syncthreads();
    *reinterpret_cast<uint4*>(Xs + sr*72 + sq*16) = xa;
    *reinterpret_cast<uint4*>(Ws + sr*72 + sq*16) = wa;
    __syncthreads();
    f16x8 af = *reinterpret_cast<const f16x8*>(Xs + (wv*16+m)*72 + g*16);
    #pragma unroll
    for (int nt=0;nt<4;nt++){
      f16x8 bf = *reinterpret_cast<const f16x8*>(Ws + (nt*16+m)*72 + g*16);
      acc[nt] = __builtin_amdgcn_mfma_f32_16x16x32_f16(af, bf, acc[nt], 0,0,0);
    }
  }
  #pragma unroll
  for (int nt=0;nt<4;nt++){
    const int col = n0 + nt*16 + m;
    float bias = b1[col] + b2[col];
    #pragma unroll
    for (int r=0;r<4;r++)
      Cz[(long)(m0 + wv*16 + g*4 + r)*ldc + col] = acc[nt][r] + bias;
  }
}

// ---------------------------------------------------------------------------
// K4: g1 mix (f16 out)
// ---------------------------------------------------------------------------
__global__ __launch_bounds__(256) void k_mix1(
  const float* __restrict__ tmp0, const float* __restrict__ An,
  const float* __restrict__ b0, _Float16* __restrict__ g1)
{
  __shared__ float ans[64];
  if (threadIdx.x < 64) ans[threadIdx.x] = An[threadIdx.x];
  __syncthreads();
  const long idx = (long)blockIdx.x*256 + threadIdx.x;   // over 1280*128
  const int g = (int)(idx >> 7), j = (int)(idx & 127);
  const float* base = tmp0 + (long)g*1024;
  float t[8];
  #pragma unroll
  for (int c=0;c<8;c++) t[c] = base[c*128+j];
  const float bj = b0[j];
  #pragma unroll
  for (int i=0;i<8;i++){
    float s = bj;
    #pragma unroll
    for (int c=0;c<8;c++) s += ans[i*8+c]*t[c];
    g1[(long)g*1024 + i*128 + j] = (_Float16)fmaxf(s, 0.f);
  }
}

// ---------------------------------------------------------------------------
// K6: g2 mix + LN + node-mean -> emb (f16 out)
// ---------------------------------------------------------------------------
__global__ __launch_bounds__(128) void k_mix2(
  const float* __restrict__ tmp1, const float* __restrict__ An,
  const float* __restrict__ b1, const float* __restrict__ lng,
  const float* __restrict__ lnb, _Float16* __restrict__ emb)
{
  const int g = blockIdx.x, j = threadIdx.x;
  __shared__ float ans[64];
  __shared__ float g2s[8*128];
  __shared__ float stats[16];
  if (j<64) ans[j] = An[j];
  const float* base = tmp1 + (long)g*1024;
  float t[8];
  #pragma unroll
  for (int c=0;c<8;c++) t[c] = base[c*128 + j];
  const float bj = b1[j];
  __syncthreads();
  #pragma unroll
  for (int i=0;i<8;i++){
    float s = bj;
    #pragma unroll
    for (int c=0;c<8;c++) s += ans[i*8+c]*t[c];
    g2s[i*128+j] = s;
  }
  __syncthreads();
  {
    const int c = j>>4, l = j&15;
    float s=0.f, sq=0.f;
    for (int jj=l; jj<128; jj+=16){ float v=g2s[c*128+jj]; s+=v; sq+=v*v; }
    #pragma unroll
    for (int off=8; off>=1; off>>=1){ s += __shfl_xor(s, off); sq += __shfl_xor(sq, off); }
    if (l==0){
      float m = s*(1.f/128.f);
      stats[2*c] = m;
      stats[2*c+1] = rsqrtf(sq*(1.f/128.f) - m*m + 1e-5f);
    }
  }
  __syncthreads();
  float acc=0.f;
  #pragma unroll
  for (int i=0;i<8;i++) acc += (g2s[i*128+j] - stats[2*i]) * stats[2*i+1];
  emb[(long)g*128 + j] = (_Float16)(lng[j]*acc*0.125f + lnb[j]);
}

// ---------------------------------------------------------------------------
// K8: one LSTM layer, both directions. Block = (batch, dir), 1024 threads.
// Weight residency: jp 0..7 in regs (all threads), jg=0's jp 8..31 in LDS;
// only jg=1..3 stream jp 8..31 from L2 -> 288 KB/step (was 512).
// ---------------------------------------------------------------------------
__global__ __launch_bounds__(1024) void k_lstm(
    const float* __restrict__ xs,          // [1280][2048] fwd|rev gates
    const h2f16* __restrict__ wtf,         // [128][1024] packed j-pairs
    const h2f16* __restrict__ wtr,
    float* __restrict__ outf,              // [1280][512]
    _Float16* __restrict__ outh)           // [1280][512]
{
  const int S = 20;
  const int b = blockIdx.x >> 1, dir = blockIdx.x & 1;
  const h2f16* wt = dir ? wtr : wtf;
  __shared__ float part[4][1024];
  __shared__ _Float16 hsh[256];
  __shared__ __align__(16) unsigned char wlds[98304];   // jg0 rows jp 8..31
  const int tid = threadIdx.x;
  const int jg = tid >> 8, r = tid & 255, grow = r*4;
  // reg-resident jp 0..7 slice for this thread
  uint4 wreg[8];
  #pragma unroll
  for (int jp=0;jp<8;jp++)
    wreg[jp] = *reinterpret_cast<const uint4*>(
        reinterpret_cast<const unsigned int*>(wt + (long)(jg*32+jp)*1024 + grow));
  // LDS-resident rows 8..31 (the jg=0 slice, full 1024 gate columns)
  {
    const uint4* wsrc = reinterpret_cast<const uint4*>(wt) + 2048;  // row 8
    uint4* wdst = reinterpret_cast<uint4*>(wlds);
    for (int i=tid; i<6144; i+=1024) wdst[i] = wsrc[i];
  }
  if (tid < 256) hsh[tid] = (_Float16)0.f;
  float cc = 0.f;
  __syncthreads();
  const h2f16* hp2 = reinterpret_cast<const h2f16*>(hsh);
  for (int st=0; st<S; ++st){
    const int t = dir ? (S-1-st) : st;
    float a0=0.f,a1=0.f,a2=0.f,a3=0.f;
    #pragma unroll
    for (int jp=0; jp<8; ++jp){
      const h2f16 hv = hp2[jg*32 + jp];
      U4H w; w.u = wreg[jp];
      a0 = __builtin_amdgcn_fdot2(hv, w.h[0], a0, false);
      a1 = __builtin_amdgcn_fdot2(hv, w.h[1], a1, false);
      a2 = __builtin_amdgcn_fdot2(hv, w.h[2], a2, false);
      a3 = __builtin_amdgcn_fdot2(hv, w.h[3], a3, false);
    }
    if (jg == 0){
      #pragma unroll 8
      for (int jp=8; jp<32; ++jp){
        const h2f16 hv = hp2[jp];
        U4H w; w.u = *reinterpret_cast<const uint4*>(wlds + (long)(jp-8)*4096 + grow*4);
        a0 = __builtin_amdgcn_fdot2(hv, w.h[0], a0, false);
        a1 = __builtin_amdgcn_fdot2(hv, w.h[1], a1, false);
        a2 = __builtin_amdgcn_fdot2(hv, w.h[2], a2, false);
        a3 = __builtin_amdgcn_fdot2(hv, w.h[3], a3, false);
      }
    } else {
      #pragma unroll 8
      for (int jp=8; jp<32; ++jp){
        const h2f16 hv = hp2[jg*32 + jp];
        U4H w; w.u = *reinterpret_cast<const uint4*>(
            reinterpret_cast<const unsigned int*>(wt + (long)(jg*32+jp)*1024 + grow));
        a0 = __builtin_amdgcn_fdot2(hv, w.h[0], a0, false);
        a1 = __builtin_amdgcn_fdot2(hv, w.h[1], a1, false);
        a2 = __builtin_amdgcn_fdot2(hv, w.h[2], a2, false);
        a3 = __builtin_amdgcn_fdot2(hv, w.h[3], a3, false);
      }
    }
    *reinterpret_cast<float4*>(&part[jg][grow]) = make_float4(a0,a1,a2,a3);
    __syncthreads();
    if (tid < 256){
      const float* xrow = xs + ((long)b*S + t)*2048 + dir*1024;
      float g0 = xrow[tid]
               + (part[0][tid]      + part[1][tid])      + (part[2][tid]      + part[3][tid]);
      float g1 = xrow[256+tid]
               + (part[0][256+tid]  + part[1][256+tid])  + (part[2][256+tid]  + part[3][256+tid]);
      float g2 = xrow[512+tid]
               + (part[0][512+tid]  + part[1][512+tid])  + (part[2][512+tid]  + part[3][512+tid]);
      float g3 = xrow[768+tid]
               + (part[0][768+tid]  + part[1][768+tid])  + (part[2][768+tid]  + part[3][768+tid]);
      cc = sigf(g1)*cc + sigf(g0)*tanh_f(g2);
      const float h = sigf(g3)*tanh_f(cc);
      hsh[tid] = (_Float16)h;
      const long o = ((long)b*S + t)*512 + dir*256 + tid;
      outf[o] = h;
      outh[o] = (_Float16)h;
    }
    __syncthreads();
  }
}

// ---------------------------------------------------------------------------
// K11: final LayerNorm(512) + classifier (5) per row
// ---------------------------------------------------------------------------
__global__ __launch_bounds__(128) void k_lncls(
  const float* __restrict__ in, const float* __restrict__ g,
  const float* __restrict__ b, const float* __restrict__ cw,
  const float* __restrict__ cb, float* __restrict__ out)
{
  const int row = blockIdx.x, tid = threadIdx.x;
  __shared__ float sred[4];
  __shared__ float cred[2][5];
  float4 v = *reinterpret_cast<const float4*>(in + (long)row*512 + tid*4);
  float s  = v.x+v.y+v.z+v.w;
  float sq = v.x*v.x+v.y*v.y+v.z*v.z+v.w*v.w;
  #pragma unroll
  for (int off=32; off>=1; off>>=1){ s += __shfl_xor(s, off); sq += __shfl_xor(sq, off); }
  const int wv = tid>>6;
  if ((tid&63)==0){ sred[wv*2]=s; sred[wv*2+1]=sq; }
  __syncthreads();
  const float S = sred[0]+sred[2], SQ = sred[1]+sred[3];
  const float m = S*(1.f/512.f);
  const float rstd = rsqrtf(SQ*(1.f/512.f) - m*m + 1e-5f);
  float4 gg = *reinterpret_cast<const float4*>(g + tid*4);
  float4 bb = *reinterpret_cast<const float4*>(b + tid*4);
  const float n0 = (v.x-m)*rstd*gg.x + bb.x;
  const float n1 = (v.y-m)*rstd*gg.y + bb.y;
  const float n2 = (v.z-m)*rstd*gg.z + bb.z;
  const float n3 = (v.w-m)*rstd*gg.w + bb.w;
  #pragma unroll
  for (int nc=0; nc<5; ++nc){
    float4 w = *reinterpret_cast<const float4*>(cw + nc*512 + tid*4);
    float p = n0*w.x + n1*w.y + n2*w.z + n3*w.w;
    #pragma unroll
    for (int off=32; off>=1; off>>=1) p += __shfl_xor(p, off);
    if ((tid&63)==0) cred[wv][nc] = p;
  }
  __syncthreads();
  if (tid < 5) out[(long)row*5 + tid] = cred[0][tid] + cred[1][tid] + cb[tid];
}

// ---------------------------------------------------------------------------
extern "C" void kernel_launch(void* const* d_in, const int* in_sizes, int n_in,
                              void* d_out, int out_size, void* d_ws, size_t ws_size,
                              hipStream_t stream)
{
  const float* x     = (const float*)d_in[0];
  const int*   ei    = (const int*)d_in[1];
  const float* w1    = (const float*)d_in[2];
  const float* c1b   = (const float*)d_in[3];
  const float* bg1   = (const float*)d_in[4];
  const float* bb1   = (const float*)d_in[5];
  const float* w2    = (const float*)d_in[6];
  const float* c2b   = (const float*)d_in[7];
  const float* bg2   = (const float*)d_in[8];
  const float* bb2   = (const float*)d_in[9];
  const float* w3    = (const float*)d_in[10];
  const float* c3b   = (const float*)d_in[11];
  const float* bg3   = (const float*)d_in[12];
  const float* bb3   = (const float*)d_in[13];
  const float* gcn0w = (const float*)d_in[14];
  const float* gcn0b = (const float*)d_in[15];
  const float* gcn1w = (const float*)d_in[16];
  const float* gcn1b = (const float*)d_in[17];
  const float* lng   = (const float*)d_in[18];
  const float* lnb   = (const float*)d_in[19];
  const float* wih0  = (const float*)d_in[20];
  const float* whh0  = (const float*)d_in[21];
  const float* bih0  = (const float*)d_in[22];
  const float* bhh0  = (const float*)d_in[23];
  const float* wih0r = (const float*)d_in[24];
  const float* whh0r = (const float*)d_in[25];
  const float* bih0r = (const float*)d_in[26];
  const float* bhh0r = (const float*)d_in[27];
  const float* wih1  = (const float*)d_in[28];
  const float* whh1  = (const float*)d_in[29];
  const float* bih1  = (const float*)d_in[30];
  const float* bhh1  = (const float*)d_in[31];
  const float* wih1r = (const float*)d_in[32];
  const float* whh1r = (const float*)d_in[33];
  const float* bih1r = (const float*)d_in[34];
  const float* bhh1r = (const float*)d_in[35];
  const float* lstmg = (const float*)d_in[36];
  const float* lstmb = (const float*)d_in[37];
  const float* clsw  = (const float*)d_in[38];
  const float* clsb  = (const float*)d_in[39];
  float* ws  = (float*)d_ws;
  float* out = (float*)d_out;

  // workspace layout (float offsets), ~23.5 MB total
  float*    An      = ws + 0;                         // 64
  _Float16* bw2f    = (_Float16*)(ws + 64);           // 3072 h
  _Float16* bw3f    = (_Float16*)(ws + 1600);         // 6144 h
  _Float16* feats16 = (_Float16*)(ws + 4672);         // 655360 h
  _Float16* g1b16   = (_Float16*)(ws + 332352);       // 1310720 h
  _Float16* emb16   = (_Float16*)(ws + 987712);       // 163840 h
  _Float16* l0h     = (_Float16*)(ws + 1069632);      // 655360 h
  _Float16* w0f     = (_Float16*)(ws + 1397312);      // 131072 h
  _Float16* w0rf    = (_Float16*)(ws + 1462848);      // 131072 h
  _Float16* w1f     = (_Float16*)(ws + 1528384);      // 524288 h
  _Float16* w1rf    = (_Float16*)(ws + 1790528);      // 524288 h
  _Float16* gw0f    = (_Float16*)(ws + 2052672);      // 8192 h
  _Float16* gw1f    = (_Float16*)(ws + 2056768);      // 16384 h
  h2f16*    wt0f    = (h2f16*)(ws + 2064960);         // 131072 f each
  h2f16*    wt0r    = (h2f16*)(ws + 2196032);
  h2f16*    wt1f    = (h2f16*)(ws + 2327104);
  h2f16*    wt1r    = (h2f16*)(ws + 2458176);
  float*    l1f     = ws + 2589248;                   // 655360 f
  float*    xs      = ws + 3244608;                   // 2621440 f
  float*    tmp     = xs;                             // aliases xs

  // Stage 0: fused prep (adjacency + all weight packs/transposes)
  k_prep<<<7289, 256, 0, stream>>>(ei, An, w2, w3, bg2, bg3, bw2f, bw3f,
                                   wih0, wih0r, wih1, wih1r, gcn0w, gcn1w,
                                   w0f, w0rf, w1f, w1rf, gw0f, gw1f,
                                   whh0, whh0r, whh1, whh1r,
                                   wt0f, wt0r, wt1f, wt1r);
  // Stage 1: conv front-end
  k_conv<<<10240, 256, 0, stream>>>(x, w1,c1b,bg1,bb1, bw2f,c2b,bg2,bb2,
                                    bw3f,c3b,bg3,bb3, feats16);

  // Stage 2: GCN
  k_gemm_mf<<<dim3(2, 160), 256, 0, stream>>>(feats16, gw0f, nullptr, nullptr, tmp, 10240, 128, 64, 128);
  k_mix1<<<640,256,0,stream>>>(tmp, An, gcn0b, g1b16);
  k_gemm_mf<<<dim3(2, 160), 256, 0, stream>>>(g1b16, gw1f, nullptr, nullptr, tmp, 10240, 128, 128, 128);
  k_mix2<<<1280,128,0,stream>>>(tmp, An, gcn1b, lng, lnb, emb16);

  // Stage 3: BiLSTM layer 0
  k_gemm_mf2<<<dim3(16, 20, 2), 256, 0, stream>>>(emb16, w0f, w0rf,
      bih0, bhh0, bih0r, bhh0r, xs, 1024, 1280, 1024, 128, 2048);
  k_lstm<<<128, 1024, 0, stream>>>(xs, wt0f, wt0r, l1f, l0h);

  // BiLSTM layer 1
  k_gemm_mf2<<<dim3(16, 20, 2), 256, 0, stream>>>(l0h, w1f, w1rf,
      bih1, bhh1, bih1r, bhh1r, xs, 1024, 1280, 1024, 512, 2048);
  k_lstm<<<128, 1024, 0, stream>>>(xs, wt1f, wt1r, l1f, l0h);

  // Stage 4: LN + classifier
  k_lncls<<<1280, 128, 0, stream>>>(l1f, lstmg, lstmb, clsw, clsb, out);
}

// Round 10
// 295.931 us; speedup vs baseline: 4.8376x; 1.0964x over previous
//
#include <hip/hip_runtime.h>
#include <hip/hip_bf16.h>

#define DEVI __device__ __forceinline__

typedef _Float16 h2f16 __attribute__((ext_vector_type(2)));
typedef _Float16 f16x4 __attribute__((ext_vector_type(4)));
typedef _Float16 f16x8 __attribute__((ext_vector_type(8)));
typedef float    f32x4 __attribute__((ext_vector_type(4)));
union U4H { uint4 u; h2f16 h[4]; };
union F8  { f16x8 v8; f16x4 v4[2]; };

DEVI float sigf(float x){ return 1.f/(1.f + __expf(-x)); }
DEVI float tanh_f(float x){
  float ax = fabsf(x);
  float e = __expf(-2.f*ax);
  float t = (1.f - e)/(1.f + e);
  return copysignf(t, x);
}
DEVI h2f16 hmax2(h2f16 a, h2f16 b){
  h2f16 r; r[0] = a[0] > b[0] ? a[0] : b[0]; r[1] = a[1] > b[1] ? a[1] : b[1]; return r;
}

// ---------------------------------------------------------------------------
// K0: fused prep. bid 0: adjacency; 1..24: conv w pack; 25..5240: GEMM w pack;
// 5241..7288: w_hh transpose+pack (4 matrices).
// ---------------------------------------------------------------------------
__global__ __launch_bounds__(256) void k_prep(
  const int* __restrict__ ei, float* __restrict__ An,
  const float* __restrict__ w2, const float* __restrict__ w3,
  const float* __restrict__ bg2, const float* __restrict__ bg3,
  _Float16* __restrict__ bw2f, _Float16* __restrict__ bw3f,
  const float* __restrict__ a0, const float* __restrict__ a1,
  const float* __restrict__ a2, const float* __restrict__ a3,
  const float* __restrict__ a4, const float* __restrict__ a5,
  _Float16* __restrict__ o0, _Float16* __restrict__ o1,
  _Float16* __restrict__ o2, _Float16* __restrict__ o3,
  _Float16* __restrict__ o4, _Float16* __restrict__ o5,
  const float* __restrict__ whh0, const float* __restrict__ whh0r,
  const float* __restrict__ whh1, const float* __restrict__ whh1r,
  h2f16* __restrict__ wt0f, h2f16* __restrict__ wt0r,
  h2f16* __restrict__ wt1f, h2f16* __restrict__ wt1r)
{
  const int bid = blockIdx.x, tid = threadIdx.x;
  if (bid == 0){
    __shared__ float A[64];
    __shared__ float dinv[8];
    if (tid<64) A[tid] = ((tid>>3)==(tid&7)) ? 1.f : 0.f;
    __syncthreads();
    if (tid==0){
      for (int e=0;e<56;e++){ int s=ei[e], d=ei[56+e]; A[d*8+s] += 1.f; }
    }
    __syncthreads();
    if (tid<8){ float s=0.f; for (int j=0;j<8;j++) s+=A[tid*8+j]; dinv[tid]=rsqrtf(s); }
    __syncthreads();
    if (tid<64) An[tid] = A[tid]*dinv[tid>>3]*dinv[tid&7];
    return;
  }
  if (bid <= 24){
    const int i = (bid-1)*256 + tid;
    const float rs = rsqrtf(1.f+1e-5f);
    if (i < 3072){
      const int j = i&7, m = (i>>3)&15, g = (i>>7)&3, nt = (i>>9)&1, s = i>>10;
      const int kk = 32*s + 8*g + j;
      const int k = kk >> 4, ic = kk & 15, oc = nt*16 + m;
      bw2f[i] = (_Float16)((k < 5 ? w2[oc*80 + ic*5 + k] : 0.f) * (bg2[oc]*rs));
    }
    if (i < 6144){
      const int j = i&7, m = (i>>3)&15, g = (i>>7)&3, wv = (i>>9)&3, s = i>>11;
      const int kk = 32*s + 8*g + j;
      const int k = kk >> 5, ic = kk & 31, oc = wv*16 + m;
      bw3f[i] = (_Float16)(w3[oc*96 + ic*3 + k] * (bg3[oc]*rs));
    }
    return;
  }
  if (bid <= 5240){
    const int i = (bid-25)*256 + tid;
    if      (i <  131072) o0[i] = (_Float16)a0[i];
    else if (i <  262144) o1[i-131072] = (_Float16)a1[i-131072];
    else if (i <  786432) o2[i-262144] = (_Float16)a2[i-262144];
    else if (i < 1310720) o3[i-786432] = (_Float16)a3[i-786432];
    else if (i < 1318912) o4[i-1310720] = (_Float16)a4[i-1310720];
    else if (i < 1335296) o5[i-1318912] = (_Float16)a5[i-1318912];
    return;
  }
  {
    const int idx = (bid-5241)*256 + tid;        // [0, 524288)
    const int which = idx >> 17, i = idx & 131071;
    const int g = i & 1023, jp = i >> 10;
    const float* in = (which==0) ? whh0 : (which==1) ? whh0r : (which==2) ? whh1 : whh1r;
    h2f16* outp    = (which==0) ? wt0f : (which==1) ? wt0r  : (which==2) ? wt1f : wt1r;
    h2f16 p;
    p[0] = (_Float16)in[g*256 + 2*jp];
    p[1] = (_Float16)in[g*256 + 2*jp + 1];
    outp[(long)jp*1024 + g] = p;
  }
}

// ---------------------------------------------------------------------------
// K1: fused conv front-end (unchanged).
// ---------------------------------------------------------------------------
__global__ __launch_bounds__(256,4) void k_conv(
    const float* __restrict__ x,
    const float* __restrict__ w1g, const float* __restrict__ c1b,
    const float* __restrict__ bg1, const float* __restrict__ bb1,
    const _Float16* __restrict__ bw2f,
    const float* __restrict__ c2b, const float* __restrict__ bg2, const float* __restrict__ bb2,
    const _Float16* __restrict__ bw3f,
    const float* __restrict__ c3b, const float* __restrict__ bg3, const float* __restrict__ bb3,
    _Float16* __restrict__ feats)
{
  __shared__ __align__(16) unsigned char smb[38592];
  __shared__ h2f16 w1p[16][4];
  __shared__ float kb1o[16], kb2o[32], kb3o[64];
  h2f16* sxh = reinterpret_cast<h2f16*>(smb + 20160);
  const int tid = threadIdx.x;
  const long sig = blockIdx.x;
  const float* xg = x + sig*3000;

  {
    const float4* xg4 = reinterpret_cast<const float4*>(xg);
    for (int i=tid; i<750; i+=256){
      float4 v = xg4[i];
      h2f16 p0; p0[0]=(_Float16)v.x; p0[1]=(_Float16)v.y;
      h2f16 p1; p1[0]=(_Float16)v.z; p1[1]=(_Float16)v.w;
      sxh[2*i+2] = p0; sxh[2*i+3] = p1;
    }
    if (tid<3){
      h2f16 z; z[0]=(_Float16)0.f; z[1]=(_Float16)0.f;
      sxh[tid<2 ? tid : 1502] = z;
    }
    if (tid<32){
      const int rr = tid>>3, cp = tid&7;
      const int row = (rr<2) ? rr : (500+rr);
      h2f16 z; z[0]=(_Float16)0.f; z[1]=(_Float16)0.f;
      *reinterpret_cast<h2f16*>(smb + row*40 + 4*cp) = z;
    }
    const float rs = rsqrtf(1.f+1e-5f);
    if (tid<64){
      const int c = tid>>2, j = tid&3;
      const float s = bg1[c]*rs;
      h2f16 p;
      if (j==0){ p[0]=(_Float16)0.f; p[1]=(_Float16)(w1g[c*7+0]*s); }
      else     { p[0]=(_Float16)(w1g[c*7+2*j-1]*s); p[1]=(_Float16)(w1g[c*7+2*j]*s); }
      w1p[c][j] = p;
    }
    if (tid<16) kb1o[tid] = c1b[tid]*(bg1[tid]*rs) + bb1[tid];
    if (tid<32) kb2o[tid] = c2b[tid]*(bg2[tid]*rs) + bb2[tid];
    if (tid<64) kb3o[tid] = c3b[tid]*(bg3[tid]*rs) + bb3[tid];
  }
  __syncthreads();

  // Phase A
  {
    const int cp = tid & 7;
    h2f16 wpa[4], wpb[4];
    #pragma unroll
    for (int j=0;j<4;j++){ wpa[j] = w1p[2*cp][j]; wpb[j] = w1p[2*cp+1][j]; }
    const float oa = kb1o[2*cp], ob = kb1o[2*cp+1];
    for (int u = tid>>3; u<500; u+=32){
      h2f16 xq[6];
      #pragma unroll
      for (int r=0;r<6;r++) xq[r] = sxh[3*u + r];
      float a0=0.f,a1=0.f,a2=0.f,b0=0.f,b1=0.f,b2=0.f;
      #pragma unroll
      for (int j=0;j<4;j++){
        a0 = __builtin_amdgcn_fdot2(xq[j],   wpa[j], a0, false);
        a1 = __builtin_amdgcn_fdot2(xq[j+1], wpa[j], a1, false);
        a2 = __builtin_amdgcn_fdot2(xq[j+2], wpa[j], a2, false);
        b0 = __builtin_amdgcn_fdot2(xq[j],   wpb[j], b0, false);
        b1 = __builtin_amdgcn_fdot2(xq[j+1], wpb[j], b1, false);
        b2 = __builtin_amdgcn_fdot2(xq[j+2], wpb[j], b2, false);
      }
      const float ya = fmaxf(fmaxf(fmaxf(a0,a1),a2) + oa, 0.f);
      const float yb = fmaxf(fmaxf(fmaxf(b0,b1),b2) + ob, 0.f);
      h2f16 p; p[0]=(_Float16)ya; p[1]=(_Float16)yb;
      *reinterpret_cast<h2f16*>(smb + (u+2)*40 + 4*cp) = p;
    }
  }
  __syncthreads();

  const int wv = tid >> 6, lane = tid & 63;
  const int m = lane & 15, g = lane >> 4;

  // Phase B
  {
    const int nt = wv & 1;
    f16x8 bf[3];
    #pragma unroll
    for (int s=0;s<3;s++)
      bf[s] = *reinterpret_cast<const f16x8*>(&bw2f[(((s*2+nt)*4+g)*16+m)*8]);
    const int oc = nt*16 + m;
    const float of = kb2o[oc];
    #pragma unroll
    for (int i=0;i<8;i++){
      const int mt = (wv>>1) + 2*i;
      const int trow = mt*16 + m;
      f32x4 acc = {0.f,0.f,0.f,0.f};
      #pragma unroll
      for (int s=0;s<3;s++){
        const int kk = 32*s + 8*g;
        const int k = kk >> 4;
        const int ab = 80*trow + 40*k + 16*(g&1);
        F8 a;
        a.v4[0] = *reinterpret_cast<const f16x4*>(smb + ab);
        a.v4[1] = *reinterpret_cast<const f16x4*>(smb + ab + 8);
        acc = __builtin_amdgcn_mfma_f32_16x16x32_f16(a.v8, bf[s], acc, 0,0,0);
      }
      #pragma unroll
      for (int r=0;r<4;r++){
        const int t = mt*16 + 4*g + r;
        const float z = fmaxf(acc[r] + of, 0.f);
        *reinterpret_cast<_Float16*>(smb + 20160 + t*72 + 2*oc) = (_Float16)z;
      }
    }
  }
  __syncthreads();

  // Pool
  {
    if (tid < 240){
      const int rr = tid >> 4, cc = tid & 15;
      const int row = (rr == 0) ? 0 : (83 + rr);
      h2f16 z; z[0]=(_Float16)0.f; z[1]=(_Float16)0.f;
      *reinterpret_cast<h2f16*>(smb + row*80 + 4*cc) = z;
    }
    for (int i=tid; i<1328; i+=256){
      const int u = i >> 4, cc = i & 15;
      h2f16 a = *reinterpret_cast<const h2f16*>(smb + 20160 + (3*u)*72 + 4*cc);
      h2f16 b = *reinterpret_cast<const h2f16*>(smb + 20160 + (3*u+1)*72 + 4*cc);
      h2f16 c = *reinterpret_cast<const h2f16*>(smb + 20160 + (3*u+2)*72 + 4*cc);
      *reinterpret_cast<h2f16*>(smb + (u+1)*80 + 4*cc) = hmax2(hmax2(a,b), c);
    }
  }
  __syncthreads();

  // Phase C
  {
    f16x8 bf[3];
    #pragma unroll
    for (int s=0;s<3;s++)
      bf[s] = *reinterpret_cast<const f16x8*>(&bw3f[(((s*4+wv)*4+g)*16+m)*8]);
    const int oc = wv*16 + m;
    const float of = kb3o[oc];
    float macc = 0.f;
    #pragma unroll
    for (int mt=0; mt<6; mt++){
      const int trow = mt*16 + m;
      f32x4 acc = {0.f,0.f,0.f,0.f};
      #pragma unroll
      for (int s=0;s<3;s++){
        f16x8 af = *reinterpret_cast<const f16x8*>(smb + (trow + s)*80 + 16*g);
        acc = __builtin_amdgcn_mfma_f32_16x16x32_f16(af, bf[s], acc, 0,0,0);
      }
      #pragma unroll
      for (int r=0;r<4;r++){
        const int t = mt*16 + 4*g + r;
        if (t < 83) macc += fmaxf(acc[r] + of, 0.f);
      }
    }
    macc += __shfl_xor(macc, 16);
    macc += __shfl_xor(macc, 32);
    if (lane < 16) feats[sig*64 + oc] = (_Float16)(macc * (1.f/83.f));
  }
}

// ---------------------------------------------------------------------------
// K3: MFMA f16 GEMM (single-W): C = X16 @ W16^T (+b1+b2), f32 out.
// ---------------------------------------------------------------------------
__global__ __launch_bounds__(256) void k_gemm_mf(
  const _Float16* __restrict__ X, const _Float16* __restrict__ W,
  const float* __restrict__ b1, const float* __restrict__ b2,
  float* __restrict__ C, int M, int N, int K, int ldc)
{
  __shared__ __align__(16) unsigned char lds[128*72];
  unsigned char* Xs = lds;
  unsigned char* Ws = lds + 64*72;
  const int tid = threadIdx.x;
  const int m0 = blockIdx.y*64, n0 = blockIdx.x*64;
  const int wv = tid>>6, lane = tid&63, m = lane&15, g = lane>>4;
  const int sr = tid>>2, sq = tid&3;
  f32x4 acc[4] = {{0.f,0.f,0.f,0.f},{0.f,0.f,0.f,0.f},{0.f,0.f,0.f,0.f},{0.f,0.f,0.f,0.f}};
  for (int k0=0; k0<K; k0+=32){
    uint4 xa = *reinterpret_cast<const uint4*>(X + (long)(m0+sr)*K + k0 + sq*8);
    uint4 wa = *reinterpret_cast<const uint4*>(W + (long)(n0+sr)*K + k0 + sq*8);
    __syncthreads();
    *reinterpret_cast<uint4*>(Xs + sr*72 + sq*16) = xa;
    *reinterpret_cast<uint4*>(Ws + sr*72 + sq*16) = wa;
    __syncthreads();
    f16x8 af = *reinterpret_cast<const f16x8*>(Xs + (wv*16+m)*72 + g*16);
    #pragma unroll
    for (int nt=0;nt<4;nt++){
      f16x8 bf = *reinterpret_cast<const f16x8*>(Ws + (nt*16+m)*72 + g*16);
      acc[nt] = __builtin_amdgcn_mfma_f32_16x16x32_f16(af, bf, acc[nt], 0,0,0);
    }
  }
  #pragma unroll
  for (int nt=0;nt<4;nt++){
    const int col = n0 + nt*16 + m;
    float bias = 0.f;
    if (b1) bias += b1[col];
    if (b2) bias += b2[col];
    #pragma unroll
    for (int r=0;r<4;r++)
      C[(long)(m0 + wv*16 + g*4 + r)*ldc + col] = acc[nt][r] + bias;
  }
}

// ---------------------------------------------------------------------------
// K3b: dual-W MFMA GEMM: blockIdx.z selects (Wa,b1a,b2a,C) vs (Wb,b1b,b2b,C+co)
// ---------------------------------------------------------------------------
__global__ __launch_bounds__(256) void k_gemm_mf2(
  const _Float16* __restrict__ X,
  const _Float16* __restrict__ Wa, const _Float16* __restrict__ Wb,
  const float* __restrict__ b1a, const float* __restrict__ b2a,
  const float* __restrict__ b1b, const float* __restrict__ b2b,
  float* __restrict__ C, int co, int M, int N, int K, int ldc)
{
  __shared__ __align__(16) unsigned char lds[128*72];
  unsigned char* Xs = lds;
  unsigned char* Ws = lds + 64*72;
  const int z = blockIdx.z;
  const _Float16* W = z ? Wb : Wa;
  const float* b1 = z ? b1b : b1a;
  const float* b2 = z ? b2b : b2a;
  float* Cz = C + (z ? co : 0);
  const int tid = threadIdx.x;
  const int m0 = blockIdx.y*64, n0 = blockIdx.x*64;
  const int wv = tid>>6, lane = tid&63, m = lane&15, g = lane>>4;
  const int sr = tid>>2, sq = tid&3;
  f32x4 acc[4] = {{0.f,0.f,0.f,0.f},{0.f,0.f,0.f,0.f},{0.f,0.f,0.f,0.f},{0.f,0.f,0.f,0.f}};
  for (int k0=0; k0<K; k0+=32){
    uint4 xa = *reinterpret_cast<const uint4*>(X + (long)(m0+sr)*K + k0 + sq*8);
    uint4 wa = *reinterpret_cast<const uint4*>(W + (long)(n0+sr)*K + k0 + sq*8);
    __syncthreads();
    *reinterpret_cast<uint4*>(Xs + sr*72 + sq*16) = xa;
    *reinterpret_cast<uint4*>(Ws + sr*72 + sq*16) = wa;
    __syncthreads();
    f16x8 af = *reinterpret_cast<const f16x8*>(Xs + (wv*16+m)*72 + g*16);
    #pragma unroll
    for (int nt=0;nt<4;nt++){
      f16x8 bf = *reinterpret_cast<const f16x8*>(Ws + (nt*16+m)*72 + g*16);
      acc[nt] = __builtin_amdgcn_mfma_f32_16x16x32_f16(af, bf, acc[nt], 0,0,0);
    }
  }
  #pragma unroll
  for (int nt=0;nt<4;nt++){
    const int col = n0 + nt*16 + m;
    float bias = b1[col] + b2[col];
    #pragma unroll
    for (int r=0;r<4;r++)
      Cz[(long)(m0 + wv*16 + g*4 + r)*ldc + col] = acc[nt][r] + bias;
  }
}

// ---------------------------------------------------------------------------
// K4: g1 mix (f16 out)
// ---------------------------------------------------------------------------
__global__ __launch_bounds__(256) void k_mix1(
  const float* __restrict__ tmp0, const float* __restrict__ An,
  const float* __restrict__ b0, _Float16* __restrict__ g1)
{
  __shared__ float ans[64];
  if (threadIdx.x < 64) ans[threadIdx.x] = An[threadIdx.x];
  __syncthreads();
  const long idx = (long)blockIdx.x*256 + threadIdx.x;   // over 1280*128
  const int g = (int)(idx >> 7), j = (int)(idx & 127);
  const float* base = tmp0 + (long)g*1024;
  float t[8];
  #pragma unroll
  for (int c=0;c<8;c++) t[c] = base[c*128+j];
  const float bj = b0[j];
  #pragma unroll
  for (int i=0;i<8;i++){
    float s = bj;
    #pragma unroll
    for (int c=0;c<8;c++) s += ans[i*8+c]*t[c];
    g1[(long)g*1024 + i*128 + j] = (_Float16)fmaxf(s, 0.f);
  }
}

// ---------------------------------------------------------------------------
// K6: g2 mix + LN + node-mean -> emb (f16 out)
// ---------------------------------------------------------------------------
__global__ __launch_bounds__(128) void k_mix2(
  const float* __restrict__ tmp1, const float* __restrict__ An,
  const float* __restrict__ b1, const float* __restrict__ lng,
  const float* __restrict__ lnb, _Float16* __restrict__ emb)
{
  const int g = blockIdx.x, j = threadIdx.x;
  __shared__ float ans[64];
  __shared__ float g2s[8*128];
  __shared__ float stats[16];
  if (j<64) ans[j] = An[j];
  const float* base = tmp1 + (long)g*1024;
  float t[8];
  #pragma unroll
  for (int c=0;c<8;c++) t[c] = base[c*128 + j];
  const float bj = b1[j];
  __syncthreads();
  #pragma unroll
  for (int i=0;i<8;i++){
    float s = bj;
    #pragma unroll
    for (int c=0;c<8;c++) s += ans[i*8+c]*t[c];
    g2s[i*128+j] = s;
  }
  __syncthreads();
  {
    const int c = j>>4, l = j&15;
    float s=0.f, sq=0.f;
    for (int jj=l; jj<128; jj+=16){ float v=g2s[c*128+jj]; s+=v; sq+=v*v; }
    #pragma unroll
    for (int off=8; off>=1; off>>=1){ s += __shfl_xor(s, off); sq += __shfl_xor(sq, off); }
    if (l==0){
      float m = s*(1.f/128.f);
      stats[2*c] = m;
      stats[2*c+1] = rsqrtf(sq*(1.f/128.f) - m*m + 1e-5f);
    }
  }
  __syncthreads();
  float acc=0.f;
  #pragma unroll
  for (int i=0;i<8;i++) acc += (g2s[i*128+j] - stats[2*i]) * stats[2*i+1];
  emb[(long)g*128 + j] = (_Float16)(lng[j]*acc*0.125f + lnb[j]);
}

// ---------------------------------------------------------------------------
// K8: one LSTM layer, both directions. Block = (batch, dir), 1024 threads.
// Weight residency: rows jp 0..15 of each quarter in regs (64 VGPR);
// rows 16..31 of jg0 and jg1 in LDS (128 KB); only jg2/jg3 stream rows
// 16..31 from L2 -> 128 KB/step (was 288).
// ---------------------------------------------------------------------------
__global__ __launch_bounds__(1024) void k_lstm(
    const float* __restrict__ xs,          // [1280][2048] fwd|rev gates
    const h2f16* __restrict__ wtf,         // [128][1024] packed j-pairs
    const h2f16* __restrict__ wtr,
    float* __restrict__ outf,              // [1280][512] (may be null)
    _Float16* __restrict__ outh)           // [1280][512] (may be null)
{
  const int S = 20;
  const int b = blockIdx.x >> 1, dir = blockIdx.x & 1;
  const h2f16* wt = dir ? wtr : wtf;
  __shared__ float part[4][1024];
  __shared__ _Float16 hsh[256];
  __shared__ __align__(16) unsigned char wlds[131072];   // rows 16..31 of jg0,jg1
  const int tid = threadIdx.x;
  const int jg = tid >> 8, r = tid & 255, grow = r*4;
  // reg-resident rows jp 0..15 of this thread's quarter (16B slice each)
  uint4 wreg[16];
  #pragma unroll
  for (int jp=0;jp<16;jp++)
    wreg[jp] = *reinterpret_cast<const uint4*>(
        reinterpret_cast<const unsigned int*>(wt + (long)(jg*32+jp)*1024 + grow));
  // LDS fill: rows 16..31 of quarter 0 (src uint4 4096..8191) then quarter 1
  // (src uint4 12288..16383); row = 256 uint4.
  {
    const uint4* wsrc = reinterpret_cast<const uint4*>(wt);
    uint4* wdst = reinterpret_cast<uint4*>(wlds);
    for (int i=tid; i<8192; i+=1024){
      const int src = (i < 4096) ? (4096 + i) : (12288 + (i - 4096));
      wdst[i] = wsrc[src];
    }
  }
  if (tid < 256) hsh[tid] = (_Float16)0.f;
  float cc = 0.f;
  __syncthreads();
  const h2f16* hp2 = reinterpret_cast<const h2f16*>(hsh);
  for (int st=0; st<S; ++st){
    const int t = dir ? (S-1-st) : st;
    float a0=0.f,a1=0.f,a2=0.f,a3=0.f;
    #pragma unroll
    for (int jp=0; jp<16; ++jp){
      const h2f16 hv = hp2[jg*32 + jp];
      U4H w; w.u = wreg[jp];
      a0 = __builtin_amdgcn_fdot2(hv, w.h[0], a0, false);
      a1 = __builtin_amdgcn_fdot2(hv, w.h[1], a1, false);
      a2 = __builtin_amdgcn_fdot2(hv, w.h[2], a2, false);
      a3 = __builtin_amdgcn_fdot2(hv, w.h[3], a3, false);
    }
    if (jg < 2){
      #pragma unroll 8
      for (int jp=16; jp<32; ++jp){
        const h2f16 hv = hp2[jg*32 + jp];
        U4H w; w.u = *reinterpret_cast<const uint4*>(
            wlds + (long)(jg*16 + (jp-16))*4096 + grow*4);
        a0 = __builtin_amdgcn_fdot2(hv, w.h[0], a0, false);
        a1 = __builtin_amdgcn_fdot2(hv, w.h[1], a1, false);
        a2 = __builtin_amdgcn_fdot2(hv, w.h[2], a2, false);
        a3 = __builtin_amdgcn_fdot2(hv, w.h[3], a3, false);
      }
    } else {
      #pragma unroll 8
      for (int jp=16; jp<32; ++jp){
        const h2f16 hv = hp2[jg*32 + jp];
        U4H w; w.u = *reinterpret_cast<const uint4*>(
            reinterpret_cast<const unsigned int*>(wt + (long)(jg*32+jp)*1024 + grow));
        a0 = __builtin_amdgcn_fdot2(hv, w.h[0], a0, false);
        a1 = __builtin_amdgcn_fdot2(hv, w.h[1], a1, false);
        a2 = __builtin_amdgcn_fdot2(hv, w.h[2], a2, false);
        a3 = __builtin_amdgcn_fdot2(hv, w.h[3], a3, false);
      }
    }
    *reinterpret_cast<float4*>(&part[jg][grow]) = make_float4(a0,a1,a2,a3);
    __syncthreads();
    if (tid < 256){
      const float* xrow = xs + ((long)b*S + t)*2048 + dir*1024;
      float g0 = xrow[tid]
               + (part[0][tid]      + part[1][tid])      + (part[2][tid]      + part[3][tid]);
      float g1 = xrow[256+tid]
               + (part[0][256+tid]  + part[1][256+tid])  + (part[2][256+tid]  + part[3][256+tid]);
      float g2 = xrow[512+tid]
               + (part[0][512+tid]  + part[1][512+tid])  + (part[2][512+tid]  + part[3][512+tid]);
      float g3 = xrow[768+tid]
               + (part[0][768+tid]  + part[1][768+tid])  + (part[2][768+tid]  + part[3][768+tid]);
      cc = sigf(g1)*cc + sigf(g0)*tanh_f(g2);
      const float h = sigf(g3)*tanh_f(cc);
      hsh[tid] = (_Float16)h;
      const long o = ((long)b*S + t)*512 + dir*256 + tid;
      if (outf) outf[o] = h;
      if (outh) outh[o] = (_Float16)h;
    }
    __syncthreads();
  }
}

// ---------------------------------------------------------------------------
// K11: final LayerNorm(512) + classifier (5) per row
// ---------------------------------------------------------------------------
__global__ __launch_bounds__(128) void k_lncls(
  const float* __restrict__ in, const float* __restrict__ g,
  const float* __restrict__ b, const float* __restrict__ cw,
  const float* __restrict__ cb, float* __restrict__ out)
{
  const int row = blockIdx.x, tid = threadIdx.x;
  __shared__ float sred[4];
  __shared__ float cred[2][5];
  float4 v = *reinterpret_cast<const float4*>(in + (long)row*512 + tid*4);
  float s  = v.x+v.y+v.z+v.w;
  float sq = v.x*v.x+v.y*v.y+v.z*v.z+v.w*v.w;
  #pragma unroll
  for (int off=32; off>=1; off>>=1){ s += __shfl_xor(s, off); sq += __shfl_xor(sq, off); }
  const int wv = tid>>6;
  if ((tid&63)==0){ sred[wv*2]=s; sred[wv*2+1]=sq; }
  __syncthreads();
  const float S = sred[0]+sred[2], SQ = sred[1]+sred[3];
  const float m = S*(1.f/512.f);
  const float rstd = rsqrtf(SQ*(1.f/512.f) - m*m + 1e-5f);
  float4 gg = *reinterpret_cast<const float4*>(g + tid*4);
  float4 bb = *reinterpret_cast<const float4*>(b + tid*4);
  const float n0 = (v.x-m)*rstd*gg.x + bb.x;
  const float n1 = (v.y-m)*rstd*gg.y + bb.y;
  const float n2 = (v.z-m)*rstd*gg.z + bb.z;
  const float n3 = (v.w-m)*rstd*gg.w + bb.w;
  #pragma unroll
  for (int nc=0; nc<5; ++nc){
    float4 w = *reinterpret_cast<const float4*>(cw + nc*512 + tid*4);
    float p = n0*w.x + n1*w.y + n2*w.z + n3*w.w;
    #pragma unroll
    for (int off=32; off>=1; off>>=1) p += __shfl_xor(p, off);
    if ((tid&63)==0) cred[wv][nc] = p;
  }
  __syncthreads();
  if (tid < 5) out[(long)row*5 + tid] = cred[0][tid] + cred[1][tid] + cb[tid];
}

// ---------------------------------------------------------------------------
extern "C" void kernel_launch(void* const* d_in, const int* in_sizes, int n_in,
                              void* d_out, int out_size, void* d_ws, size_t ws_size,
                              hipStream_t stream)
{
  const float* x     = (const float*)d_in[0];
  const int*   ei    = (const int*)d_in[1];
  const float* w1    = (const float*)d_in[2];
  const float* c1b   = (const float*)d_in[3];
  const float* bg1   = (const float*)d_in[4];
  const float* bb1   = (const float*)d_in[5];
  const float* w2    = (const float*)d_in[6];
  const float* c2b   = (const float*)d_in[7];
  const float* bg2   = (const float*)d_in[8];
  const float* bb2   = (const float*)d_in[9];
  const float* w3    = (const float*)d_in[10];
  const float* c3b   = (const float*)d_in[11];
  const float* bg3   = (const float*)d_in[12];
  const float* bb3   = (const float*)d_in[13];
  const float* gcn0w = (const float*)d_in[14];
  const float* gcn0b = (const float*)d_in[15];
  const float* gcn1w = (const float*)d_in[16];
  const float* gcn1b = (const float*)d_in[17];
  const float* lng   = (const float*)d_in[18];
  const float* lnb   = (const float*)d_in[19];
  const float* wih0  = (const float*)d_in[20];
  const float* whh0  = (const float*)d_in[21];
  const float* bih0  = (const float*)d_in[22];
  const float* bhh0  = (const float*)d_in[23];
  const float* wih0r = (const float*)d_in[24];
  const float* whh0r = (const float*)d_in[25];
  const float* bih0r = (const float*)d_in[26];
  const float* bhh0r = (const float*)d_in[27];
  const float* wih1  = (const float*)d_in[28];
  const float* whh1  = (const float*)d_in[29];
  const float* bih1  = (const float*)d_in[30];
  const float* bhh1  = (const float*)d_in[31];
  const float* wih1r = (const float*)d_in[32];
  const float* whh1r = (const float*)d_in[33];
  const float* bih1r = (const float*)d_in[34];
  const float* bhh1r = (const float*)d_in[35];
  const float* lstmg = (const float*)d_in[36];
  const float* lstmb = (const float*)d_in[37];
  const float* clsw  = (const float*)d_in[38];
  const float* clsb  = (const float*)d_in[39];
  float* ws  = (float*)d_ws;
  float* out = (float*)d_out;

  // workspace layout (float offsets), ~23.5 MB total
  float*    An      = ws + 0;                         // 64
  _Float16* bw2f    = (_Float16*)(ws + 64);           // 3072 h
  _Float16* bw3f    = (_Float16*)(ws + 1600);         // 6144 h
  _Float16* feats16 = (_Float16*)(ws + 4672);         // 655360 h
  _Float16* g1b16   = (_Float16*)(ws + 332352);       // 1310720 h
  _Float16* emb16   = (_Float16*)(ws + 987712);       // 163840 h
  _Float16* l0h     = (_Float16*)(ws + 1069632);      // 655360 h
  _Float16* w0f     = (_Float16*)(ws + 1397312);      // 131072 h
  _Float16* w0rf    = (_Float16*)(ws + 1462848);      // 131072 h
  _Float16* w1f     = (_Float16*)(ws + 1528384);      // 524288 h
  _Float16* w1rf    = (_Float16*)(ws + 1790528);      // 524288 h
  _Float16* gw0f    = (_Float16*)(ws + 2052672);      // 8192 h
  _Float16* gw1f    = (_Float16*)(ws + 2056768);      // 16384 h
  h2f16*    wt0f    = (h2f16*)(ws + 2064960);         // 131072 f each
  h2f16*    wt0r    = (h2f16*)(ws + 2196032);
  h2f16*    wt1f    = (h2f16*)(ws + 2327104);
  h2f16*    wt1r    = (h2f16*)(ws + 2458176);
  float*    l1f     = ws + 2589248;                   // 655360 f
  float*    xs      = ws + 3244608;                   // 2621440 f
  float*    tmp     = xs;                             // aliases xs

  // Stage 0: fused prep (adjacency + all weight packs/transposes)
  k_prep<<<7289, 256, 0, stream>>>(ei, An, w2, w3, bg2, bg3, bw2f, bw3f,
                                   wih0, wih0r, wih1, wih1r, gcn0w, gcn1w,
                                   w0f, w0rf, w1f, w1rf, gw0f, gw1f,
                                   whh0, whh0r, whh1, whh1r,
                                   wt0f, wt0r, wt1f, wt1r);
  // Stage 1: conv front-end
  k_conv<<<10240, 256, 0, stream>>>(x, w1,c1b,bg1,bb1, bw2f,c2b,bg2,bb2,
                                    bw3f,c3b,bg3,bb3, feats16);

  // Stage 2: GCN
  k_gemm_mf<<<dim3(2, 160), 256, 0, stream>>>(feats16, gw0f, nullptr, nullptr, tmp, 10240, 128, 64, 128);
  k_mix1<<<640,256,0,stream>>>(tmp, An, gcn0b, g1b16);
  k_gemm_mf<<<dim3(2, 160), 256, 0, stream>>>(g1b16, gw1f, nullptr, nullptr, tmp, 10240, 128, 128, 128);
  k_mix2<<<1280,128,0,stream>>>(tmp, An, gcn1b, lng, lnb, emb16);

  // Stage 3: BiLSTM layer 0
  k_gemm_mf2<<<dim3(16, 20, 2), 256, 0, stream>>>(emb16, w0f, w0rf,
      bih0, bhh0, bih0r, bhh0r, xs, 1024, 1280, 1024, 128, 2048);
  k_lstm<<<128, 1024, 0, stream>>>(xs, wt0f, wt0r, nullptr, l0h);

  // BiLSTM layer 1
  k_gemm_mf2<<<dim3(16, 20, 2), 256, 0, stream>>>(l0h, w1f, w1rf,
      bih1, bhh1, bih1r, bhh1r, xs, 1024, 1280, 1024, 512, 2048);
  k_lstm<<<128, 1024, 0, stream>>>(xs, wt1f, wt1r, l1f, nullptr);

  // Stage 4: LN + classifier
  k_lncls<<<1280, 128, 0, stream>>>(l1f, lstmg, lstmb, clsw, clsb, out);
}